// Round 3
// baseline (1160.843 us; speedup 1.0000x reference)
//
#include <hip/hip_runtime.h>
#include <hip/hip_bf16.h>

#define NTOT   65536
#define NEDGE  1048576
#define HEADS  5
#define K1     32
#define K2     8
#define MEMH   100
#define EPSF   1e-8f

// ---- workspace layout (bytes) ----
// timeline:  xc(C) --lin1--> qv(B) --aggr128--> aggr2(A) --lin2 in-place--> qbn(A)
//            --bnapply in-place--> qf(A) --k_qk--> qk(B..B+40MB) --memconv0--> mq1, mq2
#define OFF_DEG     0x0000000
#define OFF_CURSOR  0x0040000
#define OFF_OFFS    0x0080000
#define OFF_BNSUM   0x00C0000
#define OFF_BNSQ    0x00C0400
#define OFF_SCALE   0x00C0800
#define OFF_SHIFT   0x00C0A00
#define OFF_KSQ0    0x00C0C00
#define OFF_KSQ1    0x00C0E80
#define OFF_KL      0x00C0F40
#define OFF_FLAG    0x00C0F60
#define OFF_W       0x00C1000   // canonical f32 weights (102816 floats)
#define OFF_CSR     0x0140000   // 4MB
#define OFF_A       0x0540000   // 32MB: aggr64 / aggr128 -> qbn -> qf
#define OFF_B       0x2540000   // 32MB: qv ; later qk (40MB, spills past B while dead)
#define OFF_QK      0x2540000   // 40MB: 0x2540000 .. 0x4D40000
#define OFF_C       0x4540000   // 16MB: xc (dead after lin1; mq1 written later)
#define OFF_MQ1     0x4D40000   // 3.2MB
#define OFF_MQ2     0x5060000   // 0.8MB
// peak ws use: 0x5540000 (~89.3MB)

// ---- canonical weight offsets (floats) ----
#define W_WREL0  0
#define W_BREL0  8192
#define W_WROOT0 8320
#define W_WREL1  16512
#define W_BREL1  32896
#define W_WROOT1 33024
#define W_GAMMA  49408
#define W_BETA   49536
#define W_KEYS0  49664
#define W_CONVW0 70144
#define W_LINW0  70149
#define W_LINB0  82949
#define W_KEYS1  83049
#define W_CONVW1 87049
#define W_LINW1  87054
#define W_LINB1  97054
#define W_MLPW1  97154
#define W_MLPB1  102154
#define W_MLPW2  102204
#define W_MLPB2  102804
#define W_TOTAL  102816

__device__ __forceinline__ float bf2f(unsigned short u){
  union { unsigned int i; float f; } v; v.i = ((unsigned int)u) << 16; return v.f;
}

__device__ const int g_seg[21] = {0,8192,8320,16512,32896,33024,49408,49536,49664,
                                  70144,70149,82949,83049,87049,87054,97054,97154,
                                  102154,102204,102804,102816};
struct WPtrs { const void* p[20]; };

// ---------------- dtype probe ----------------
// bf16 stream: even u16s are bf16 of N(0,1) -> exponent ~[115,135], nonzero.
// f32 stream: even u16s are low mantissa bits -> uniform exponent field, or 0.
__global__ void k_detect(const unsigned short* __restrict__ xr, int* flag){
  int t = threadIdx.x & 63;
  unsigned short u = xr[2*t];
  int e = (u >> 7) & 0xFF;
  bool plaus = (u != 0) && (e >= 115) && (e <= 135);
  unsigned long long m = __ballot(plaus);
  if(t == 0) flag[0] = (__popcll(m) >= 48) ? 1 : 0;
}

__global__ __launch_bounds__(256) void k_cvtx(const void* __restrict__ xin,
                                              const int* __restrict__ flag,
                                              float* __restrict__ xout){
  int i = blockIdx.x*256 + threadIdx.x;          // NTOT*64
  if(flag[0]) xout[i] = bf2f(((const unsigned short*)xin)[i]);
  else        xout[i] = ((const float*)xin)[i];
}

__global__ __launch_bounds__(256) void k_cvtw(WPtrs wp, const int* __restrict__ flag,
                                              float* __restrict__ wout){
  int i = blockIdx.x*256 + threadIdx.x;
  if(i >= W_TOTAL) return;
  int s = 0;
  #pragma unroll
  for(int k=0;k<20;k++) if(i >= g_seg[k+1]) s = k+1;
  int j = i - g_seg[s];
  const void* src = wp.p[s];
  wout[i] = flag[0] ? bf2f(((const unsigned short*)src)[j]) : ((const float*)src)[j];
}

// ---------------- init / CSR build ----------------
__global__ __launch_bounds__(256) void k_init(int* deg, int* cursor,
                                              unsigned long long* bnsum,
                                              unsigned long long* bnsq, float* kl){
  int i = blockIdx.x*256 + threadIdx.x;
  if(i < NTOT){ deg[i]=0; cursor[i]=0; }
  if(i < 128){ bnsum[i]=0ULL; bnsq[i]=0ULL; }
  if(i < 2) kl[i]=0.f;
}

__global__ __launch_bounds__(256) void k_count(const int* __restrict__ dst, int* deg){
  int e = blockIdx.x*256 + threadIdx.x;
  atomicAdd(&deg[dst[e]], 1);
}

__global__ __launch_bounds__(1024) void k_scan(const int* __restrict__ deg, int* __restrict__ offs){
  __shared__ int ts[1024];
  const int t = threadIdx.x;
  const int base = t*64;
  int s = 0;
  for(int i=0;i<64;i++) s += deg[base+i];
  ts[t] = s; __syncthreads();
  for(int off=1; off<1024; off<<=1){
    int v = (t>=off) ? ts[t-off] : 0;
    __syncthreads();
    ts[t] += v;
    __syncthreads();
  }
  int run = (t==0) ? 0 : ts[t-1];
  for(int i=0;i<64;i++){ offs[base+i]=run; run += deg[base+i]; }
}

__global__ __launch_bounds__(256) void k_fill(const int* __restrict__ src, const int* __restrict__ dst,
                                              const int* __restrict__ offs, int* cursor, int* __restrict__ csr){
  int e = blockIdx.x*256 + threadIdx.x;
  int d = dst[e];
  int p = atomicAdd(&cursor[d], 1);
  csr[offs[d] + p] = src[e];
}

// ---------------- graph conv ----------------
__global__ __launch_bounds__(256) void k_aggr64(const float* __restrict__ xc,
                                                const int* __restrict__ offs, const int* __restrict__ deg,
                                                const int* __restrict__ csr, float* __restrict__ aggr){
  int wid  = (blockIdx.x*256 + threadIdx.x) >> 6;
  int lane = threadIdx.x & 63;
  int beg = offs[wid], n = deg[wid];
  float acc = 0.f;
  for(int i=0;i<n;i++){
    int s = csr[beg+i];
    acc += xc[(size_t)s*64 + lane];
  }
  aggr[(size_t)wid*64 + lane] = acc;
}

__global__ __launch_bounds__(128) void k_lin1(const float* __restrict__ aggr, const float* __restrict__ xc,
                                              const float* __restrict__ W, float* __restrict__ qout){
  __shared__ float a_s[64];
  __shared__ float x_s[64];
  const int n = blockIdx.x, j = threadIdx.x;
  if(j < 64){
    a_s[j] = aggr[(size_t)n*64 + j];
    x_s[j] = xc[(size_t)n*64 + j];
  }
  __syncthreads();
  float acc = W[W_BREL0 + j];
  #pragma unroll 8
  for(int f=0;f<64;f++)
    acc += a_s[f]*W[W_WREL0 + f*128 + j] + x_s[f]*W[W_WROOT0 + f*128 + j];
  qout[(size_t)n*128 + j] = fmaxf(acc, 0.f);
}

__global__ __launch_bounds__(256) void k_aggr128(const float* __restrict__ q,
                                                 const int* __restrict__ offs, const int* __restrict__ deg,
                                                 const int* __restrict__ csr, float* __restrict__ aggr){
  int wid  = (blockIdx.x*256 + threadIdx.x) >> 6;
  int lane = threadIdx.x & 63;
  int beg = offs[wid], n = deg[wid];
  float a0=0.f, a1=0.f;
  for(int i=0;i<n;i++){
    int s = csr[beg+i];
    const float* r = q + (size_t)s*128;
    a0 += r[lane]; a1 += r[lane+64];
  }
  aggr[(size_t)wid*128 + lane]      = a0;
  aggr[(size_t)wid*128 + lane + 64] = a1;
}

// in-place safe: block n reads only row n into LDS, then overwrites row n
__global__ __launch_bounds__(128) void k_lin2(const float* __restrict__ aggr, const float* __restrict__ q,
                                              const float* __restrict__ W, float* __restrict__ qout){
  __shared__ float a_s[128];
  __shared__ float x_s[128];
  const int n = blockIdx.x, j = threadIdx.x;
  a_s[j] = aggr[(size_t)n*128 + j];
  x_s[j] = q[(size_t)n*128 + j];
  __syncthreads();
  float acc = W[W_BREL1 + j];
  #pragma unroll 8
  for(int f=0;f<128;f++)
    acc += a_s[f]*W[W_WREL1 + f*128 + j] + x_s[f]*W[W_WROOT1 + f*128 + j];
  qout[(size_t)n*128 + j] = fmaxf(acc, 0.f);
}

// ---------------- batchnorm ----------------
__global__ __launch_bounds__(128) void k_bnstats(const float* __restrict__ qbn, double* bnsum, double* bnsq){
  const int j = threadIdx.x;
  const int r0 = blockIdx.x*128;
  float s=0.f, s2=0.f;
  for(int r=0;r<128;r++){ float v = qbn[(size_t)(r0+r)*128 + j]; s += v; s2 += v*v; }
  atomicAdd(&bnsum[j], (double)s);
  atomicAdd(&bnsq[j], (double)s2);
}

__global__ __launch_bounds__(256) void k_bnfin(const double* __restrict__ bnsum, const double* __restrict__ bnsq,
                                               const float* __restrict__ W,
                                               float* scale, float* shift, float* ksq0, float* ksq1){
  const int t = threadIdx.x;
  if(t < 128){
    double mu  = bnsum[t] / (double)NTOT;
    double var = bnsq[t] / (double)NTOT - mu*mu;
    if(var < 0.0) var = 0.0;
    float sc = W[W_GAMMA + t] * rsqrtf((float)var + 1e-5f);
    scale[t] = sc;
    shift[t] = W[W_BETA + t] - (float)mu * sc;
  }
  if(t < HEADS*K1){
    float s=0.f;
    for(int f=0;f<128;f++){ float v = W[W_KEYS0 + t*128 + f]; s += v*v; }
    ksq0[t] = s;
  }
  if(t < HEADS*K2){
    float s=0.f;
    for(int f=0;f<100;f++){ float v = W[W_KEYS1 + t*100 + f]; s += v*v; }
    ksq1[t] = s;
  }
}

// in-place safe: elementwise, same index
__global__ __launch_bounds__(256) void k_bnapply(const float* __restrict__ qbn, const float* __restrict__ scale,
                                                 const float* __restrict__ shift, float* __restrict__ qf){
  int i = blockIdx.x*256 + threadIdx.x;   // NTOT*128
  int f = i & 127;
  qf[i] = qbn[i]*scale[f] + shift[f];
}

// ---------------- qk: (65536x128) @ keys0^T (160x128) -> qk (65536x160), VALU ----
__global__ __launch_bounds__(256) void k_qk(const float* __restrict__ qf,
                                            const float* __restrict__ W,
                                            float* __restrict__ qk){
  __shared__ float Qs[32*129];
  __shared__ float Ks[8*128];
  const int r0 = blockIdx.x*32;
  const int t = threadIdx.x;
  for(int idx=t; idx<32*128; idx+=256){
    int r = idx >> 7, f = idx & 127;
    Qs[r*129+f] = qf[(size_t)(r0+r)*128 + f];
  }
  const int r = t & 31, kk = t >> 5;   // 32 rows x 8 keys per chunk
  for(int c=0; c<20; c++){
    __syncthreads();
    for(int idx=t; idx<8*128; idx+=256) Ks[idx] = W[W_KEYS0 + c*1024 + idx];
    __syncthreads();
    float a=0.f;
    const float* qp = &Qs[r*129];
    const float* kp = &Ks[kk*128];
    #pragma unroll 8
    for(int f=0; f<128; f++) a += qp[f]*kp[f];
    qk[(size_t)(r0+r)*160 + c*8 + kk] = a;
  }
}

// ---------------- mem conv 0 (block per batch) ----------------
__global__ __launch_bounds__(256) void k_memconv0(
    const float* __restrict__ qk, const float* __restrict__ qf,
    const float* __restrict__ W, const float* __restrict__ ksq,
    float* __restrict__ mq1, float* __restrict__ klacc)
{
  __shared__ float Cs[256*33];
  __shared__ float Vs[32*132];
  __shared__ float cn_s[32];
  __shared__ float pn_s[256];
  __shared__ float red_s[4];
  const int b = blockIdx.x, t = threadIdx.x;

  const float4* qrow = (const float4*)(qf + (size_t)(b*256 + t)*128);
  float qsq = 0.f;
  #pragma unroll 8
  for(int jj=0; jj<32; jj++){
    float4 v = qrow[jj];
    qsq += v.x*v.x + v.y*v.y + v.z*v.z + v.w*v.w;
  }

  const float* qkrow = qk + (size_t)(b*256 + t)*160;
  float wsum[32];
  #pragma unroll
  for(int k=0;k<32;k++) wsum[k]=0.f;
  for(int h=0; h<HEADS; h++){
    float cw = W[W_CONVW0 + h];
    float c[32]; float rs = 0.f;
    #pragma unroll
    for(int k=0;k<32;k++){
      float d2 = qsq + ksq[h*32+k] - 2.f*qkrow[h*32+k];
      d2 = fmaxf(d2, 1e-12f);
      float cc = 1.f/(1.f+d2);
      c[k]=cc; rs += cc;
    }
    float sc = cw/fmaxf(rs, 1e-20f);
    #pragma unroll
    for(int k=0;k<32;k++) wsum[k] += c[k]*sc;
  }
  float mx = wsum[0];
  #pragma unroll
  for(int k=1;k<32;k++) mx = fmaxf(mx, wsum[k]);
  float se = 0.f;
  #pragma unroll
  for(int k=0;k<32;k++){ float e = __expf(wsum[k]-mx); wsum[k]=e; se+=e; }
  float inv = 1.f/se;
  #pragma unroll
  for(int k=0;k<32;k++) Cs[t*33+k] = wsum[k]*inv;
  __syncthreads();

  if(t < 32){ float s=0.f; for(int n=0;n<256;n++) s += Cs[n*33+t]; cn_s[t] = s + EPSF; }
  __syncthreads();
  {
    float p = 0.f;
    #pragma unroll
    for(int k=0;k<32;k++){ float sv = Cs[t*33+k]; p += sv*sv/cn_s[k]; }
    pn_s[t] = p + EPSF;
  }
  __syncthreads();

  float acc = 0.f;
  for(int idx=t; idx<256*32; idx+=256){
    int n = idx>>5, k = idx&31;
    float sv = Cs[n*33+k];
    float P = sv*sv/(cn_s[k]*pn_s[n]);
    acc += P*(__logf(P+EPSF) - __logf(sv+EPSF));
  }
  #pragma unroll
  for(int off=32; off>0; off>>=1) acc += __shfl_down(acc, off);
  if((t&63)==0) red_s[t>>6] = acc;

  // V = C^T Q : thread handles k = t>>3, 16 features
  const int vk = t>>3;
  const int f0 = (t&7)<<4;
  float vacc[16];
  #pragma unroll
  for(int i=0;i<16;i++) vacc[i]=0.f;
  const float* qbase = qf + (size_t)b*256*128 + f0;
  for(int n=0;n<256;n++){
    float cv = Cs[n*33+vk];
    const float4* qp = (const float4*)(qbase + (size_t)n*128);
    #pragma unroll
    for(int jj=0;jj<4;jj++){
      float4 u = qp[jj];
      vacc[jj*4+0] += cv*u.x;
      vacc[jj*4+1] += cv*u.y;
      vacc[jj*4+2] += cv*u.z;
      vacc[jj*4+3] += cv*u.w;
    }
  }
  #pragma unroll
  for(int i=0;i<16;i++) Vs[vk*132 + f0 + i] = vacc[i];
  __syncthreads();

  if(t==0) atomicAdd(klacc, 100.f*(red_s[0]+red_s[1]+red_s[2]+red_s[3]));

  for(int idx=t; idx<K1*MEMH; idx+=256){
    int k = idx/100, m = idx - k*100;
    float a = W[W_LINB0 + m];
    for(int f=0; f<128; f++) a += Vs[k*132+f]*W[W_LINW0 + f*100 + m];
    mq1[(size_t)(b*32+k)*100 + m] = (a>0.f) ? a : 0.01f*a;
  }
}

// ---------------- mem conv 1 ----------------
__global__ __launch_bounds__(256) void k_memconv1(
    const float* __restrict__ mq1, const float* __restrict__ W,
    const float* __restrict__ ksq, float* __restrict__ mq2, float* __restrict__ klacc)
{
  __shared__ float Qs[32*104];
  __shared__ float Ks[40*100];
  __shared__ float QKs[32*40];
  __shared__ float Cs[32*8];
  __shared__ float cn_s[8];
  __shared__ float pn_s[32];
  __shared__ float qsq_s[32];
  __shared__ float Vs[8*100];
  __shared__ float red_s[4];
  const int b = blockIdx.x, t = threadIdx.x;

  for(int idx=t; idx<32*100; idx+=256){
    int n = idx/100, f = idx - n*100;
    Qs[n*104+f] = mq1[(size_t)b*3200 + idx];
  }
  for(int idx=t; idx<40*100; idx+=256) Ks[idx] = W[W_KEYS1 + idx];
  __syncthreads();

  if(t < 32){ float s=0.f; for(int f=0;f<100;f++){ float v=Qs[t*104+f]; s+=v*v; } qsq_s[t]=s; }
  for(int idx=t; idx<32*40; idx+=256){
    int n = idx/40, c = idx - n*40;
    float a = 0.f;
    for(int f=0;f<100;f++) a += Qs[n*104+f]*Ks[c*100+f];
    QKs[idx] = a;
  }
  __syncthreads();

  if(t < 32){
    float wsum[8];
    #pragma unroll
    for(int k=0;k<8;k++) wsum[k]=0.f;
    for(int h=0;h<HEADS;h++){
      float cw = W[W_CONVW1 + h];
      float c[8]; float rs=0.f;
      #pragma unroll
      for(int k=0;k<8;k++){
        float d2 = qsq_s[t] + ksq[h*8+k] - 2.f*QKs[t*40 + h*8+k];
        d2 = fmaxf(d2, 1e-12f);
        float cc = 1.f/(1.f+d2);
        c[k]=cc; rs+=cc;
      }
      float sc = cw/fmaxf(rs, 1e-20f);
      #pragma unroll
      for(int k=0;k<8;k++) wsum[k] += c[k]*sc;
    }
    float mx = wsum[0];
    #pragma unroll
    for(int k=1;k<8;k++) mx = fmaxf(mx, wsum[k]);
    float se=0.f;
    #pragma unroll
    for(int k=0;k<8;k++){ float e=__expf(wsum[k]-mx); wsum[k]=e; se+=e; }
    float inv = 1.f/se;
    #pragma unroll
    for(int k=0;k<8;k++) Cs[t*8+k] = wsum[k]*inv;
  }
  __syncthreads();
  if(t < 8){ float s=0.f; for(int n=0;n<32;n++) s += Cs[n*8+t]; cn_s[t]=s+EPSF; }
  __syncthreads();
  if(t < 32){
    float p=0.f;
    #pragma unroll
    for(int k=0;k<8;k++){ float sv=Cs[t*8+k]; p += sv*sv/cn_s[k]; }
    pn_s[t]=p+EPSF;
  }
  __syncthreads();

  float acc;
  {
    int n = t>>3, k = t&7;
    float sv = Cs[t];
    float P = sv*sv/(cn_s[k]*pn_s[n]);
    acc = (t < 256) ? P*(__logf(P+EPSF) - __logf(sv+EPSF)) : 0.f;
  }
  #pragma unroll
  for(int off=32; off>0; off>>=1) acc += __shfl_down(acc, off);
  if((t&63)==0) red_s[t>>6] = acc;

  for(int idx=t; idx<8*100; idx+=256){
    int k = idx/100, f = idx - k*100;
    float a=0.f;
    for(int n=0;n<32;n++) a += Cs[n*8+k]*Qs[n*104+f];
    Vs[idx] = a;
  }
  __syncthreads();

  if(t==0) atomicAdd(klacc, 100.f*(red_s[0]+red_s[1]+red_s[2]+red_s[3]));

  for(int idx=t; idx<8*100; idx+=256){
    int k = idx/100, m = idx - k*100;
    float a = W[W_LINB1 + m];
    for(int f=0;f<100;f++) a += Vs[k*100+f]*W[W_LINW1 + f*100 + m];
    mq2[(size_t)b*800 + idx] = (a>0.f) ? a : 0.01f*a;
  }
}

// ---------------- head ----------------
__global__ __launch_bounds__(128) void k_final(const float* __restrict__ mq2,
                                               const float* __restrict__ W,
                                               const int* __restrict__ flag,
                                               void* __restrict__ out){
  __shared__ float h_s[100];
  __shared__ float hid_s[50];
  const int b = blockIdx.x, t = threadIdx.x;
  if(t < 100){
    float s=0.f;
    #pragma unroll
    for(int k=0;k<8;k++) s += mq2[(size_t)b*800 + k*100 + t];
    h_s[t] = s*0.125f;
  }
  __syncthreads();
  if(t < 50){
    float a = W[W_MLPB1 + t];
    for(int f=0;f<100;f++) a += h_s[f]*W[W_MLPW1 + f*50 + t];
    hid_s[t] = (a>0.f) ? a : 0.01f*a;
  }
  __syncthreads();
  if(t < 12){
    float a = W[W_MLPB2 + t];
    #pragma unroll
    for(int j=0;j<50;j++) a += hid_s[j]*W[W_MLPW2 + j*12 + t];
    if(flag[0]) ((__hip_bfloat16*)out)[b*12+t] = __float2bfloat16(a);
    else        ((float*)out)[b*12+t] = a;
  }
}

__global__ void k_klout(const float* __restrict__ kl, const int* __restrict__ flag,
                        void* __restrict__ out){
  if(blockIdx.x==0 && threadIdx.x==0){
    float v = (kl[0]+kl[1]) * (1.f/65536.f);
    if(flag[0]) ((__hip_bfloat16*)out)[3072] = __float2bfloat16(v);
    else        ((float*)out)[3072] = v;
  }
}

// ---------------- launch ----------------
extern "C" void kernel_launch(void* const* d_in, const int* in_sizes, int n_in,
                              void* d_out, int out_size, void* d_ws, size_t ws_size,
                              hipStream_t stream) {
  (void)in_sizes; (void)n_in; (void)out_size; (void)ws_size;
  const void* x   = d_in[0];
  const int*  ei  = (const int*)d_in[1];
  const int* src = ei;
  const int* dst = ei + NEDGE;

  WPtrs wp;
  for(int i=0;i<20;i++) wp.p[i] = d_in[3+i];

  char* w = (char*)d_ws;
  int*    deg    = (int*)   (w + OFF_DEG);
  int*    cursor = (int*)   (w + OFF_CURSOR);
  int*    offs   = (int*)   (w + OFF_OFFS);
  double* bnsum  = (double*)(w + OFF_BNSUM);
  double* bnsq   = (double*)(w + OFF_BNSQ);
  float*  scale  = (float*) (w + OFF_SCALE);
  float*  shift  = (float*) (w + OFF_SHIFT);
  float*  ksq0   = (float*) (w + OFF_KSQ0);
  float*  ksq1   = (float*) (w + OFF_KSQ1);
  float*  kl     = (float*) (w + OFF_KL);
  int*    flag   = (int*)   (w + OFF_FLAG);
  float*  Wc     = (float*) (w + OFF_W);
  int*    csr    = (int*)   (w + OFF_CSR);
  float*  regA   = (float*) (w + OFF_A);
  float*  regB   = (float*) (w + OFF_B);
  float*  qkbuf  = (float*) (w + OFF_QK);
  float*  xc     = (float*) (w + OFF_C);
  float*  mq1    = (float*) (w + OFF_MQ1);
  float*  mq2    = (float*) (w + OFF_MQ2);

  float* aggr = regA;       // aggr64 (16MB) then aggr128 (32MB)
  float* qv   = regB;       // lin1 out (32MB)
  float* qbn  = regA;       // lin2 writes in place over aggr128
  float* qf   = regA;       // bnapply in place

  k_detect <<<1,      64, 0, stream>>>((const unsigned short*)x, flag);
  k_init   <<<256,   256, 0, stream>>>(deg, cursor, (unsigned long long*)bnsum, (unsigned long long*)bnsq, kl);
  k_cvtx   <<<16384, 256, 0, stream>>>(x, flag, xc);
  k_cvtw   <<<402,   256, 0, stream>>>(wp, flag, Wc);
  k_count  <<<4096,  256, 0, stream>>>(dst, deg);
  k_scan   <<<1,    1024, 0, stream>>>(deg, offs);
  k_fill   <<<4096,  256, 0, stream>>>(src, dst, offs, cursor, csr);
  k_aggr64 <<<16384, 256, 0, stream>>>(xc, offs, deg, csr, aggr);
  k_lin1   <<<65536, 128, 0, stream>>>(aggr, xc, Wc, qv);
  k_aggr128<<<16384, 256, 0, stream>>>(qv, offs, deg, csr, aggr);
  k_lin2   <<<65536, 128, 0, stream>>>(aggr, qv, Wc, qbn);
  k_bnstats<<<512,   128, 0, stream>>>(qbn, bnsum, bnsq);
  k_bnfin  <<<1,     256, 0, stream>>>(bnsum, bnsq, Wc, scale, shift, ksq0, ksq1);
  k_bnapply<<<32768, 256, 0, stream>>>(qbn, scale, shift, qf);
  k_qk     <<<2048,  256, 0, stream>>>(qf, Wc, qkbuf);
  k_memconv0<<<256,  256, 0, stream>>>(qkbuf, qf, Wc, ksq0, mq1, kl);
  k_memconv1<<<256,  256, 0, stream>>>(mq1, Wc, ksq1, mq2, kl+1);
  k_final  <<<256,   128, 0, stream>>>(mq2, Wc, flag, d_out);
  k_klout  <<<1,      64, 0, stream>>>(kl, flag, d_out);
}

// Round 4
// 728.512 us; speedup vs baseline: 1.5934x; 1.5934x over previous
//
#include <hip/hip_runtime.h>
#include <hip/hip_bf16.h>

#define NTOT   65536
#define NEDGE  1048576
#define HEADS  5
#define K1     32
#define K2     8
#define MEMH   100
#define EPSF   1e-8f

// ---- workspace layout (bytes) ----
#define OFF_DEG     0x0000000
#define OFF_CURSOR  0x0040000
#define OFF_OFFS    0x0080000
#define OFF_BNSUM   0x00C0000
#define OFF_BNSQ    0x00C0400
#define OFF_SCALE   0x00C0800
#define OFF_SHIFT   0x00C0A00
#define OFF_KSQ0    0x00C0C00
#define OFF_KSQ1    0x00C0E80
#define OFF_KL      0x00C0F40
#define OFF_FLAG    0x00C0F60
#define OFF_W       0x00C1000   // canonical f32 weights
#define OFF_CSR     0x0140000   // 4MB
#define OFF_A       0x0540000   // 32MB: aggr64/aggr128 -> qbn -> qf (in-place chain)
#define OFF_B       0x2540000   // 32MB: qv ; later qk (40MB while qv dead)
#define OFF_QK      0x2540000
#define OFF_C       0x4540000   // 16MB: xc
#define OFF_MQ1     0x4D40000
#define OFF_MQ2     0x5060000

// ---- canonical weight offsets (floats) ----
#define W_WREL0  0
#define W_BREL0  8192
#define W_WROOT0 8320
#define W_WREL1  16512
#define W_BREL1  32896
#define W_WROOT1 33024
#define W_GAMMA  49408
#define W_BETA   49536
#define W_KEYS0  49664
#define W_CONVW0 70144
#define W_LINW0  70149
#define W_LINB0  82949
#define W_KEYS1  83049
#define W_CONVW1 87049
#define W_LINW1  87054
#define W_LINB1  97054
#define W_MLPW1  97154
#define W_MLPB1  102154
#define W_MLPW2  102204
#define W_MLPB2  102804
#define W_TOTAL  102816

__device__ __forceinline__ float bf2f(unsigned short u){
  union { unsigned int i; float f; } v; v.i = ((unsigned int)u) << 16; return v.f;
}

__device__ const int g_seg[21] = {0,8192,8320,16512,32896,33024,49408,49536,49664,
                                  70144,70149,82949,83049,87049,87054,97054,97154,
                                  102154,102204,102804,102816};
struct WPtrs { const void* p[20]; };

// ---------------- dtype probe ----------------
__global__ void k_detect(const unsigned short* __restrict__ xr, int* flag){
  int t = threadIdx.x & 63;
  unsigned short u = xr[2*t];
  int e = (u >> 7) & 0xFF;
  bool plaus = (u != 0) && (e >= 115) && (e <= 135);
  unsigned long long m = __ballot(plaus);
  if(t == 0) flag[0] = (__popcll(m) >= 48) ? 1 : 0;
}

__global__ __launch_bounds__(256) void k_cvtx(const void* __restrict__ xin,
                                              const int* __restrict__ flag,
                                              float* __restrict__ xout){
  int i = blockIdx.x*256 + threadIdx.x;          // NTOT*64
  if(flag[0]) xout[i] = bf2f(((const unsigned short*)xin)[i]);
  else        xout[i] = ((const float*)xin)[i];
}

__global__ __launch_bounds__(256) void k_cvtw(WPtrs wp, const int* __restrict__ flag,
                                              float* __restrict__ wout){
  int i = blockIdx.x*256 + threadIdx.x;
  if(i >= W_TOTAL) return;
  int s = 0;
  #pragma unroll
  for(int k=0;k<20;k++) if(i >= g_seg[k+1]) s = k+1;
  int j = i - g_seg[s];
  const void* src = wp.p[s];
  wout[i] = flag[0] ? bf2f(((const unsigned short*)src)[j]) : ((const float*)src)[j];
}

// ---------------- init / CSR build ----------------
__global__ __launch_bounds__(256) void k_init(int* deg, int* cursor,
                                              unsigned long long* bnsum,
                                              unsigned long long* bnsq, float* kl){
  int i = blockIdx.x*256 + threadIdx.x;
  if(i < NTOT){ deg[i]=0; cursor[i]=0; }
  if(i < 128){ bnsum[i]=0ULL; bnsq[i]=0ULL; }
  if(i < 2) kl[i]=0.f;
}

__global__ __launch_bounds__(256) void k_count(const int* __restrict__ dst, int* deg){
  int e = blockIdx.x*256 + threadIdx.x;
  atomicAdd(&deg[dst[e]], 1);
}

__global__ __launch_bounds__(1024) void k_scan(const int* __restrict__ deg, int* __restrict__ offs){
  __shared__ int ts[1024];
  const int t = threadIdx.x;
  const int base = t*64;
  int s = 0;
  for(int i=0;i<64;i++) s += deg[base+i];
  ts[t] = s; __syncthreads();
  for(int off=1; off<1024; off<<=1){
    int v = (t>=off) ? ts[t-off] : 0;
    __syncthreads();
    ts[t] += v;
    __syncthreads();
  }
  int run = (t==0) ? 0 : ts[t-1];
  for(int i=0;i<64;i++){ offs[base+i]=run; run += deg[base+i]; }
}

__global__ __launch_bounds__(256) void k_fill(const int* __restrict__ src, const int* __restrict__ dst,
                                              const int* __restrict__ offs, int* cursor, int* __restrict__ csr){
  int e = blockIdx.x*256 + threadIdx.x;
  int d = dst[e];
  int p = atomicAdd(&cursor[d], 1);
  csr[offs[d] + p] = src[e];
}

// ---------------- graph aggregation (ILP-unrolled gathers) ----------------
// 4 edges per wave; lane: sub=lane>>4 edge slot, fl=lane&15 feature quad
__global__ __launch_bounds__(256) void k_aggr64(const float* __restrict__ xc,
                                                const int* __restrict__ offs, const int* __restrict__ deg,
                                                const int* __restrict__ csr, float* __restrict__ aggr){
  const int wid  = (blockIdx.x*256 + threadIdx.x) >> 6;
  const int lane = threadIdx.x & 63;
  const int sub = lane >> 4, fl = lane & 15;
  const int beg = offs[wid], n = deg[wid];
  float4 acc = {0.f,0.f,0.f,0.f};
  int i = 0;
  for(; i+32 <= n; i += 32){
    int s[8];
    #pragma unroll
    for(int j=0;j<8;j++) s[j] = csr[beg + i + 4*j + sub];
    #pragma unroll
    for(int j=0;j<8;j++){
      float4 v = *(const float4*)(xc + (size_t)s[j]*64 + fl*4);
      acc.x += v.x; acc.y += v.y; acc.z += v.z; acc.w += v.w;
    }
  }
  for(; i < n; i += 4){
    if(i + sub < n){
      int s = csr[beg + i + sub];
      float4 v = *(const float4*)(xc + (size_t)s*64 + fl*4);
      acc.x += v.x; acc.y += v.y; acc.z += v.z; acc.w += v.w;
    }
  }
  acc.x += __shfl_xor(acc.x, 16); acc.y += __shfl_xor(acc.y, 16);
  acc.z += __shfl_xor(acc.z, 16); acc.w += __shfl_xor(acc.w, 16);
  acc.x += __shfl_xor(acc.x, 32); acc.y += __shfl_xor(acc.y, 32);
  acc.z += __shfl_xor(acc.z, 32); acc.w += __shfl_xor(acc.w, 32);
  if(sub == 0) *(float4*)(aggr + (size_t)wid*64 + fl*4) = acc;
}

// 2 edges per wave; sub=lane>>5, fl=lane&31 feature quad
__global__ __launch_bounds__(256) void k_aggr128(const float* __restrict__ q,
                                                 const int* __restrict__ offs, const int* __restrict__ deg,
                                                 const int* __restrict__ csr, float* __restrict__ aggr){
  const int wid  = (blockIdx.x*256 + threadIdx.x) >> 6;
  const int lane = threadIdx.x & 63;
  const int sub = lane >> 5, fl = lane & 31;
  const int beg = offs[wid], n = deg[wid];
  float4 acc = {0.f,0.f,0.f,0.f};
  int i = 0;
  for(; i+16 <= n; i += 16){
    int s[8];
    #pragma unroll
    for(int j=0;j<8;j++) s[j] = csr[beg + i + 2*j + sub];
    #pragma unroll
    for(int j=0;j<8;j++){
      float4 v = *(const float4*)(q + (size_t)s[j]*128 + fl*4);
      acc.x += v.x; acc.y += v.y; acc.z += v.z; acc.w += v.w;
    }
  }
  for(; i < n; i += 2){
    if(i + sub < n){
      int s = csr[beg + i + sub];
      float4 v = *(const float4*)(q + (size_t)s*128 + fl*4);
      acc.x += v.x; acc.y += v.y; acc.z += v.z; acc.w += v.w;
    }
  }
  acc.x += __shfl_xor(acc.x, 32); acc.y += __shfl_xor(acc.y, 32);
  acc.z += __shfl_xor(acc.z, 32); acc.w += __shfl_xor(acc.w, 32);
  if(sub == 0) *(float4*)(aggr + (size_t)wid*128 + fl*4) = acc;
}

// ---------------- lin1: 64-row tile, thread = 8 rows x 4 cols ----------------
__global__ __launch_bounds__(256) void k_lin1(const float* __restrict__ aggr, const float* __restrict__ xc,
                                              const float* __restrict__ W, float* __restrict__ qout){
  __shared__ float As[64*68];   // [f][r], stride 68 keeps 16B align + breaks bank stride
  __shared__ float Xs[64*68];
  const int r0b = blockIdx.x*64;
  const int t = threadIdx.x;
  for(int idx=t; idx<64*64; idx+=256){
    int r = idx >> 6, f = idx & 63;
    As[f*68 + r] = aggr[(size_t)(r0b+r)*64 + f];
    Xs[f*68 + r] = xc  [(size_t)(r0b+r)*64 + f];
  }
  __syncthreads();
  const int j4 = (t & 31)*4;
  const int r0 = (t >> 5)*8;
  float acc[8][4];
  #pragma unroll
  for(int r=0;r<8;r++){ acc[r][0]=0;acc[r][1]=0;acc[r][2]=0;acc[r][3]=0; }
  for(int f=0; f<64; f++){
    float4 wr = *(const float4*)(W + W_WREL0  + f*128 + j4);
    float4 wo = *(const float4*)(W + W_WROOT0 + f*128 + j4);
    float4 a0 = *(const float4*)(As + f*68 + r0);
    float4 a1 = *(const float4*)(As + f*68 + r0 + 4);
    float4 x0 = *(const float4*)(Xs + f*68 + r0);
    float4 x1 = *(const float4*)(Xs + f*68 + r0 + 4);
    float ar[8] = {a0.x,a0.y,a0.z,a0.w,a1.x,a1.y,a1.z,a1.w};
    float xr[8] = {x0.x,x0.y,x0.z,x0.w,x1.x,x1.y,x1.z,x1.w};
    #pragma unroll
    for(int r=0;r<8;r++){
      acc[r][0] += ar[r]*wr.x + xr[r]*wo.x;
      acc[r][1] += ar[r]*wr.y + xr[r]*wo.y;
      acc[r][2] += ar[r]*wr.z + xr[r]*wo.z;
      acc[r][3] += ar[r]*wr.w + xr[r]*wo.w;
    }
  }
  float4 bi = *(const float4*)(W + W_BREL0 + j4);
  #pragma unroll
  for(int r=0;r<8;r++){
    float4 o;
    o.x = fmaxf(acc[r][0]+bi.x, 0.f);
    o.y = fmaxf(acc[r][1]+bi.y, 0.f);
    o.z = fmaxf(acc[r][2]+bi.z, 0.f);
    o.w = fmaxf(acc[r][3]+bi.w, 0.f);
    *(float4*)(qout + (size_t)(r0b+r0+r)*128 + j4) = o;
  }
}

// ---------------- lin2: 32-row tile, thread = 4 rows x 4 cols (in-place safe) ----
__global__ __launch_bounds__(256) void k_lin2(const float* __restrict__ aggr, const float* __restrict__ q,
                                              const float* __restrict__ W, float* __restrict__ qout){
  __shared__ float As[128*36];
  __shared__ float Xs[128*36];
  const int r0b = blockIdx.x*32;
  const int t = threadIdx.x;
  for(int idx=t; idx<32*128; idx+=256){
    int r = idx >> 7, f = idx & 127;
    As[f*36 + r] = aggr[(size_t)(r0b+r)*128 + f];
    Xs[f*36 + r] = q   [(size_t)(r0b+r)*128 + f];
  }
  __syncthreads();
  const int j4 = (t & 31)*4;
  const int r0 = (t >> 5)*4;
  float acc[4][4];
  #pragma unroll
  for(int r=0;r<4;r++){ acc[r][0]=0;acc[r][1]=0;acc[r][2]=0;acc[r][3]=0; }
  for(int f=0; f<128; f++){
    float4 wr = *(const float4*)(W + W_WREL1  + f*128 + j4);
    float4 wo = *(const float4*)(W + W_WROOT1 + f*128 + j4);
    float4 a0 = *(const float4*)(As + f*36 + r0);
    float4 x0 = *(const float4*)(Xs + f*36 + r0);
    float ar[4] = {a0.x,a0.y,a0.z,a0.w};
    float xr[4] = {x0.x,x0.y,x0.z,x0.w};
    #pragma unroll
    for(int r=0;r<4;r++){
      acc[r][0] += ar[r]*wr.x + xr[r]*wo.x;
      acc[r][1] += ar[r]*wr.y + xr[r]*wo.y;
      acc[r][2] += ar[r]*wr.z + xr[r]*wo.z;
      acc[r][3] += ar[r]*wr.w + xr[r]*wo.w;
    }
  }
  float4 bi = *(const float4*)(W + W_BREL1 + j4);
  #pragma unroll
  for(int r=0;r<4;r++){
    float4 o;
    o.x = fmaxf(acc[r][0]+bi.x, 0.f);
    o.y = fmaxf(acc[r][1]+bi.y, 0.f);
    o.z = fmaxf(acc[r][2]+bi.z, 0.f);
    o.w = fmaxf(acc[r][3]+bi.w, 0.f);
    *(float4*)(qout + (size_t)(r0b+r0+r)*128 + j4) = o;
  }
}

// ---------------- batchnorm ----------------
__global__ __launch_bounds__(128) void k_bnstats(const float* __restrict__ qbn, double* bnsum, double* bnsq){
  const int j = threadIdx.x;
  const int r0 = blockIdx.x*128;
  float s=0.f, s2=0.f;
  for(int r=0;r<128;r++){ float v = qbn[(size_t)(r0+r)*128 + j]; s += v; s2 += v*v; }
  atomicAdd(&bnsum[j], (double)s);
  atomicAdd(&bnsq[j], (double)s2);
}

__global__ __launch_bounds__(256) void k_bnfin(const double* __restrict__ bnsum, const double* __restrict__ bnsq,
                                               const float* __restrict__ W,
                                               float* scale, float* shift, float* ksq0, float* ksq1){
  const int t = threadIdx.x;
  if(t < 128){
    double mu  = bnsum[t] / (double)NTOT;
    double var = bnsq[t] / (double)NTOT - mu*mu;
    if(var < 0.0) var = 0.0;
    float sc = W[W_GAMMA + t] * rsqrtf((float)var + 1e-5f);
    scale[t] = sc;
    shift[t] = W[W_BETA + t] - (float)mu * sc;
  }
  if(t < HEADS*K1){
    float s=0.f;
    for(int f=0;f<128;f++){ float v = W[W_KEYS0 + t*128 + f]; s += v*v; }
    ksq0[t] = s;
  }
  if(t < HEADS*K2){
    float s=0.f;
    for(int f=0;f<100;f++){ float v = W[W_KEYS1 + t*100 + f]; s += v*v; }
    ksq1[t] = s;
  }
}

__global__ __launch_bounds__(256) void k_bnapply(const float* __restrict__ qbn, const float* __restrict__ scale,
                                                 const float* __restrict__ shift, float* __restrict__ qf){
  int i = blockIdx.x*256 + threadIdx.x;   // NTOT*128
  int f = i & 127;
  qf[i] = qbn[i]*scale[f] + shift[f];
}

// ---------------- qk: 32 rows/block, f-vectorized, K staged in 16-key chunks ----
__global__ __launch_bounds__(256) void k_qk(const float* __restrict__ qf,
                                            const float* __restrict__ W,
                                            float* __restrict__ qk){
  __shared__ float Qs[32*132];
  __shared__ float Ks[16*132];
  const int r0 = blockIdx.x*32;
  const int t = threadIdx.x;
  for(int idx=t; idx<32*128; idx+=256){
    int r = idx>>7, f = idx&127;
    Qs[r*132+f] = qf[(size_t)(r0+r)*128+f];
  }
  const int r = t>>3, g = t&7;
  for(int c=0; c<10; c++){
    __syncthreads();
    for(int idx=t; idx<16*128; idx+=256){
      int kk = idx>>7, f = idx&127;
      Ks[kk*132+f] = W[W_KEYS0 + (c*16+kk)*128 + f];
    }
    __syncthreads();
    float a0=0.f, a1=0.f;
    #pragma unroll 8
    for(int f=0; f<128; f+=4){
      float4 qv = *(const float4*)(Qs + r*132 + f);
      float4 ka = *(const float4*)(Ks + g*132 + f);
      float4 kb = *(const float4*)(Ks + (g+8)*132 + f);
      a0 += qv.x*ka.x + qv.y*ka.y + qv.z*ka.z + qv.w*ka.w;
      a1 += qv.x*kb.x + qv.y*kb.y + qv.z*kb.z + qv.w*kb.w;
    }
    qk[(size_t)(r0+r)*160 + c*16 + g]     = a0;
    qk[(size_t)(r0+r)*160 + c*16 + g + 8] = a1;
  }
}

// ---------------- mem conv 0 (block per batch) ----------------
__global__ __launch_bounds__(256) void k_memconv0(
    const float* __restrict__ qk, const float* __restrict__ qf,
    const float* __restrict__ W, const float* __restrict__ ksq,
    float* __restrict__ mq1, float* __restrict__ klacc)
{
  __shared__ float Cs[256*36];
  __shared__ float Vs[32*132];
  __shared__ float cn_s[32];
  __shared__ float pn_s[256];
  __shared__ float red_s[4];
  const int b = blockIdx.x, t = threadIdx.x;

  const float4* qrow = (const float4*)(qf + (size_t)(b*256 + t)*128);
  float qsq = 0.f;
  #pragma unroll 8
  for(int jj=0; jj<32; jj++){
    float4 v = qrow[jj];
    qsq += v.x*v.x + v.y*v.y + v.z*v.z + v.w*v.w;
  }

  const float* qkrow = qk + (size_t)(b*256 + t)*160;
  float wsum[32];
  #pragma unroll
  for(int k=0;k<32;k++) wsum[k]=0.f;
  for(int h=0; h<HEADS; h++){
    float cw = W[W_CONVW0 + h];
    float c[32]; float rs = 0.f;
    #pragma unroll
    for(int k=0;k<32;k++){
      float d2 = qsq + ksq[h*32+k] - 2.f*qkrow[h*32+k];
      d2 = fmaxf(d2, 1e-12f);
      float cc = 1.f/(1.f+d2);
      c[k]=cc; rs += cc;
    }
    float sc = cw/fmaxf(rs, 1e-20f);
    #pragma unroll
    for(int k=0;k<32;k++) wsum[k] += c[k]*sc;
  }
  float mx = wsum[0];
  #pragma unroll
  for(int k=1;k<32;k++) mx = fmaxf(mx, wsum[k]);
  float se = 0.f;
  #pragma unroll
  for(int k=0;k<32;k++){ float e = __expf(wsum[k]-mx); wsum[k]=e; se+=e; }
  float inv = 1.f/se;
  #pragma unroll
  for(int k=0;k<32;k++) Cs[t*36+k] = wsum[k]*inv;
  __syncthreads();

  if(t < 32){ float s=0.f; for(int n=0;n<256;n++) s += Cs[n*36+t]; cn_s[t] = s + EPSF; }
  __syncthreads();
  {
    float p = 0.f;
    #pragma unroll
    for(int k=0;k<32;k++){ float sv = Cs[t*36+k]; p += sv*sv/cn_s[k]; }
    pn_s[t] = p + EPSF;
  }
  __syncthreads();

  float acc = 0.f;
  for(int idx=t; idx<256*32; idx+=256){
    int n = idx>>5, k = idx&31;
    float sv = Cs[n*36+k];
    float P = sv*sv/(cn_s[k]*pn_s[n]);
    acc += P*(__logf(P+EPSF) - __logf(sv+EPSF));
  }
  #pragma unroll
  for(int off=32; off>0; off>>=1) acc += __shfl_down(acc, off);
  if((t&63)==0) red_s[t>>6] = acc;

  // V = C^T Q : thread = 4 k's x 4 f's (8x less global dup than 16-f layout)
  {
    const int k4 = (t&7)*4;
    const int f0 = (t>>3)*4;
    float vacc[4][4];
    #pragma unroll
    for(int a=0;a<4;a++){ vacc[a][0]=0;vacc[a][1]=0;vacc[a][2]=0;vacc[a][3]=0; }
    const float* qbase = qf + (size_t)b*256*128 + f0;
    for(int n=0;n<256;n++){
      float4 cv = *(const float4*)(Cs + n*36 + k4);
      float4 u  = *(const float4*)(qbase + (size_t)n*128);
      float cr[4] = {cv.x,cv.y,cv.z,cv.w};
      #pragma unroll
      for(int a=0;a<4;a++){
        vacc[a][0] += cr[a]*u.x;
        vacc[a][1] += cr[a]*u.y;
        vacc[a][2] += cr[a]*u.z;
        vacc[a][3] += cr[a]*u.w;
      }
    }
    #pragma unroll
    for(int a=0;a<4;a++){
      Vs[(k4+a)*132 + f0 + 0] = vacc[a][0];
      Vs[(k4+a)*132 + f0 + 1] = vacc[a][1];
      Vs[(k4+a)*132 + f0 + 2] = vacc[a][2];
      Vs[(k4+a)*132 + f0 + 3] = vacc[a][3];
    }
  }
  __syncthreads();

  if(t==0) atomicAdd(klacc, 100.f*(red_s[0]+red_s[1]+red_s[2]+red_s[3]));

  for(int idx=t; idx<K1*MEMH; idx+=256){
    int k = idx/100, m = idx - k*100;
    float a = W[W_LINB0 + m];
    for(int f=0; f<128; f++) a += Vs[k*132+f]*W[W_LINW0 + f*100 + m];
    mq1[(size_t)(b*32+k)*100 + m] = (a>0.f) ? a : 0.01f*a;
  }
}

// ---------------- mem conv 1 ----------------
__global__ __launch_bounds__(256) void k_memconv1(
    const float* __restrict__ mq1, const float* __restrict__ W,
    const float* __restrict__ ksq, float* __restrict__ mq2, float* __restrict__ klacc)
{
  __shared__ float Qs[32*104];
  __shared__ float Ks[40*100];
  __shared__ float QKs[32*40];
  __shared__ float Cs[32*8];
  __shared__ float cn_s[8];
  __shared__ float pn_s[32];
  __shared__ float qsq_s[32];
  __shared__ float Vs[8*100];
  __shared__ float red_s[4];
  const int b = blockIdx.x, t = threadIdx.x;

  for(int idx=t; idx<32*100; idx+=256){
    int n = idx/100, f = idx - n*100;
    Qs[n*104+f] = mq1[(size_t)b*3200 + idx];
  }
  for(int idx=t; idx<40*100; idx+=256) Ks[idx] = W[W_KEYS1 + idx];
  __syncthreads();

  if(t < 32){ float s=0.f; for(int f=0;f<100;f++){ float v=Qs[t*104+f]; s+=v*v; } qsq_s[t]=s; }
  for(int idx=t; idx<32*40; idx+=256){
    int n = idx/40, c = idx - n*40;
    float a = 0.f;
    for(int f=0;f<100;f++) a += Qs[n*104+f]*Ks[c*100+f];
    QKs[idx] = a;
  }
  __syncthreads();

  if(t < 32){
    float wsum[8];
    #pragma unroll
    for(int k=0;k<8;k++) wsum[k]=0.f;
    for(int h=0;h<HEADS;h++){
      float cw = W[W_CONVW1 + h];
      float c[8]; float rs=0.f;
      #pragma unroll
      for(int k=0;k<8;k++){
        float d2 = qsq_s[t] + ksq[h*8+k] - 2.f*QKs[t*40 + h*8+k];
        d2 = fmaxf(d2, 1e-12f);
        float cc = 1.f/(1.f+d2);
        c[k]=cc; rs+=cc;
      }
      float sc = cw/fmaxf(rs, 1e-20f);
      #pragma unroll
      for(int k=0;k<8;k++) wsum[k] += c[k]*sc;
    }
    float mx = wsum[0];
    #pragma unroll
    for(int k=1;k<8;k++) mx = fmaxf(mx, wsum[k]);
    float se=0.f;
    #pragma unroll
    for(int k=0;k<8;k++){ float e=__expf(wsum[k]-mx); wsum[k]=e; se+=e; }
    float inv = 1.f/se;
    #pragma unroll
    for(int k=0;k<8;k++) Cs[t*8+k] = wsum[k]*inv;
  }
  __syncthreads();
  if(t < 8){ float s=0.f; for(int n=0;n<32;n++) s += Cs[n*8+t]; cn_s[t]=s+EPSF; }
  __syncthreads();
  if(t < 32){
    float p=0.f;
    #pragma unroll
    for(int k=0;k<8;k++){ float sv=Cs[t*8+k]; p += sv*sv/cn_s[k]; }
    pn_s[t]=p+EPSF;
  }
  __syncthreads();

  float acc;
  {
    int n = t>>3, k = t&7;
    float sv = Cs[t];
    float P = sv*sv/(cn_s[k]*pn_s[n]);
    acc = P*(__logf(P+EPSF) - __logf(sv+EPSF));
  }
  #pragma unroll
  for(int off=32; off>0; off>>=1) acc += __shfl_down(acc, off);
  if((t&63)==0) red_s[t>>6] = acc;

  for(int idx=t; idx<8*100; idx+=256){
    int k = idx/100, f = idx - k*100;
    float a=0.f;
    for(int n=0;n<32;n++) a += Cs[n*8+k]*Qs[n*104+f];
    Vs[idx] = a;
  }
  __syncthreads();

  if(t==0) atomicAdd(klacc, 100.f*(red_s[0]+red_s[1]+red_s[2]+red_s[3]));

  for(int idx=t; idx<8*100; idx+=256){
    int k = idx/100, m = idx - k*100;
    float a = W[W_LINB1 + m];
    for(int f=0;f<100;f++) a += Vs[k*100+f]*W[W_LINW1 + f*100 + m];
    mq2[(size_t)b*800 + idx] = (a>0.f) ? a : 0.01f*a;
  }
}

// ---------------- head ----------------
__global__ __launch_bounds__(128) void k_final(const float* __restrict__ mq2,
                                               const float* __restrict__ W,
                                               const int* __restrict__ flag,
                                               void* __restrict__ out){
  __shared__ float h_s[100];
  __shared__ float hid_s[50];
  const int b = blockIdx.x, t = threadIdx.x;
  if(t < 100){
    float s=0.f;
    #pragma unroll
    for(int k=0;k<8;k++) s += mq2[(size_t)b*800 + k*100 + t];
    h_s[t] = s*0.125f;
  }
  __syncthreads();
  if(t < 50){
    float a = W[W_MLPB1 + t];
    for(int f=0;f<100;f++) a += h_s[f]*W[W_MLPW1 + f*50 + t];
    hid_s[t] = (a>0.f) ? a : 0.01f*a;
  }
  __syncthreads();
  if(t < 12){
    float a = W[W_MLPB2 + t];
    #pragma unroll
    for(int j=0;j<50;j++) a += hid_s[j]*W[W_MLPW2 + j*12 + t];
    if(flag[0]) ((__hip_bfloat16*)out)[b*12+t] = __float2bfloat16(a);
    else        ((float*)out)[b*12+t] = a;
  }
}

__global__ void k_klout(const float* __restrict__ kl, const int* __restrict__ flag,
                        void* __restrict__ out){
  if(blockIdx.x==0 && threadIdx.x==0){
    float v = (kl[0]+kl[1]) * (1.f/65536.f);
    if(flag[0]) ((__hip_bfloat16*)out)[3072] = __float2bfloat16(v);
    else        ((float*)out)[3072] = v;
  }
}

// ---------------- launch ----------------
extern "C" void kernel_launch(void* const* d_in, const int* in_sizes, int n_in,
                              void* d_out, int out_size, void* d_ws, size_t ws_size,
                              hipStream_t stream) {
  (void)in_sizes; (void)n_in; (void)out_size; (void)ws_size;
  const void* x   = d_in[0];
  const int*  ei  = (const int*)d_in[1];
  const int* src = ei;
  const int* dst = ei + NEDGE;

  WPtrs wp;
  for(int i=0;i<20;i++) wp.p[i] = d_in[3+i];

  char* w = (char*)d_ws;
  int*    deg    = (int*)   (w + OFF_DEG);
  int*    cursor = (int*)   (w + OFF_CURSOR);
  int*    offs   = (int*)   (w + OFF_OFFS);
  double* bnsum  = (double*)(w + OFF_BNSUM);
  double* bnsq   = (double*)(w + OFF_BNSQ);
  float*  scale  = (float*) (w + OFF_SCALE);
  float*  shift  = (float*) (w + OFF_SHIFT);
  float*  ksq0   = (float*) (w + OFF_KSQ0);
  float*  ksq1   = (float*) (w + OFF_KSQ1);
  float*  kl     = (float*) (w + OFF_KL);
  int*    flag   = (int*)   (w + OFF_FLAG);
  float*  Wc     = (float*) (w + OFF_W);
  int*    csr    = (int*)   (w + OFF_CSR);
  float*  regA   = (float*) (w + OFF_A);
  float*  regB   = (float*) (w + OFF_B);
  float*  qkbuf  = (float*) (w + OFF_QK);
  float*  xc     = (float*) (w + OFF_C);
  float*  mq1    = (float*) (w + OFF_MQ1);
  float*  mq2    = (float*) (w + OFF_MQ2);

  float* aggr = regA;       // aggr64 (16MB) then aggr128 (32MB)
  float* qv   = regB;       // lin1 out
  float* qbn  = regA;       // lin2 in place over aggr128 rows
  float* qf   = regA;       // bnapply in place

  k_detect <<<1,      64, 0, stream>>>((const unsigned short*)x, flag);
  k_init   <<<256,   256, 0, stream>>>(deg, cursor, (unsigned long long*)bnsum, (unsigned long long*)bnsq, kl);
  k_cvtx   <<<16384, 256, 0, stream>>>(x, flag, xc);
  k_cvtw   <<<402,   256, 0, stream>>>(wp, flag, Wc);
  k_count  <<<4096,  256, 0, stream>>>(dst, deg);
  k_scan   <<<1,    1024, 0, stream>>>(deg, offs);
  k_fill   <<<4096,  256, 0, stream>>>(src, dst, offs, cursor, csr);
  k_aggr64 <<<16384, 256, 0, stream>>>(xc, offs, deg, csr, aggr);
  k_lin1   <<<1024,  256, 0, stream>>>(aggr, xc, Wc, qv);
  k_aggr128<<<16384, 256, 0, stream>>>(qv, offs, deg, csr, aggr);
  k_lin2   <<<2048,  256, 0, stream>>>(aggr, qv, Wc, qbn);
  k_bnstats<<<512,   128, 0, stream>>>(qbn, bnsum, bnsq);
  k_bnfin  <<<1,     256, 0, stream>>>(bnsum, bnsq, Wc, scale, shift, ksq0, ksq1);
  k_bnapply<<<32768, 256, 0, stream>>>(qbn, scale, shift, qf);
  k_qk     <<<2048,  256, 0, stream>>>(qf, Wc, qkbuf);
  k_memconv0<<<256,  256, 0, stream>>>(qkbuf, qf, Wc, ksq0, mq1, kl);
  k_memconv1<<<256,  256, 0, stream>>>(mq1, Wc, ksq1, mq2, kl+1);
  k_final  <<<256,   128, 0, stream>>>(mq2, Wc, flag, d_out);
  k_klout  <<<1,      64, 0, stream>>>(kl, flag, d_out);
}

// Round 5
// 680.545 us; speedup vs baseline: 1.7058x; 1.0705x over previous
//
#include <hip/hip_runtime.h>
#include <hip/hip_bf16.h>

#define NTOT   65536
#define NEDGE  1048576
#define HEADS  5
#define K1     32
#define K2     8
#define MEMH   100
#define EPSF   1e-8f

// ---- workspace layout (bytes) ----
#define OFF_DEG     0x0000000
#define OFF_CURSOR  0x0040000
#define OFF_OFFS    0x0080000
#define OFF_BNSUM   0x00C0000
#define OFF_BNSQ    0x00C0400
#define OFF_SCALE   0x00C0800
#define OFF_SHIFT   0x00C0A00
#define OFF_KSQ0    0x00C0C00
#define OFF_KSQ1    0x00C0E80
#define OFF_KL      0x00C0F40
#define OFF_FLAG    0x00C0F60
#define OFF_W       0x00C1000   // canonical f32 weights
#define OFF_K0B     0x0128000   // keys0 as bf16 (40KB)
#define OFF_CSR     0x0140000   // 4MB
#define OFF_A       0x0540000   // 32MB: aggr64/aggr128 -> qbn -> qf (in-place chain)
#define OFF_B       0x2540000   // 32MB: qv ; later qk (40MB while qv dead)
#define OFF_QK      0x2540000
#define OFF_C       0x4540000   // 16MB: xc
#define OFF_MQ1     0x4D40000
#define OFF_MQ2     0x5060000

// ---- canonical weight offsets (floats) ----
#define W_WREL0  0
#define W_BREL0  8192
#define W_WROOT0 8320
#define W_WREL1  16512
#define W_BREL1  32896
#define W_WROOT1 33024
#define W_GAMMA  49408
#define W_BETA   49536
#define W_KEYS0  49664
#define W_CONVW0 70144
#define W_LINW0  70149
#define W_LINB0  82949
#define W_KEYS1  83049
#define W_CONVW1 87049
#define W_LINW1  87054
#define W_LINB1  97054
#define W_MLPW1  97154
#define W_MLPB1  102154
#define W_MLPW2  102204
#define W_MLPB2  102804
#define W_TOTAL  102816

typedef __attribute__((ext_vector_type(8))) short  bf16x8;
typedef __attribute__((ext_vector_type(4))) float  f32x4;

__device__ __forceinline__ float bf2f(unsigned short u){
  union { unsigned int i; float f; } v; v.i = ((unsigned int)u) << 16; return v.f;
}
__device__ __forceinline__ unsigned short f2bf(float f){
  union { float f; unsigned int i; } v; v.f = f;
  unsigned int r = (v.i + 0x7FFFu + ((v.i >> 16) & 1u)) >> 16;   // RNE
  return (unsigned short)r;
}

__device__ const int g_seg[21] = {0,8192,8320,16512,32896,33024,49408,49536,49664,
                                  70144,70149,82949,83049,87049,87054,97054,97154,
                                  102154,102204,102804,102816};
struct WPtrs { const void* p[20]; };

// ---------------- dtype probe ----------------
__global__ void k_detect(const unsigned short* __restrict__ xr, int* flag){
  int t = threadIdx.x & 63;
  unsigned short u = xr[2*t];
  int e = (u >> 7) & 0xFF;
  bool plaus = (u != 0) && (e >= 115) && (e <= 135);
  unsigned long long m = __ballot(plaus);
  if(t == 0) flag[0] = (__popcll(m) >= 48) ? 1 : 0;
}

__global__ __launch_bounds__(256) void k_cvtx(const void* __restrict__ xin,
                                              const int* __restrict__ flag,
                                              float* __restrict__ xout){
  int i = blockIdx.x*256 + threadIdx.x;          // NTOT*64
  if(flag[0]) xout[i] = bf2f(((const unsigned short*)xin)[i]);
  else        xout[i] = ((const float*)xin)[i];
}

__global__ __launch_bounds__(256) void k_cvtw(WPtrs wp, const int* __restrict__ flag,
                                              float* __restrict__ wout){
  int i = blockIdx.x*256 + threadIdx.x;
  if(i >= W_TOTAL) return;
  int s = 0;
  #pragma unroll
  for(int k=0;k<20;k++) if(i >= g_seg[k+1]) s = k+1;
  int j = i - g_seg[s];
  const void* src = wp.p[s];
  wout[i] = flag[0] ? bf2f(((const unsigned short*)src)[j]) : ((const float*)src)[j];
}

// keys0 f32 -> bf16 (20480 elems)
__global__ __launch_bounds__(256) void k_cvtk(const float* __restrict__ W,
                                              unsigned short* __restrict__ k0b){
  int i = blockIdx.x*256 + threadIdx.x;
  if(i < HEADS*K1*128) k0b[i] = f2bf(W[W_KEYS0 + i]);
}

// ---------------- init / CSR build ----------------
__global__ __launch_bounds__(256) void k_init(int* deg, int* cursor,
                                              unsigned long long* bnsum,
                                              unsigned long long* bnsq, float* kl){
  int i = blockIdx.x*256 + threadIdx.x;
  if(i < NTOT){ deg[i]=0; cursor[i]=0; }
  if(i < 128){ bnsum[i]=0ULL; bnsq[i]=0ULL; }
  if(i < 2) kl[i]=0.f;
}

__global__ __launch_bounds__(256) void k_count(const int* __restrict__ dst, int* deg){
  int e = blockIdx.x*256 + threadIdx.x;
  atomicAdd(&deg[dst[e]], 1);
}

__global__ __launch_bounds__(1024) void k_scan(const int* __restrict__ deg, int* __restrict__ offs){
  __shared__ int ts[1024];
  const int t = threadIdx.x;
  const int base = t*64;
  int s = 0;
  for(int i=0;i<64;i++) s += deg[base+i];
  ts[t] = s; __syncthreads();
  for(int off=1; off<1024; off<<=1){
    int v = (t>=off) ? ts[t-off] : 0;
    __syncthreads();
    ts[t] += v;
    __syncthreads();
  }
  int run = (t==0) ? 0 : ts[t-1];
  for(int i=0;i<64;i++){ offs[base+i]=run; run += deg[base+i]; }
}

__global__ __launch_bounds__(256) void k_fill(const int* __restrict__ src, const int* __restrict__ dst,
                                              const int* __restrict__ offs, int* cursor, int* __restrict__ csr){
  int e = blockIdx.x*256 + threadIdx.x;
  int d = dst[e];
  int p = atomicAdd(&cursor[d], 1);
  csr[offs[d] + p] = src[e];
}

// ---------------- graph aggregation (ILP-unrolled gathers) ----------------
__global__ __launch_bounds__(256) void k_aggr64(const float* __restrict__ xc,
                                                const int* __restrict__ offs, const int* __restrict__ deg,
                                                const int* __restrict__ csr, float* __restrict__ aggr){
  const int wid  = (blockIdx.x*256 + threadIdx.x) >> 6;
  const int lane = threadIdx.x & 63;
  const int sub = lane >> 4, fl = lane & 15;
  const int beg = offs[wid], n = deg[wid];
  float4 acc = {0.f,0.f,0.f,0.f};
  int i = 0;
  for(; i+32 <= n; i += 32){
    int s[8];
    #pragma unroll
    for(int j=0;j<8;j++) s[j] = csr[beg + i + 4*j + sub];
    #pragma unroll
    for(int j=0;j<8;j++){
      float4 v = *(const float4*)(xc + (size_t)s[j]*64 + fl*4);
      acc.x += v.x; acc.y += v.y; acc.z += v.z; acc.w += v.w;
    }
  }
  for(; i < n; i += 4){
    if(i + sub < n){
      int s = csr[beg + i + sub];
      float4 v = *(const float4*)(xc + (size_t)s*64 + fl*4);
      acc.x += v.x; acc.y += v.y; acc.z += v.z; acc.w += v.w;
    }
  }
  acc.x += __shfl_xor(acc.x, 16); acc.y += __shfl_xor(acc.y, 16);
  acc.z += __shfl_xor(acc.z, 16); acc.w += __shfl_xor(acc.w, 16);
  acc.x += __shfl_xor(acc.x, 32); acc.y += __shfl_xor(acc.y, 32);
  acc.z += __shfl_xor(acc.z, 32); acc.w += __shfl_xor(acc.w, 32);
  if(sub == 0) *(float4*)(aggr + (size_t)wid*64 + fl*4) = acc;
}

__global__ __launch_bounds__(256) void k_aggr128(const float* __restrict__ q,
                                                 const int* __restrict__ offs, const int* __restrict__ deg,
                                                 const int* __restrict__ csr, float* __restrict__ aggr){
  const int wid  = (blockIdx.x*256 + threadIdx.x) >> 6;
  const int lane = threadIdx.x & 63;
  const int sub = lane >> 5, fl = lane & 31;
  const int beg = offs[wid], n = deg[wid];
  float4 acc = {0.f,0.f,0.f,0.f};
  int i = 0;
  for(; i+16 <= n; i += 16){
    int s[8];
    #pragma unroll
    for(int j=0;j<8;j++) s[j] = csr[beg + i + 2*j + sub];
    #pragma unroll
    for(int j=0;j<8;j++){
      float4 v = *(const float4*)(q + (size_t)s[j]*128 + fl*4);
      acc.x += v.x; acc.y += v.y; acc.z += v.z; acc.w += v.w;
    }
  }
  for(; i < n; i += 2){
    if(i + sub < n){
      int s = csr[beg + i + sub];
      float4 v = *(const float4*)(q + (size_t)s*128 + fl*4);
      acc.x += v.x; acc.y += v.y; acc.z += v.z; acc.w += v.w;
    }
  }
  acc.x += __shfl_xor(acc.x, 32); acc.y += __shfl_xor(acc.y, 32);
  acc.z += __shfl_xor(acc.z, 32); acc.w += __shfl_xor(acc.w, 32);
  if(sub == 0) *(float4*)(aggr + (size_t)wid*128 + fl*4) = acc;
}

// ---------------- lin1: 64-row tile, thread = 4 rows x 8 cols ----------------
// row-major LDS staging (stride 68): coalesced global reads, conflict-free writes,
// broadcast reads in compute (r0 stride 4*68 -> 2-way bank alias = free)
__global__ __launch_bounds__(256) void k_lin1(const float* __restrict__ aggr, const float* __restrict__ xc,
                                              const float* __restrict__ W, float* __restrict__ qout){
  __shared__ float As[64*68];
  __shared__ float Xs[64*68];
  const int r0b = blockIdx.x*64;
  const int t = threadIdx.x;
  for(int idx=t; idx<64*64; idx+=256){
    int r = idx >> 6, f = idx & 63;
    As[r*68 + f] = aggr[(size_t)(r0b+r)*64 + f];
    Xs[r*68 + f] = xc  [(size_t)(r0b+r)*64 + f];
  }
  __syncthreads();
  const int j8 = (t & 15)*8;
  const int r0 = (t >> 4)*4;
  float acc[4][8];
  #pragma unroll
  for(int r=0;r<4;r++)
    #pragma unroll
    for(int c=0;c<8;c++) acc[r][c]=0.f;
  for(int f=0; f<64; f+=4){
    float4 a[4], x[4];
    #pragma unroll
    for(int rr=0;rr<4;rr++){
      a[rr] = *(const float4*)(As + (r0+rr)*68 + f);
      x[rr] = *(const float4*)(Xs + (r0+rr)*68 + f);
    }
    #pragma unroll
    for(int ff=0; ff<4; ff++){
      float4 wr0 = *(const float4*)(W + W_WREL0  + (f+ff)*128 + j8);
      float4 wr1 = *(const float4*)(W + W_WREL0  + (f+ff)*128 + j8 + 4);
      float4 wo0 = *(const float4*)(W + W_WROOT0 + (f+ff)*128 + j8);
      float4 wo1 = *(const float4*)(W + W_WROOT0 + (f+ff)*128 + j8 + 4);
      #pragma unroll
      for(int rr=0;rr<4;rr++){
        float av = ((const float*)&a[rr])[ff];
        float xv = ((const float*)&x[rr])[ff];
        acc[rr][0] += av*wr0.x + xv*wo0.x;
        acc[rr][1] += av*wr0.y + xv*wo0.y;
        acc[rr][2] += av*wr0.z + xv*wo0.z;
        acc[rr][3] += av*wr0.w + xv*wo0.w;
        acc[rr][4] += av*wr1.x + xv*wo1.x;
        acc[rr][5] += av*wr1.y + xv*wo1.y;
        acc[rr][6] += av*wr1.z + xv*wo1.z;
        acc[rr][7] += av*wr1.w + xv*wo1.w;
      }
    }
  }
  float4 b0 = *(const float4*)(W + W_BREL0 + j8);
  float4 b1 = *(const float4*)(W + W_BREL0 + j8 + 4);
  #pragma unroll
  for(int rr=0;rr<4;rr++){
    float4 o0, o1;
    o0.x = fmaxf(acc[rr][0]+b0.x, 0.f);
    o0.y = fmaxf(acc[rr][1]+b0.y, 0.f);
    o0.z = fmaxf(acc[rr][2]+b0.z, 0.f);
    o0.w = fmaxf(acc[rr][3]+b0.w, 0.f);
    o1.x = fmaxf(acc[rr][4]+b1.x, 0.f);
    o1.y = fmaxf(acc[rr][5]+b1.y, 0.f);
    o1.z = fmaxf(acc[rr][6]+b1.z, 0.f);
    o1.w = fmaxf(acc[rr][7]+b1.w, 0.f);
    *(float4*)(qout + (size_t)(r0b+r0+rr)*128 + j8)     = o0;
    *(float4*)(qout + (size_t)(r0b+r0+rr)*128 + j8 + 4) = o1;
  }
}

// ---------------- lin2: 64-row tile, thread = 4 rows x 8 cols (in-place safe) ----
__global__ __launch_bounds__(256) void k_lin2(const float* __restrict__ aggr, const float* __restrict__ q,
                                              const float* __restrict__ W, float* __restrict__ qout){
  __shared__ float As[64*132];
  __shared__ float Xs[64*132];
  const int r0b = blockIdx.x*64;
  const int t = threadIdx.x;
  for(int idx=t; idx<64*128; idx+=256){
    int r = idx >> 7, f = idx & 127;
    As[r*132 + f] = aggr[(size_t)(r0b+r)*128 + f];
    Xs[r*132 + f] = q   [(size_t)(r0b+r)*128 + f];
  }
  __syncthreads();
  const int j8 = (t & 15)*8;
  const int r0 = (t >> 4)*4;
  float acc[4][8];
  #pragma unroll
  for(int r=0;r<4;r++)
    #pragma unroll
    for(int c=0;c<8;c++) acc[r][c]=0.f;
  for(int f=0; f<128; f+=4){
    float4 a[4], x[4];
    #pragma unroll
    for(int rr=0;rr<4;rr++){
      a[rr] = *(const float4*)(As + (r0+rr)*132 + f);
      x[rr] = *(const float4*)(Xs + (r0+rr)*132 + f);
    }
    #pragma unroll
    for(int ff=0; ff<4; ff++){
      float4 wr0 = *(const float4*)(W + W_WREL1  + (f+ff)*128 + j8);
      float4 wr1 = *(const float4*)(W + W_WREL1  + (f+ff)*128 + j8 + 4);
      float4 wo0 = *(const float4*)(W + W_WROOT1 + (f+ff)*128 + j8);
      float4 wo1 = *(const float4*)(W + W_WROOT1 + (f+ff)*128 + j8 + 4);
      #pragma unroll
      for(int rr=0;rr<4;rr++){
        float av = ((const float*)&a[rr])[ff];
        float xv = ((const float*)&x[rr])[ff];
        acc[rr][0] += av*wr0.x + xv*wo0.x;
        acc[rr][1] += av*wr0.y + xv*wo0.y;
        acc[rr][2] += av*wr0.z + xv*wo0.z;
        acc[rr][3] += av*wr0.w + xv*wo0.w;
        acc[rr][4] += av*wr1.x + xv*wo1.x;
        acc[rr][5] += av*wr1.y + xv*wo1.y;
        acc[rr][6] += av*wr1.z + xv*wo1.z;
        acc[rr][7] += av*wr1.w + xv*wo1.w;
      }
    }
  }
  float4 b0 = *(const float4*)(W + W_BREL1 + j8);
  float4 b1 = *(const float4*)(W + W_BREL1 + j8 + 4);
  #pragma unroll
  for(int rr=0;rr<4;rr++){
    float4 o0, o1;
    o0.x = fmaxf(acc[rr][0]+b0.x, 0.f);
    o0.y = fmaxf(acc[rr][1]+b0.y, 0.f);
    o0.z = fmaxf(acc[rr][2]+b0.z, 0.f);
    o0.w = fmaxf(acc[rr][3]+b0.w, 0.f);
    o1.x = fmaxf(acc[rr][4]+b1.x, 0.f);
    o1.y = fmaxf(acc[rr][5]+b1.y, 0.f);
    o1.z = fmaxf(acc[rr][6]+b1.z, 0.f);
    o1.w = fmaxf(acc[rr][7]+b1.w, 0.f);
    *(float4*)(qout + (size_t)(r0b+r0+rr)*128 + j8)     = o0;
    *(float4*)(qout + (size_t)(r0b+r0+rr)*128 + j8 + 4) = o1;
  }
}

// ---------------- batchnorm ----------------
__global__ __launch_bounds__(128) void k_bnstats(const float* __restrict__ qbn, double* bnsum, double* bnsq){
  const int j = threadIdx.x;
  const int r0 = blockIdx.x*128;
  float s=0.f, s2=0.f;
  for(int r=0;r<128;r++){ float v = qbn[(size_t)(r0+r)*128 + j]; s += v; s2 += v*v; }
  atomicAdd(&bnsum[j], (double)s);
  atomicAdd(&bnsq[j], (double)s2);
}

__global__ __launch_bounds__(256) void k_bnfin(const double* __restrict__ bnsum, const double* __restrict__ bnsq,
                                               const float* __restrict__ W,
                                               float* scale, float* shift, float* ksq0, float* ksq1){
  const int t = threadIdx.x;
  if(t < 128){
    double mu  = bnsum[t] / (double)NTOT;
    double var = bnsq[t] / (double)NTOT - mu*mu;
    if(var < 0.0) var = 0.0;
    float sc = W[W_GAMMA + t] * rsqrtf((float)var + 1e-5f);
    scale[t] = sc;
    shift[t] = W[W_BETA + t] - (float)mu * sc;
  }
  if(t < HEADS*K1){
    float s=0.f;
    for(int f=0;f<128;f++){ float v = W[W_KEYS0 + t*128 + f]; s += v*v; }
    ksq0[t] = s;
  }
  if(t < HEADS*K2){
    float s=0.f;
    for(int f=0;f<100;f++){ float v = W[W_KEYS1 + t*100 + f]; s += v*v; }
    ksq1[t] = s;
  }
}

__global__ __launch_bounds__(256) void k_bnapply(const float* __restrict__ qbn, const float* __restrict__ scale,
                                                 const float* __restrict__ shift, float* __restrict__ qf){
  int i = blockIdx.x*256 + threadIdx.x;   // NTOT*128
  int f = i & 127;
  qf[i] = qbn[i]*scale[f] + shift[f];
}

// ---------------- qk via MFMA bf16: (65536x128) @ keys0^T -> qk (65536x160) f32 ----
// A: qf rows converted f32->bf16 in-register; B: pre-converted keys0 bf16.
// Fragment layouts (m89-verified): A[m=lane&15][k=quad*8+j]; C/D col=lane&15, row=quad*4+reg.
__global__ __launch_bounds__(256) void k_qk(const float* __restrict__ qf,
                                            const unsigned short* __restrict__ k0b,
                                            float* __restrict__ qk){
  const int wave = (blockIdx.x*256 + threadIdx.x) >> 6;   // 16 rows per wave
  const int lane = threadIdx.x & 63;
  const int quad = lane >> 4;
  const int r    = lane & 15;
  const int m0   = wave << 4;

  const float4* arow = (const float4*)(qf + (size_t)(m0 + r)*128);
  bf16x8 a[4];
  #pragma unroll
  for(int ks=0; ks<4; ks++){
    float4 u = arow[ks*8 + quad*2];
    float4 v = arow[ks*8 + quad*2 + 1];
    bf16x8 pk;
    pk[0]=(short)f2bf(u.x); pk[1]=(short)f2bf(u.y); pk[2]=(short)f2bf(u.z); pk[3]=(short)f2bf(u.w);
    pk[4]=(short)f2bf(v.x); pk[5]=(short)f2bf(v.y); pk[6]=(short)f2bf(v.z); pk[7]=(short)f2bf(v.w);
    a[ks] = pk;
  }
  for(int nb=0; nb<10; nb++){
    f32x4 acc = {0.f,0.f,0.f,0.f};
    const bf16x8* brow = (const bf16x8*)(k0b + (size_t)(nb*16 + r)*128);
    #pragma unroll
    for(int ks=0; ks<4; ks++)
      acc = __builtin_amdgcn_mfma_f32_16x16x32_bf16(a[ks], brow[ks*4 + quad], acc, 0, 0, 0);
    #pragma unroll
    for(int i=0;i<4;i++)
      qk[(size_t)(m0 + quad*4 + i)*160 + nb*16 + r] = acc[i];
  }
}

// ---------------- mem conv 0 (block per batch) ----------------
__global__ __launch_bounds__(256) void k_memconv0(
    const float* __restrict__ qk, const float* __restrict__ qf,
    const float* __restrict__ W, const float* __restrict__ ksq,
    float* __restrict__ mq1, float* __restrict__ klacc)
{
  __shared__ float Cs[256*36];
  __shared__ float Vs[32*132];
  __shared__ float cn_s[32];
  __shared__ float pn_s[256];
  __shared__ float red_s[4];
  const int b = blockIdx.x, t = threadIdx.x;

  const float4* qrow = (const float4*)(qf + (size_t)(b*256 + t)*128);
  float qsq = 0.f;
  #pragma unroll 8
  for(int jj=0; jj<32; jj++){
    float4 v = qrow[jj];
    qsq += v.x*v.x + v.y*v.y + v.z*v.z + v.w*v.w;
  }

  const float* qkrow = qk + (size_t)(b*256 + t)*160;
  float wsum[32];
  #pragma unroll
  for(int k=0;k<32;k++) wsum[k]=0.f;
  for(int h=0; h<HEADS; h++){
    float cw = W[W_CONVW0 + h];
    float c[32]; float rs = 0.f;
    #pragma unroll
    for(int k=0;k<32;k++){
      float d2 = qsq + ksq[h*32+k] - 2.f*qkrow[h*32+k];
      d2 = fmaxf(d2, 1e-12f);
      float cc = 1.f/(1.f+d2);
      c[k]=cc; rs += cc;
    }
    float sc = cw/fmaxf(rs, 1e-20f);
    #pragma unroll
    for(int k=0;k<32;k++) wsum[k] += c[k]*sc;
  }
  float mx = wsum[0];
  #pragma unroll
  for(int k=1;k<32;k++) mx = fmaxf(mx, wsum[k]);
  float se = 0.f;
  #pragma unroll
  for(int k=0;k<32;k++){ float e = __expf(wsum[k]-mx); wsum[k]=e; se+=e; }
  float inv = 1.f/se;
  #pragma unroll
  for(int k=0;k<32;k++) Cs[t*36+k] = wsum[k]*inv;
  __syncthreads();

  if(t < 32){ float s=0.f; for(int n=0;n<256;n++) s += Cs[n*36+t]; cn_s[t] = s + EPSF; }
  __syncthreads();
  {
    float p = 0.f;
    #pragma unroll
    for(int k=0;k<32;k++){ float sv = Cs[t*36+k]; p += sv*sv/cn_s[k]; }
    pn_s[t] = p + EPSF;
  }
  __syncthreads();

  float acc = 0.f;
  for(int idx=t; idx<256*32; idx+=256){
    int n = idx>>5, k = idx&31;
    float sv = Cs[n*36+k];
    float P = sv*sv/(cn_s[k]*pn_s[n]);
    acc += P*(__logf(P+EPSF) - __logf(sv+EPSF));
  }
  #pragma unroll
  for(int off=32; off>0; off>>=1) acc += __shfl_down(acc, off);
  if((t&63)==0) red_s[t>>6] = acc;

  // V = C^T Q : thread = 4 k's x 4 f's
  {
    const int k4 = (t&7)*4;
    const int f0 = (t>>3)*4;
    float vacc[4][4];
    #pragma unroll
    for(int a=0;a<4;a++){ vacc[a][0]=0;vacc[a][1]=0;vacc[a][2]=0;vacc[a][3]=0; }
    const float* qbase = qf + (size_t)b*256*128 + f0;
    for(int n=0;n<256;n++){
      float4 cv = *(const float4*)(Cs + n*36 + k4);
      float4 u  = *(const float4*)(qbase + (size_t)n*128);
      float cr[4] = {cv.x,cv.y,cv.z,cv.w};
      #pragma unroll
      for(int a=0;a<4;a++){
        vacc[a][0] += cr[a]*u.x;
        vacc[a][1] += cr[a]*u.y;
        vacc[a][2] += cr[a]*u.z;
        vacc[a][3] += cr[a]*u.w;
      }
    }
    #pragma unroll
    for(int a=0;a<4;a++){
      Vs[(k4+a)*132 + f0 + 0] = vacc[a][0];
      Vs[(k4+a)*132 + f0 + 1] = vacc[a][1];
      Vs[(k4+a)*132 + f0 + 2] = vacc[a][2];
      Vs[(k4+a)*132 + f0 + 3] = vacc[a][3];
    }
  }
  __syncthreads();

  if(t==0) atomicAdd(klacc, 100.f*(red_s[0]+red_s[1]+red_s[2]+red_s[3]));

  for(int idx=t; idx<K1*MEMH; idx+=256){
    int k = idx/100, m = idx - k*100;
    float a = W[W_LINB0 + m];
    for(int f=0; f<128; f++) a += Vs[k*132+f]*W[W_LINW0 + f*100 + m];
    mq1[(size_t)(b*32+k)*100 + m] = (a>0.f) ? a : 0.01f*a;
  }
}

// ---------------- mem conv 1 ----------------
__global__ __launch_bounds__(256) void k_memconv1(
    const float* __restrict__ mq1, const float* __restrict__ W,
    const float* __restrict__ ksq, float* __restrict__ mq2, float* __restrict__ klacc)
{
  __shared__ float Qs[32*104];
  __shared__ float Ks[40*100];
  __shared__ float QKs[32*40];
  __shared__ float Cs[32*8];
  __shared__ float cn_s[8];
  __shared__ float pn_s[32];
  __shared__ float qsq_s[32];
  __shared__ float Vs[8*100];
  __shared__ float red_s[4];
  const int b = blockIdx.x, t = threadIdx.x;

  for(int idx=t; idx<32*100; idx+=256){
    int n = idx/100, f = idx - n*100;
    Qs[n*104+f] = mq1[(size_t)b*3200 + idx];
  }
  for(int idx=t; idx<40*100; idx+=256) Ks[idx] = W[W_KEYS1 + idx];
  __syncthreads();

  if(t < 32){ float s=0.f; for(int f=0;f<100;f++){ float v=Qs[t*104+f]; s+=v*v; } qsq_s[t]=s; }
  for(int idx=t; idx<32*40; idx+=256){
    int n = idx/40, c = idx - n*40;
    float a = 0.f;
    for(int f=0;f<100;f++) a += Qs[n*104+f]*Ks[c*100+f];
    QKs[idx] = a;
  }
  __syncthreads();

  if(t < 32){
    float wsum[8];
    #pragma unroll
    for(int k=0;k<8;k++) wsum[k]=0.f;
    for(int h=0;h<HEADS;h++){
      float cw = W[W_CONVW1 + h];
      float c[8]; float rs=0.f;
      #pragma unroll
      for(int k=0;k<8;k++){
        float d2 = qsq_s[t] + ksq[h*8+k] - 2.f*QKs[t*40 + h*8+k];
        d2 = fmaxf(d2, 1e-12f);
        float cc = 1.f/(1.f+d2);
        c[k]=cc; rs+=cc;
      }
      float sc = cw/fmaxf(rs, 1e-20f);
      #pragma unroll
      for(int k=0;k<8;k++) wsum[k] += c[k]*sc;
    }
    float mx = wsum[0];
    #pragma unroll
    for(int k=1;k<8;k++) mx = fmaxf(mx, wsum[k]);
    float se=0.f;
    #pragma unroll
    for(int k=0;k<8;k++){ float e=__expf(wsum[k]-mx); wsum[k]=e; se+=e; }
    float inv = 1.f/se;
    #pragma unroll
    for(int k=0;k<8;k++) Cs[t*8+k] = wsum[k]*inv;
  }
  __syncthreads();
  if(t < 8){ float s=0.f; for(int n=0;n<32;n++) s += Cs[n*8+t]; cn_s[t]=s+EPSF; }
  __syncthreads();
  if(t < 32){
    float p=0.f;
    #pragma unroll
    for(int k=0;k<8;k++){ float sv=Cs[t*8+k]; p += sv*sv/cn_s[k]; }
    pn_s[t]=p+EPSF;
  }
  __syncthreads();

  float acc;
  {
    int n = t>>3, k = t&7;
    float sv = Cs[t];
    float P = sv*sv/(cn_s[k]*pn_s[n]);
    acc = P*(__logf(P+EPSF) - __logf(sv+EPSF));
  }
  #pragma unroll
  for(int off=32; off>0; off>>=1) acc += __shfl_down(acc, off);
  if((t&63)==0) red_s[t>>6] = acc;

  for(int idx=t; idx<8*100; idx+=256){
    int k = idx/100, f = idx - k*100;
    float a=0.f;
    for(int n=0;n<32;n++) a += Cs[n*8+k]*Qs[n*104+f];
    Vs[idx] = a;
  }
  __syncthreads();

  if(t==0) atomicAdd(klacc, 100.f*(red_s[0]+red_s[1]+red_s[2]+red_s[3]));

  for(int idx=t; idx<8*100; idx+=256){
    int k = idx/100, m = idx - k*100;
    float a = W[W_LINB1 + m];
    for(int f=0;f<100;f++) a += Vs[k*100+f]*W[W_LINW1 + f*100 + m];
    mq2[(size_t)b*800 + idx] = (a>0.f) ? a : 0.01f*a;
  }
}

// ---------------- head ----------------
__global__ __launch_bounds__(128) void k_final(const float* __restrict__ mq2,
                                               const float* __restrict__ W,
                                               const int* __restrict__ flag,
                                               void* __restrict__ out){
  __shared__ float h_s[100];
  __shared__ float hid_s[50];
  const int b = blockIdx.x, t = threadIdx.x;
  if(t < 100){
    float s=0.f;
    #pragma unroll
    for(int k=0;k<8;k++) s += mq2[(size_t)b*800 + k*100 + t];
    h_s[t] = s*0.125f;
  }
  __syncthreads();
  if(t < 50){
    float a = W[W_MLPB1 + t];
    for(int f=0;f<100;f++) a += h_s[f]*W[W_MLPW1 + f*50 + t];
    hid_s[t] = (a>0.f) ? a : 0.01f*a;
  }
  __syncthreads();
  if(t < 12){
    float a = W[W_MLPB2 + t];
    #pragma unroll
    for(int j=0;j<50;j++) a += hid_s[j]*W[W_MLPW2 + j*12 + t];
    if(flag[0]) ((__hip_bfloat16*)out)[b*12+t] = __float2bfloat16(a);
    else        ((float*)out)[b*12+t] = a;
  }
}

__global__ void k_klout(const float* __restrict__ kl, const int* __restrict__ flag,
                        void* __restrict__ out){
  if(blockIdx.x==0 && threadIdx.x==0){
    float v = (kl[0]+kl[1]) * (1.f/65536.f);
    if(flag[0]) ((__hip_bfloat16*)out)[3072] = __float2bfloat16(v);
    else        ((float*)out)[3072] = v;
  }
}

// ---------------- launch ----------------
extern "C" void kernel_launch(void* const* d_in, const int* in_sizes, int n_in,
                              void* d_out, int out_size, void* d_ws, size_t ws_size,
                              hipStream_t stream) {
  (void)in_sizes; (void)n_in; (void)out_size; (void)ws_size;
  const void* x   = d_in[0];
  const int*  ei  = (const int*)d_in[1];
  const int* src = ei;
  const int* dst = ei + NEDGE;

  WPtrs wp;
  for(int i=0;i<20;i++) wp.p[i] = d_in[3+i];

  char* w = (char*)d_ws;
  int*    deg    = (int*)   (w + OFF_DEG);
  int*    cursor = (int*)   (w + OFF_CURSOR);
  int*    offs   = (int*)   (w + OFF_OFFS);
  double* bnsum  = (double*)(w + OFF_BNSUM);
  double* bnsq   = (double*)(w + OFF_BNSQ);
  float*  scale  = (float*) (w + OFF_SCALE);
  float*  shift  = (float*) (w + OFF_SHIFT);
  float*  ksq0   = (float*) (w + OFF_KSQ0);
  float*  ksq1   = (float*) (w + OFF_KSQ1);
  float*  kl     = (float*) (w + OFF_KL);
  int*    flag   = (int*)   (w + OFF_FLAG);
  float*  Wc     = (float*) (w + OFF_W);
  unsigned short* k0b = (unsigned short*)(w + OFF_K0B);
  int*    csr    = (int*)   (w + OFF_CSR);
  float*  regA   = (float*) (w + OFF_A);
  float*  regB   = (float*) (w + OFF_B);
  float*  qkbuf  = (float*) (w + OFF_QK);
  float*  xc     = (float*) (w + OFF_C);
  float*  mq1    = (float*) (w + OFF_MQ1);
  float*  mq2    = (float*) (w + OFF_MQ2);

  float* aggr = regA;       // aggr64 (16MB) then aggr128 (32MB)
  float* qv   = regB;       // lin1 out
  float* qbn  = regA;       // lin2 in place over aggr128 rows
  float* qf   = regA;       // bnapply in place

  k_detect <<<1,      64, 0, stream>>>((const unsigned short*)x, flag);
  k_init   <<<256,   256, 0, stream>>>(deg, cursor, (unsigned long long*)bnsum, (unsigned long long*)bnsq, kl);
  k_cvtx   <<<16384, 256, 0, stream>>>(x, flag, xc);
  k_cvtw   <<<402,   256, 0, stream>>>(wp, flag, Wc);
  k_cvtk   <<<80,    256, 0, stream>>>(Wc, k0b);
  k_count  <<<4096,  256, 0, stream>>>(dst, deg);
  k_scan   <<<1,    1024, 0, stream>>>(deg, offs);
  k_fill   <<<4096,  256, 0, stream>>>(src, dst, offs, cursor, csr);
  k_aggr64 <<<16384, 256, 0, stream>>>(xc, offs, deg, csr, aggr);
  k_lin1   <<<1024,  256, 0, stream>>>(aggr, xc, Wc, qv);
  k_aggr128<<<16384, 256, 0, stream>>>(qv, offs, deg, csr, aggr);
  k_lin2   <<<1024,  256, 0, stream>>>(aggr, qv, Wc, qbn);
  k_bnstats<<<512,   128, 0, stream>>>(qbn, bnsum, bnsq);
  k_bnfin  <<<1,     256, 0, stream>>>(bnsum, bnsq, Wc, scale, shift, ksq0, ksq1);
  k_bnapply<<<32768, 256, 0, stream>>>(qbn, scale, shift, qf);
  k_qk     <<<1024,  256, 0, stream>>>(qf, k0b, qkbuf);
  k_memconv0<<<256,  256, 0, stream>>>(qkbuf, qf, Wc, ksq0, mq1, kl);
  k_memconv1<<<256,  256, 0, stream>>>(mq1, Wc, ksq1, mq2, kl+1);
  k_final  <<<256,   128, 0, stream>>>(mq2, Wc, flag, d_out);
  k_klout  <<<1,      64, 0, stream>>>(kl, flag, d_out);
}

// Round 7
// 641.311 us; speedup vs baseline: 1.8101x; 1.0612x over previous
//
#include <hip/hip_runtime.h>
#include <hip/hip_bf16.h>

#define NTOT   65536
#define NEDGE  1048576
#define HEADS  5
#define K1     32
#define K2     8
#define MEMH   100
#define EPSF   1e-8f

// ---- workspace layout (bytes) ----
#define OFF_DEG     0x0000000
#define OFF_CURSOR  0x0040000   // dead after k_fill -> reused for WT planes
#define OFF_WT1     0x0040000   // lin1 W^T bf16 hi/lo planes (64KB), written AFTER k_fill
#define OFF_WT2     0x0050000   // lin2 W^T bf16 hi/lo planes (128KB), ends 0x70000 < 0x80000
#define OFF_OFFS    0x0080000
#define OFF_BNSUM   0x00C0000
#define OFF_BNSQ    0x00C0400
#define OFF_SCALE   0x00C0800
#define OFF_SHIFT   0x00C0A00
#define OFF_KSQ0    0x00C0C00
#define OFF_KSQ1    0x00C0E80
#define OFF_KL      0x00C0F40
#define OFF_FLAG    0x00C0F60
#define OFF_W       0x00C1000   // canonical f32 weights (ends ~0x125680)
#define OFF_K0B     0x0128000   // keys0 as bf16 (40KB, ends 0x132000)
#define OFF_CSR     0x0140000   // 4MB
#define OFF_A       0x0540000   // 32MB: aggr64/aggr128 -> qbn (in-place chain)
#define OFF_B       0x2540000   // 32MB: qv ; later qk (40MB while qv dead)
#define OFF_QK      0x2540000
#define OFF_C       0x4540000   // 16MB: xc (0x4540000..0x5540000; mq1/mq2/qk-tail overlay after xc dies)
#define OFF_MQ1     0x4D40000
#define OFF_MQ2     0x5060000
// peak ws: 0x5540000 (unchanged from R3-R5, proven in-bounds)

// ---- canonical weight offsets (floats) ----
#define W_WREL0  0
#define W_BREL0  8192
#define W_WROOT0 8320
#define W_WREL1  16512
#define W_BREL1  32896
#define W_WROOT1 33024
#define W_GAMMA  49408
#define W_BETA   49536
#define W_KEYS0  49664
#define W_CONVW0 70144
#define W_LINW0  70149
#define W_LINB0  82949
#define W_KEYS1  83049
#define W_CONVW1 87049
#define W_LINW1  87054
#define W_LINB1  97054
#define W_MLPW1  97154
#define W_MLPB1  102154
#define W_MLPW2  102204
#define W_MLPB2  102804
#define W_TOTAL  102816

typedef __attribute__((ext_vector_type(8))) short  bf16x8;
typedef __attribute__((ext_vector_type(4))) float  f32x4;

__device__ __forceinline__ float bf2f(unsigned short u){
  union { unsigned int i; float f; } v; v.i = ((unsigned int)u) << 16; return v.f;
}
__device__ __forceinline__ unsigned short f2bf(float f){
  union { float f; unsigned int i; } v; v.f = f;
  unsigned int r = (v.i + 0x7FFFu + ((v.i >> 16) & 1u)) >> 16;   // RNE
  return (unsigned short)r;
}

__device__ const int g_seg[21] = {0,8192,8320,16512,32896,33024,49408,49536,49664,
                                  70144,70149,82949,83049,87049,87054,97054,97154,
                                  102154,102204,102804,102816};
struct WPtrs { const void* p[20]; };

// ---------------- dtype probe ----------------
__global__ void k_detect(const unsigned short* __restrict__ xr, int* flag){
  int t = threadIdx.x & 63;
  unsigned short u = xr[2*t];
  int e = (u >> 7) & 0xFF;
  bool plaus = (u != 0) && (e >= 115) && (e <= 135);
  unsigned long long m = __ballot(plaus);
  if(t == 0) flag[0] = (__popcll(m) >= 48) ? 1 : 0;
}

__global__ __launch_bounds__(256) void k_cvtx(const void* __restrict__ xin,
                                              const int* __restrict__ flag,
                                              float* __restrict__ xout){
  int i = blockIdx.x*256 + threadIdx.x;          // NTOT*64
  if(flag[0]) xout[i] = bf2f(((const unsigned short*)xin)[i]);
  else        xout[i] = ((const float*)xin)[i];
}

__global__ __launch_bounds__(256) void k_cvtw(WPtrs wp, const int* __restrict__ flag,
                                              float* __restrict__ wout){
  int i = blockIdx.x*256 + threadIdx.x;
  if(i >= W_TOTAL) return;
  int s = 0;
  #pragma unroll
  for(int k=0;k<20;k++) if(i >= g_seg[k+1]) s = k+1;
  int j = i - g_seg[s];
  const void* src = wp.p[s];
  wout[i] = flag[0] ? bf2f(((const unsigned short*)src)[j]) : ((const float*)src)[j];
}

// keys0 f32 -> bf16 (20480 elems)
__global__ __launch_bounds__(256) void k_cvtk(const float* __restrict__ W,
                                              unsigned short* __restrict__ k0b){
  int i = blockIdx.x*256 + threadIdx.x;
  if(i < HEADS*K1*128) k0b[i] = f2bf(W[W_KEYS0 + i]);
}

// lin weights -> transposed bf16 hi/lo planes [col][k]
__global__ __launch_bounds__(256) void k_cvtwt(const float* __restrict__ W,
                                               unsigned short* __restrict__ wt1,
                                               unsigned short* __restrict__ wt2){
  int i = blockIdx.x*256 + threadIdx.x;
  if(i < 128*64){
    int col = i>>6, k = i&63;
    float wr = W[W_WREL0  + k*128 + col];
    float wo = W[W_WROOT0 + k*128 + col];
    unsigned short rh = f2bf(wr), oh = f2bf(wo);
    wt1[i]            = rh;
    wt1[ 8192 + i]    = f2bf(wr - bf2f(rh));
    wt1[16384 + i]    = oh;
    wt1[24576 + i]    = f2bf(wo - bf2f(oh));
  }
  if(i < 128*128){
    int col = i>>7, k = i&127;
    float wr = W[W_WREL1  + k*128 + col];
    float wo = W[W_WROOT1 + k*128 + col];
    unsigned short rh = f2bf(wr), oh = f2bf(wo);
    wt2[i]            = rh;
    wt2[16384 + i]    = f2bf(wr - bf2f(rh));
    wt2[32768 + i]    = oh;
    wt2[49152 + i]    = f2bf(wo - bf2f(oh));
  }
}

// ---------------- init / CSR build ----------------
__global__ __launch_bounds__(256) void k_init(int* deg, int* cursor,
                                              unsigned long long* bnsum,
                                              unsigned long long* bnsq, float* kl){
  int i = blockIdx.x*256 + threadIdx.x;
  if(i < NTOT){ deg[i]=0; cursor[i]=0; }
  if(i < 128){ bnsum[i]=0ULL; bnsq[i]=0ULL; }
  if(i < 2) kl[i]=0.f;
}

__global__ __launch_bounds__(256) void k_count(const int* __restrict__ dst, int* deg){
  int e = blockIdx.x*256 + threadIdx.x;
  atomicAdd(&deg[dst[e]], 1);
}

__global__ __launch_bounds__(1024) void k_scan(const int* __restrict__ deg, int* __restrict__ offs){
  __shared__ int ts[1024];
  const int t = threadIdx.x;
  const int base = t*64;
  int s = 0;
  for(int i=0;i<64;i++) s += deg[base+i];
  ts[t] = s; __syncthreads();
  for(int off=1; off<1024; off<<=1){
    int v = (t>=off) ? ts[t-off] : 0;
    __syncthreads();
    ts[t] += v;
    __syncthreads();
  }
  int run = (t==0) ? 0 : ts[t-1];
  for(int i=0;i<64;i++){ offs[base+i]=run; run += deg[base+i]; }
}

__global__ __launch_bounds__(256) void k_fill(const int* __restrict__ src, const int* __restrict__ dst,
                                              const int* __restrict__ offs, int* cursor, int* __restrict__ csr){
  int e = blockIdx.x*256 + threadIdx.x;
  int d = dst[e];
  int p = atomicAdd(&cursor[d], 1);
  csr[offs[d] + p] = src[e];
}

// ---------------- graph aggregation (ILP-unrolled gathers) ----------------
__global__ __launch_bounds__(256) void k_aggr64(const float* __restrict__ xc,
                                                const int* __restrict__ offs, const int* __restrict__ deg,
                                                const int* __restrict__ csr, float* __restrict__ aggr){
  const int wid  = (blockIdx.x*256 + threadIdx.x) >> 6;
  const int lane = threadIdx.x & 63;
  const int sub = lane >> 4, fl = lane & 15;
  const int beg = offs[wid], n = deg[wid];
  float4 acc = {0.f,0.f,0.f,0.f};
  int i = 0;
  for(; i+32 <= n; i += 32){
    int s[8];
    #pragma unroll
    for(int j=0;j<8;j++) s[j] = csr[beg + i + 4*j + sub];
    #pragma unroll
    for(int j=0;j<8;j++){
      float4 v = *(const float4*)(xc + (size_t)s[j]*64 + fl*4);
      acc.x += v.x; acc.y += v.y; acc.z += v.z; acc.w += v.w;
    }
  }
  for(; i < n; i += 4){
    if(i + sub < n){
      int s = csr[beg + i + sub];
      float4 v = *(const float4*)(xc + (size_t)s*64 + fl*4);
      acc.x += v.x; acc.y += v.y; acc.z += v.z; acc.w += v.w;
    }
  }
  acc.x += __shfl_xor(acc.x, 16); acc.y += __shfl_xor(acc.y, 16);
  acc.z += __shfl_xor(acc.z, 16); acc.w += __shfl_xor(acc.w, 16);
  acc.x += __shfl_xor(acc.x, 32); acc.y += __shfl_xor(acc.y, 32);
  acc.z += __shfl_xor(acc.z, 32); acc.w += __shfl_xor(acc.w, 32);
  if(sub == 0) *(float4*)(aggr + (size_t)wid*64 + fl*4) = acc;
}

__global__ __launch_bounds__(256) void k_aggr128(const float* __restrict__ q,
                                                 const int* __restrict__ offs, const int* __restrict__ deg,
                                                 const int* __restrict__ csr, float* __restrict__ aggr){
  const int wid  = (blockIdx.x*256 + threadIdx.x) >> 6;
  const int lane = threadIdx.x & 63;
  const int sub = lane >> 5, fl = lane & 31;
  const int beg = offs[wid], n = deg[wid];
  float4 acc = {0.f,0.f,0.f,0.f};
  int i = 0;
  for(; i+16 <= n; i += 16){
    int s[8];
    #pragma unroll
    for(int j=0;j<8;j++) s[j] = csr[beg + i + 2*j + sub];
    #pragma unroll
    for(int j=0;j<8;j++){
      float4 v = *(const float4*)(q + (size_t)s[j]*128 + fl*4);
      acc.x += v.x; acc.y += v.y; acc.z += v.z; acc.w += v.w;
    }
  }
  for(; i < n; i += 2){
    if(i + sub < n){
      int s = csr[beg + i + sub];
      float4 v = *(const float4*)(q + (size_t)s*128 + fl*4);
      acc.x += v.x; acc.y += v.y; acc.z += v.z; acc.w += v.w;
    }
  }
  acc.x += __shfl_xor(acc.x, 32); acc.y += __shfl_xor(acc.y, 32);
  acc.z += __shfl_xor(acc.z, 32); acc.w += __shfl_xor(acc.w, 32);
  if(sub == 0) *(float4*)(aggr + (size_t)wid*128 + fl*4) = acc;
}

// ---------------- lin via split-bf16 MFMA ----------------
// out[64 rows x 128 cols] = relu(A@Wrel + X@Wroot + b), split bf16 hi/lo (3-term).
template<int KD>
__global__ __launch_bounds__(256) void k_linm(const float* __restrict__ A,
                                              const float* __restrict__ X,
                                              const unsigned short* __restrict__ WT,
                                              const float* __restrict__ W, int bofs,
                                              float* __restrict__ out){
  __shared__ unsigned short Ah[64*72], Al[64*72], Xh[64*72], Xl[64*72];
  const int r0b = blockIdx.x*64;
  const int t = threadIdx.x;
  const int wv = t>>6, lane = t&63, quad = lane>>4, m = lane&15;
  const unsigned short* WRh = WT;
  const unsigned short* WRl = WT + 128*KD;
  const unsigned short* WOh = WT + 256*KD;
  const unsigned short* WOl = WT + 384*KD;
  f32x4 acc[8];
  #pragma unroll
  for(int ct=0; ct<8; ct++) acc[ct] = (f32x4){0.f,0.f,0.f,0.f};

  for(int kh=0; kh<KD; kh+=64){
    __syncthreads();
    for(int idx=t; idx<64*16; idx+=256){
      int r = idx>>4, k4 = (idx&15)*4;
      float4 va = *(const float4*)(A + (size_t)(r0b+r)*KD + kh + k4);
      float4 vx = *(const float4*)(X + (size_t)(r0b+r)*KD + kh + k4);
      ushort4 ah, al, xh, xl;
      ah.x=f2bf(va.x); al.x=f2bf(va.x-bf2f(ah.x));
      ah.y=f2bf(va.y); al.y=f2bf(va.y-bf2f(ah.y));
      ah.z=f2bf(va.z); al.z=f2bf(va.z-bf2f(ah.z));
      ah.w=f2bf(va.w); al.w=f2bf(va.w-bf2f(ah.w));
      xh.x=f2bf(vx.x); xl.x=f2bf(vx.x-bf2f(xh.x));
      xh.y=f2bf(vx.y); xl.y=f2bf(vx.y-bf2f(xh.y));
      xh.z=f2bf(vx.z); xl.z=f2bf(vx.z-bf2f(xh.z));
      xh.w=f2bf(vx.w); xl.w=f2bf(vx.w-bf2f(xh.w));
      *(ushort4*)(Ah + r*72 + k4) = ah;
      *(ushort4*)(Al + r*72 + k4) = al;
      *(ushort4*)(Xh + r*72 + k4) = xh;
      *(ushort4*)(Xl + r*72 + k4) = xl;
    }
    __syncthreads();
    #pragma unroll
    for(int ks=0; ks<2; ks++){
      const int ko = ks*32 + quad*8;
      bf16x8 fah = *(const bf16x8*)(Ah + (wv*16+m)*72 + ko);
      bf16x8 fal = *(const bf16x8*)(Al + (wv*16+m)*72 + ko);
      bf16x8 fxh = *(const bf16x8*)(Xh + (wv*16+m)*72 + ko);
      bf16x8 fxl = *(const bf16x8*)(Xl + (wv*16+m)*72 + ko);
      #pragma unroll
      for(int ct=0; ct<8; ct++){
        const size_t wo = (size_t)(ct*16+m)*KD + kh + ko;
        bf16x8 brh = *(const bf16x8*)(WRh + wo);
        bf16x8 brl = *(const bf16x8*)(WRl + wo);
        bf16x8 boh = *(const bf16x8*)(WOh + wo);
        bf16x8 bol = *(const bf16x8*)(WOl + wo);
        acc[ct] = __builtin_amdgcn_mfma_f32_16x16x32_bf16(fah, brh, acc[ct], 0,0,0);
        acc[ct] = __builtin_amdgcn_mfma_f32_16x16x32_bf16(fal, brh, acc[ct], 0,0,0);
        acc[ct] = __builtin_amdgcn_mfma_f32_16x16x32_bf16(fah, brl, acc[ct], 0,0,0);
        acc[ct] = __builtin_amdgcn_mfma_f32_16x16x32_bf16(fxh, boh, acc[ct], 0,0,0);
        acc[ct] = __builtin_amdgcn_mfma_f32_16x16x32_bf16(fxl, boh, acc[ct], 0,0,0);
        acc[ct] = __builtin_amdgcn_mfma_f32_16x16x32_bf16(fxh, bol, acc[ct], 0,0,0);
      }
    }
  }
  #pragma unroll
  for(int ct=0; ct<8; ct++){
    float b = W[bofs + ct*16 + m];
    #pragma unroll
    for(int i=0;i<4;i++){
      float v = acc[ct][i] + b;
      out[(size_t)(r0b + wv*16 + quad*4 + i)*128 + ct*16 + m] = fmaxf(v, 0.f);
    }
  }
}

// ---------------- batchnorm ----------------
__global__ __launch_bounds__(128) void k_bnstats(const float* __restrict__ qbn, double* bnsum, double* bnsq){
  const int j = threadIdx.x;
  const int r0 = blockIdx.x*128;
  float s=0.f, s2=0.f;
  for(int r=0;r<128;r++){ float v = qbn[(size_t)(r0+r)*128 + j]; s += v; s2 += v*v; }
  atomicAdd(&bnsum[j], (double)s);
  atomicAdd(&bnsq[j], (double)s2);
}

__global__ __launch_bounds__(256) void k_bnfin(const double* __restrict__ bnsum, const double* __restrict__ bnsq,
                                               const float* __restrict__ W,
                                               float* scale, float* shift, float* ksq0, float* ksq1){
  const int t = threadIdx.x;
  if(t < 128){
    double mu  = bnsum[t] / (double)NTOT;
    double var = bnsq[t] / (double)NTOT - mu*mu;
    if(var < 0.0) var = 0.0;
    float sc = W[W_GAMMA + t] * rsqrtf((float)var + 1e-5f);
    scale[t] = sc;
    shift[t] = W[W_BETA + t] - (float)mu * sc;
  }
  if(t < HEADS*K1){
    float s=0.f;
    for(int f=0;f<128;f++){ float v = W[W_KEYS0 + t*128 + f]; s += v*v; }
    ksq0[t] = s;
  }
  if(t < HEADS*K2){
    float s=0.f;
    for(int f=0;f<100;f++){ float v = W[W_KEYS1 + t*100 + f]; s += v*v; }
    ksq1[t] = s;
  }
}

// ---------------- qk via MFMA bf16, BN fused on load ----------------
__global__ __launch_bounds__(256) void k_qk(const float* __restrict__ qbn,
                                            const float* __restrict__ scale,
                                            const float* __restrict__ shift,
                                            const unsigned short* __restrict__ k0b,
                                            float* __restrict__ qk){
  const int wave = (blockIdx.x*256 + threadIdx.x) >> 6;   // 16 rows per wave
  const int lane = threadIdx.x & 63;
  const int quad = lane >> 4;
  const int r    = lane & 15;
  const int m0   = wave << 4;

  const float4* arow = (const float4*)(qbn + (size_t)(m0 + r)*128);
  bf16x8 a[4];
  #pragma unroll
  for(int ks=0; ks<4; ks++){
    int f0 = ks*32 + quad*8;
    float4 u = arow[ks*8 + quad*2];
    float4 v = arow[ks*8 + quad*2 + 1];
    float4 s0 = *(const float4*)(scale + f0), s1 = *(const float4*)(scale + f0 + 4);
    float4 h0 = *(const float4*)(shift + f0), h1 = *(const float4*)(shift + f0 + 4);
    bf16x8 pk;
    pk[0]=(short)f2bf(u.x*s0.x+h0.x); pk[1]=(short)f2bf(u.y*s0.y+h0.y);
    pk[2]=(short)f2bf(u.z*s0.z+h0.z); pk[3]=(short)f2bf(u.w*s0.w+h0.w);
    pk[4]=(short)f2bf(v.x*s1.x+h1.x); pk[5]=(short)f2bf(v.y*s1.y+h1.y);
    pk[6]=(short)f2bf(v.z*s1.z+h1.z); pk[7]=(short)f2bf(v.w*s1.w+h1.w);
    a[ks] = pk;
  }
  for(int nb=0; nb<10; nb++){
    f32x4 acc = {0.f,0.f,0.f,0.f};
    const bf16x8* brow = (const bf16x8*)(k0b + (size_t)(nb*16 + r)*128);
    #pragma unroll
    for(int ks=0; ks<4; ks++)
      acc = __builtin_amdgcn_mfma_f32_16x16x32_bf16(a[ks], brow[ks*4 + quad], acc, 0, 0, 0);
    #pragma unroll
    for(int i=0;i<4;i++)
      qk[(size_t)(m0 + quad*4 + i)*160 + nb*16 + r] = acc[i];
  }
}

// ---------------- mem conv 0 (block per batch), BN fused on load ----------------
__global__ __launch_bounds__(256) void k_memconv0(
    const float* __restrict__ qk, const float* __restrict__ qbn,
    const float* __restrict__ scale, const float* __restrict__ shift,
    const float* __restrict__ W, const float* __restrict__ ksq,
    float* __restrict__ mq1, float* __restrict__ klacc)
{
  __shared__ float Cs[256*36];
  __shared__ float Vs[32*132];
  __shared__ float cn_s[32];
  __shared__ float pn_s[256];
  __shared__ float red_s[4];
  const int b = blockIdx.x, t = threadIdx.x;
  const float4* sc4 = (const float4*)scale;
  const float4* sh4 = (const float4*)shift;

  const float4* qrow = (const float4*)(qbn + (size_t)(b*256 + t)*128);
  float qsq = 0.f;
  #pragma unroll 8
  for(int jj=0; jj<32; jj++){
    float4 v = qrow[jj];
    float4 s = sc4[jj], h = sh4[jj];
    float a0 = v.x*s.x+h.x, a1 = v.y*s.y+h.y, a2 = v.z*s.z+h.z, a3 = v.w*s.w+h.w;
    qsq += a0*a0 + a1*a1 + a2*a2 + a3*a3;
  }

  const float* qkrow = qk + (size_t)(b*256 + t)*160;
  float wsum[32];
  #pragma unroll
  for(int k=0;k<32;k++) wsum[k]=0.f;
  for(int h=0; h<HEADS; h++){
    float cw = W[W_CONVW0 + h];
    float c[32]; float rs = 0.f;
    #pragma unroll
    for(int k=0;k<32;k++){
      float d2 = qsq + ksq[h*32+k] - 2.f*qkrow[h*32+k];
      d2 = fmaxf(d2, 1e-12f);
      float cc = 1.f/(1.f+d2);
      c[k]=cc; rs += cc;
    }
    float sc = cw/fmaxf(rs, 1e-20f);
    #pragma unroll
    for(int k=0;k<32;k++) wsum[k] += c[k]*sc;
  }
  float mx = wsum[0];
  #pragma unroll
  for(int k=1;k<32;k++) mx = fmaxf(mx, wsum[k]);
  float se = 0.f;
  #pragma unroll
  for(int k=0;k<32;k++){ float e = __expf(wsum[k]-mx); wsum[k]=e; se+=e; }
  float inv = 1.f/se;
  #pragma unroll
  for(int k=0;k<32;k++) Cs[t*36+k] = wsum[k]*inv;
  __syncthreads();

  if(t < 32){ float s=0.f; for(int n=0;n<256;n++) s += Cs[n*36+t]; cn_s[t] = s + EPSF; }
  __syncthreads();
  {
    float p = 0.f;
    #pragma unroll
    for(int k=0;k<32;k++){ float sv = Cs[t*36+k]; p += sv*sv/cn_s[k]; }
    pn_s[t] = p + EPSF;
  }
  __syncthreads();

  float acc = 0.f;
  for(int idx=t; idx<256*32; idx+=256){
    int n = idx>>5, k = idx&31;
    float sv = Cs[n*36+k];
    float P = sv*sv/(cn_s[k]*pn_s[n]);
    acc += P*(__logf(P+EPSF) - __logf(sv+EPSF));
  }
  #pragma unroll
  for(int off=32; off>0; off>>=1) acc += __shfl_down(acc, off);
  if((t&63)==0) red_s[t>>6] = acc;

  // V = C^T Q : thread = 4 k's x 4 f's, BN applied on load
  {
    const int k4 = (t&7)*4;
    const int f0 = (t>>3)*4;
    const float4 sf = *(const float4*)(scale + f0);
    const float4 hf = *(const float4*)(shift + f0);
    float vacc[4][4];
    #pragma unroll
    for(int a=0;a<4;a++){ vacc[a][0]=0;vacc[a][1]=0;vacc[a][2]=0;vacc[a][3]=0; }
    const float* qbase = qbn + (size_t)b*256*128 + f0;
    for(int n=0;n<256;n++){
      float4 cv = *(const float4*)(Cs + n*36 + k4);
      float4 u  = *(const float4*)(qbase + (size_t)n*128);
      float u0 = u.x*sf.x+hf.x, u1 = u.y*sf.y+hf.y, u2 = u.z*sf.z+hf.z, u3 = u.w*sf.w+hf.w;
      float cr[4] = {cv.x,cv.y,cv.z,cv.w};
      #pragma unroll
      for(int a=0;a<4;a++){
        vacc[a][0] += cr[a]*u0;
        vacc[a][1] += cr[a]*u1;
        vacc[a][2] += cr[a]*u2;
        vacc[a][3] += cr[a]*u3;
      }
    }
    #pragma unroll
    for(int a=0;a<4;a++){
      Vs[(k4+a)*132 + f0 + 0] = vacc[a][0];
      Vs[(k4+a)*132 + f0 + 1] = vacc[a][1];
      Vs[(k4+a)*132 + f0 + 2] = vacc[a][2];
      Vs[(k4+a)*132 + f0 + 3] = vacc[a][3];
    }
  }
  __syncthreads();

  if(t==0) atomicAdd(klacc, 100.f*(red_s[0]+red_s[1]+red_s[2]+red_s[3]));

  for(int idx=t; idx<K1*MEMH; idx+=256){
    int k = idx/100, m = idx - k*100;
    float a = W[W_LINB0 + m];
    for(int f=0; f<128; f++) a += Vs[k*132+f]*W[W_LINW0 + f*100 + m];
    mq1[(size_t)(b*32+k)*100 + m] = (a>0.f) ? a : 0.01f*a;
  }
}

// ---------------- mem conv 1 ----------------
__global__ __launch_bounds__(256) void k_memconv1(
    const float* __restrict__ mq1, const float* __restrict__ W,
    const float* __restrict__ ksq, float* __restrict__ mq2, float* __restrict__ klacc)
{
  __shared__ float Qs[32*104];
  __shared__ float Ks[40*100];
  __shared__ float QKs[32*40];
  __shared__ float Cs[32*8];
  __shared__ float cn_s[8];
  __shared__ float pn_s[32];
  __shared__ float qsq_s[32];
  __shared__ float Vs[8*100];
  __shared__ float red_s[4];
  const int b = blockIdx.x, t = threadIdx.x;

  for(int idx=t; idx<32*100; idx+=256){
    int n = idx/100, f = idx - n*100;
    Qs[n*104+f] = mq1[(size_t)b*3200 + idx];
  }
  for(int idx=t; idx<40*100; idx+=256) Ks[idx] = W[W_KEYS1 + idx];
  __syncthreads();

  if(t < 32){ float s=0.f; for(int f=0;f<100;f++){ float v=Qs[t*104+f]; s+=v*v; } qsq_s[t]=s; }
  for(int idx=t; idx<32*40; idx+=256){
    int n = idx/40, c = idx - n*40;
    float a = 0.f;
    for(int f=0;f<100;f++) a += Qs[n*104+f]*Ks[c*100+f];
    QKs[idx] = a;
  }
  __syncthreads();

  if(t < 32){
    float wsum[8];
    #pragma unroll
    for(int k=0;k<8;k++) wsum[k]=0.f;
    for(int h=0;h<HEADS;h++){
      float cw = W[W_CONVW1 + h];
      float c[8]; float rs=0.f;
      #pragma unroll
      for(int k=0;k<8;k++){
        float d2 = qsq_s[t] + ksq[h*8+k] - 2.f*QKs[t*40 + h*8+k];
        d2 = fmaxf(d2, 1e-12f);
        float cc = 1.f/(1.f+d2);
        c[k]=cc; rs+=cc;
      }
      float sc = cw/fmaxf(rs, 1e-20f);
      #pragma unroll
      for(int k=0;k<8;k++) wsum[k] += c[k]*sc;
    }
    float mx = wsum[0];
    #pragma unroll
    for(int k=1;k<8;k++) mx = fmaxf(mx, wsum[k]);
    float se=0.f;
    #pragma unroll
    for(int k=0;k<8;k++){ float e=__expf(wsum[k]-mx); wsum[k]=e; se+=e; }
    float inv = 1.f/se;
    #pragma unroll
    for(int k=0;k<8;k++) Cs[t*8+k] = wsum[k]*inv;
  }
  __syncthreads();
  if(t < 8){ float s=0.f; for(int n=0;n<32;n++) s += Cs[n*8+t]; cn_s[t]=s+EPSF; }
  __syncthreads();
  if(t < 32){
    float p=0.f;
    #pragma unroll
    for(int k=0;k<8;k++){ float sv=Cs[t*8+k]; p += sv*sv/cn_s[k]; }
    pn_s[t]=p+EPSF;
  }
  __syncthreads();

  float acc;
  {
    int n = t>>3, k = t&7;
    float sv = Cs[t];
    float P = sv*sv/(cn_s[k]*pn_s[n]);
    acc = P*(__logf(P+EPSF) - __logf(sv+EPSF));
  }
  #pragma unroll
  for(int off=32; off>0; off>>=1) acc += __shfl_down(acc, off);
  if((t&63)==0) red_s[t>>6] = acc;

  for(int idx=t; idx<8*100; idx+=256){
    int k = idx/100, f = idx - k*100;
    float a=0.f;
    for(int n=0;n<32;n++) a += Cs[n*8+k]*Qs[n*104+f];
    Vs[idx] = a;
  }
  __syncthreads();

  if(t==0) atomicAdd(klacc, 100.f*(red_s[0]+red_s[1]+red_s[2]+red_s[3]));

  for(int idx=t; idx<8*100; idx+=256){
    int k = idx/100, m = idx - k*100;
    float a = W[W_LINB1 + m];
    for(int f=0;f<100;f++) a += Vs[k*100+f]*W[W_LINW1 + f*100 + m];
    mq2[(size_t)b*800 + idx] = (a>0.f) ? a : 0.01f*a;
  }
}

// ---------------- head ----------------
__global__ __launch_bounds__(128) void k_final(const float* __restrict__ mq2,
                                               const float* __restrict__ W,
                                               const int* __restrict__ flag,
                                               void* __restrict__ out){
  __shared__ float h_s[100];
  __shared__ float hid_s[50];
  const int b = blockIdx.x, t = threadIdx.x;
  if(t < 100){
    float s=0.f;
    #pragma unroll
    for(int k=0;k<8;k++) s += mq2[(size_t)b*800 + k*100 + t];
    h_s[t] = s*0.125f;
  }
  __syncthreads();
  if(t < 50){
    float a = W[W_MLPB1 + t];
    for(int f=0;f<100;f++) a += h_s[f]*W[W_MLPW1 + f*50 + t];
    hid_s[t] = (a>0.f) ? a : 0.01f*a;
  }
  __syncthreads();
  if(t < 12){
    float a = W[W_MLPB2 + t];
    #pragma unroll
    for(int j=0;j<50;j++) a += hid_s[j]*W[W_MLPW2 + j*12 + t];
    if(flag[0]) ((__hip_bfloat16*)out)[b*12+t] = __float2bfloat16(a);
    else        ((float*)out)[b*12+t] = a;
  }
}

__global__ void k_klout(const float* __restrict__ kl, const int* __restrict__ flag,
                        void* __restrict__ out){
  if(blockIdx.x==0 && threadIdx.x==0){
    float v = (kl[0]+kl[1]) * (1.f/65536.f);
    if(flag[0]) ((__hip_bfloat16*)out)[3072] = __float2bfloat16(v);
    else        ((float*)out)[3072] = v;
  }
}

// ---------------- launch ----------------
extern "C" void kernel_launch(void* const* d_in, const int* in_sizes, int n_in,
                              void* d_out, int out_size, void* d_ws, size_t ws_size,
                              hipStream_t stream) {
  (void)in_sizes; (void)n_in; (void)out_size; (void)ws_size;
  const void* x   = d_in[0];
  const int*  ei  = (const int*)d_in[1];
  const int* src = ei;
  const int* dst = ei + NEDGE;

  WPtrs wp;
  for(int i=0;i<20;i++) wp.p[i] = d_in[3+i];

  char* w = (char*)d_ws;
  int*    deg    = (int*)   (w + OFF_DEG);
  int*    cursor = (int*)   (w + OFF_CURSOR);
  int*    offs   = (int*)   (w + OFF_OFFS);
  double* bnsum  = (double*)(w + OFF_BNSUM);
  double* bnsq   = (double*)(w + OFF_BNSQ);
  float*  scale  = (float*) (w + OFF_SCALE);
  float*  shift  = (float*) (w + OFF_SHIFT);
  float*  ksq0   = (float*) (w + OFF_KSQ0);
  float*  ksq1   = (float*) (w + OFF_KSQ1);
  float*  kl     = (float*) (w + OFF_KL);
  int*    flag   = (int*)   (w + OFF_FLAG);
  float*  Wc     = (float*) (w + OFF_W);
  unsigned short* k0b = (unsigned short*)(w + OFF_K0B);
  unsigned short* wt1 = (unsigned short*)(w + OFF_WT1);   // aliases cursor (dead after k_fill)
  unsigned short* wt2 = (unsigned short*)(w + OFF_WT2);
  int*    csr    = (int*)   (w + OFF_CSR);
  float*  regA   = (float*) (w + OFF_A);
  float*  regB   = (float*) (w + OFF_B);
  float*  qkbuf  = (float*) (w + OFF_QK);
  float*  xc     = (float*) (w + OFF_C);
  float*  mq1    = (float*) (w + OFF_MQ1);
  float*  mq2    = (float*) (w + OFF_MQ2);

  float* aggr = regA;       // aggr64 (16MB) then aggr128 (32MB)
  float* qv   = regB;       // lin1 out
  float* qbn  = regA;       // lin2 writes in place over aggr128 rows

  // CSR build first (cursor dies), then weight conversions into the cursor region.
  k_detect <<<1,      64, 0, stream>>>((const unsigned short*)x, flag);
  k_init   <<<256,   256, 0, stream>>>(deg, cursor, (unsigned long long*)bnsum, (unsigned long long*)bnsq, kl);
  k_count  <<<4096,  256, 0, stream>>>(dst, deg);
  k_scan   <<<1,    1024, 0, stream>>>(deg, offs);
  k_fill   <<<4096,  256, 0, stream>>>(src, dst, offs, cursor, csr);
  k_cvtx   <<<16384, 256, 0, stream>>>(x, flag, xc);
  k_cvtw   <<<402,   256, 0, stream>>>(wp, flag, Wc);
  k_cvtk   <<<80,    256, 0, stream>>>(Wc, k0b);
  k_cvtwt  <<<64,    256, 0, stream>>>(Wc, wt1, wt2);
  k_aggr64 <<<16384, 256, 0, stream>>>(xc, offs, deg, csr, aggr);
  k_linm<64> <<<1024,256, 0, stream>>>(aggr, xc, wt1, Wc, W_BREL0, qv);
  k_aggr128<<<16384, 256, 0, stream>>>(qv, offs, deg, csr, aggr);
  k_linm<128><<<1024,256, 0, stream>>>(aggr, qv, wt2, Wc, W_BREL1, qbn);
  k_bnstats<<<512,   128, 0, stream>>>(qbn, bnsum, bnsq);
  k_bnfin  <<<1,     256, 0, stream>>>(bnsum, bnsq, Wc, scale, shift, ksq0, ksq1);
  k_qk     <<<1024,  256, 0, stream>>>(qbn, scale, shift, k0b, qkbuf);
  k_memconv0<<<256,  256, 0, stream>>>(qkbuf, qbn, scale, shift, Wc, ksq0, mq1, kl);
  k_memconv1<<<256,  256, 0, stream>>>(mq1, Wc, ksq1, mq2, kl+1);
  k_final  <<<256,   128, 0, stream>>>(mq2, Wc, flag, d_out);
  k_klout  <<<1,      64, 0, stream>>>(kl, flag, d_out);
}

// Round 8
// 631.554 us; speedup vs baseline: 1.8381x; 1.0154x over previous
//
#include <hip/hip_runtime.h>
#include <hip/hip_bf16.h>

#define NTOT   65536
#define NEDGE  1048576
#define HEADS  5
#define K1     32
#define K2     8
#define MEMH   100
#define EPSF   1e-8f

// ---- workspace layout (bytes) ----
#define OFF_DEG     0x0000000
#define OFF_CURSOR  0x0040000   // dead after k_fill -> WT planes
#define OFF_WT1     0x0040000
#define OFF_WT2     0x0050000   // ends 0x70000
#define OFF_OFFS    0x0080000
#define OFF_BNSUM   0x00C0000
#define OFF_BNSQ    0x00C0400
#define OFF_SCALE   0x00C0800
#define OFF_SHIFT   0x00C0A00
#define OFF_KSQ0    0x00C0C00
#define OFF_KSQ1    0x00C0E80
#define OFF_KL      0x00C0F40
#define OFF_FLAG    0x00C0F60
#define OFF_W       0x00C1000   // f32 weights, ends ~0x125680
#define OFF_K0B     0x0128000   // keys0 bf16, ends 0x132000
#define OFF_CN      0x0134000   // cn[256*32] f32, ends 0x13C000
#define OFF_CSR     0x0140000   // 4MB
#define OFF_A       0x0540000   // 32MB: aggr64/aggr128 -> qbn (in-place, lives to end)
#define OFF_B       0x2540000   // 32MB: xcb(8MB) -> qv(32MB) -> Cg(8MB)+V(4MB)
#define OFF_CG      0x2540000
#define OFF_V       0x2D40000
#define OFF_C       0x4540000   // 16MB: xc -> qvb (in-place via linm64) -> mq1/mq2 tail
#define OFF_MQ1     0x4D40000
#define OFF_MQ2     0x5060000
// peak ws: 0x5540000 (identical to R3-R7 proven footprint)

// ---- canonical weight offsets (floats) ----
#define W_WREL0  0
#define W_BREL0  8192
#define W_WROOT0 8320
#define W_WREL1  16512
#define W_BREL1  32896
#define W_WROOT1 33024
#define W_GAMMA  49408
#define W_BETA   49536
#define W_KEYS0  49664
#define W_CONVW0 70144
#define W_LINW0  70149
#define W_LINB0  82949
#define W_KEYS1  83049
#define W_CONVW1 87049
#define W_LINW1  87054
#define W_LINB1  97054
#define W_MLPW1  97154
#define W_MLPB1  102154
#define W_MLPW2  102204
#define W_MLPB2  102804
#define W_TOTAL  102816

typedef __attribute__((ext_vector_type(8))) short  bf16x8;
typedef __attribute__((ext_vector_type(4))) float  f32x4;

__device__ __forceinline__ float bf2f(unsigned short u){
  union { unsigned int i; float f; } v; v.i = ((unsigned int)u) << 16; return v.f;
}
__device__ __forceinline__ unsigned short f2bf(float f){
  union { float f; unsigned int i; } v; v.f = f;
  unsigned int r = (v.i + 0x7FFFu + ((v.i >> 16) & 1u)) >> 16;   // RNE
  return (unsigned short)r;
}

__device__ const int g_seg[21] = {0,8192,8320,16512,32896,33024,49408,49536,49664,
                                  70144,70149,82949,83049,87049,87054,97054,97154,
                                  102154,102204,102804,102816};
struct WPtrs { const void* p[20]; };

// ---------------- dtype probe ----------------
__global__ void k_detect(const unsigned short* __restrict__ xr, int* flag){
  int t = threadIdx.x & 63;
  unsigned short u = xr[2*t];
  int e = (u >> 7) & 0xFF;
  bool plaus = (u != 0) && (e >= 115) && (e <= 135);
  unsigned long long m = __ballot(plaus);
  if(t == 0) flag[0] = (__popcll(m) >= 48) ? 1 : 0;
}

__global__ __launch_bounds__(256) void k_cvtx(const void* __restrict__ xin,
                                              const int* __restrict__ flag,
                                              float* __restrict__ xout,
                                              unsigned short* __restrict__ xcb){
  int i = blockIdx.x*256 + threadIdx.x;          // NTOT*64
  float v;
  if(flag[0]) v = bf2f(((const unsigned short*)xin)[i]);
  else        v = ((const float*)xin)[i];
  xout[i] = v;
  xcb[i]  = f2bf(v);
}

__global__ __launch_bounds__(256) void k_cvtw(WPtrs wp, const int* __restrict__ flag,
                                              float* __restrict__ wout){
  int i = blockIdx.x*256 + threadIdx.x;
  if(i >= W_TOTAL) return;
  int s = 0;
  #pragma unroll
  for(int k=0;k<20;k++) if(i >= g_seg[k+1]) s = k+1;
  int j = i - g_seg[s];
  const void* src = wp.p[s];
  wout[i] = flag[0] ? bf2f(((const unsigned short*)src)[j]) : ((const float*)src)[j];
}

// keys0 bf16 + lin W^T bf16 hi/lo planes
__global__ __launch_bounds__(256) void k_cvtaux(const float* __restrict__ W,
                                                unsigned short* __restrict__ k0b,
                                                unsigned short* __restrict__ wt1,
                                                unsigned short* __restrict__ wt2){
  int i = blockIdx.x*256 + threadIdx.x;
  if(i < HEADS*K1*128) k0b[i] = f2bf(W[W_KEYS0 + i]);
  if(i < 128*64){
    int col = i>>6, k = i&63;
    float wr = W[W_WREL0  + k*128 + col];
    float wo = W[W_WROOT0 + k*128 + col];
    unsigned short rh = f2bf(wr), oh = f2bf(wo);
    wt1[i]         = rh;
    wt1[ 8192 + i] = f2bf(wr - bf2f(rh));
    wt1[16384 + i] = oh;
    wt1[24576 + i] = f2bf(wo - bf2f(oh));
  }
  if(i < 128*128){
    int col = i>>7, k = i&127;
    float wr = W[W_WREL1  + k*128 + col];
    float wo = W[W_WROOT1 + k*128 + col];
    unsigned short rh = f2bf(wr), oh = f2bf(wo);
    wt2[i]         = rh;
    wt2[16384 + i] = f2bf(wr - bf2f(rh));
    wt2[32768 + i] = oh;
    wt2[49152 + i] = f2bf(wo - bf2f(oh));
  }
}

// ---------------- init / CSR build ----------------
__global__ __launch_bounds__(256) void k_init(int* deg, int* cursor,
                                              unsigned long long* bnsum,
                                              unsigned long long* bnsq, float* kl, float* cn){
  int i = blockIdx.x*256 + threadIdx.x;
  if(i < NTOT){ deg[i]=0; cursor[i]=0; }
  if(i < 128){ bnsum[i]=0ULL; bnsq[i]=0ULL; }
  if(i < 2) kl[i]=0.f;
  if(i < 256*32) cn[i]=0.f;
}

__global__ __launch_bounds__(256) void k_count(const int* __restrict__ dst, int* deg){
  int e = blockIdx.x*256 + threadIdx.x;
  atomicAdd(&deg[dst[e]], 1);
}

__global__ __launch_bounds__(1024) void k_scan(const int* __restrict__ deg, int* __restrict__ offs){
  __shared__ int ts[1024];
  const int t = threadIdx.x;
  const int base = t*64;
  int s = 0;
  for(int i=0;i<64;i++) s += deg[base+i];
  ts[t] = s; __syncthreads();
  for(int off=1; off<1024; off<<=1){
    int v = (t>=off) ? ts[t-off] : 0;
    __syncthreads();
    ts[t] += v;
    __syncthreads();
  }
  int run = (t==0) ? 0 : ts[t-1];
  for(int i=0;i<64;i++){ offs[base+i]=run; run += deg[base+i]; }
}

__global__ __launch_bounds__(256) void k_fill(const int* __restrict__ src, const int* __restrict__ dst,
                                              const int* __restrict__ offs, int* cursor, int* __restrict__ csr){
  int e = blockIdx.x*256 + threadIdx.x;
  int d = dst[e];
  int p = atomicAdd(&cursor[d], 1);
  csr[offs[d] + p] = src[e];
}

// ---------------- graph aggregation (bf16 gathers, f32 accumulate) ----------------
__global__ __launch_bounds__(256) void k_aggr64(const unsigned short* __restrict__ xcb,
                                                const int* __restrict__ offs, const int* __restrict__ deg,
                                                const int* __restrict__ csr, float* __restrict__ aggr){
  const int wid  = (blockIdx.x*256 + threadIdx.x) >> 6;
  const int lane = threadIdx.x & 63;
  const int sub = lane >> 4, fl = lane & 15;
  const int beg = offs[wid], n = deg[wid];
  float4 acc = {0.f,0.f,0.f,0.f};
  int i = 0;
  for(; i+32 <= n; i += 32){
    int s[8];
    #pragma unroll
    for(int j=0;j<8;j++) s[j] = csr[beg + i + 4*j + sub];
    #pragma unroll
    for(int j=0;j<8;j++){
      ushort4 u = *(const ushort4*)(xcb + (size_t)s[j]*64 + fl*4);
      acc.x += bf2f(u.x); acc.y += bf2f(u.y); acc.z += bf2f(u.z); acc.w += bf2f(u.w);
    }
  }
  for(; i < n; i += 4){
    if(i + sub < n){
      int s = csr[beg + i + sub];
      ushort4 u = *(const ushort4*)(xcb + (size_t)s*64 + fl*4);
      acc.x += bf2f(u.x); acc.y += bf2f(u.y); acc.z += bf2f(u.z); acc.w += bf2f(u.w);
    }
  }
  acc.x += __shfl_xor(acc.x, 16); acc.y += __shfl_xor(acc.y, 16);
  acc.z += __shfl_xor(acc.z, 16); acc.w += __shfl_xor(acc.w, 16);
  acc.x += __shfl_xor(acc.x, 32); acc.y += __shfl_xor(acc.y, 32);
  acc.z += __shfl_xor(acc.z, 32); acc.w += __shfl_xor(acc.w, 32);
  if(sub == 0) *(float4*)(aggr + (size_t)wid*64 + fl*4) = acc;
}

__global__ __launch_bounds__(256) void k_aggr128(const unsigned short* __restrict__ qvb,
                                                 const int* __restrict__ offs, const int* __restrict__ deg,
                                                 const int* __restrict__ csr, float* __restrict__ aggr){
  const int wid  = (blockIdx.x*256 + threadIdx.x) >> 6;
  const int lane = threadIdx.x & 63;
  const int sub = lane >> 5, fl = lane & 31;
  const int beg = offs[wid], n = deg[wid];
  float4 acc = {0.f,0.f,0.f,0.f};
  int i = 0;
  for(; i+16 <= n; i += 16){
    int s[8];
    #pragma unroll
    for(int j=0;j<8;j++) s[j] = csr[beg + i + 2*j + sub];
    #pragma unroll
    for(int j=0;j<8;j++){
      ushort4 u = *(const ushort4*)(qvb + (size_t)s[j]*128 + fl*4);
      acc.x += bf2f(u.x); acc.y += bf2f(u.y); acc.z += bf2f(u.z); acc.w += bf2f(u.w);
    }
  }
  for(; i < n; i += 2){
    if(i + sub < n){
      int s = csr[beg + i + sub];
      ushort4 u = *(const ushort4*)(qvb + (size_t)s*128 + fl*4);
      acc.x += bf2f(u.x); acc.y += bf2f(u.y); acc.z += bf2f(u.z); acc.w += bf2f(u.w);
    }
  }
  acc.x += __shfl_xor(acc.x, 32); acc.y += __shfl_xor(acc.y, 32);
  acc.z += __shfl_xor(acc.z, 32); acc.w += __shfl_xor(acc.w, 32);
  if(sub == 0) *(float4*)(aggr + (size_t)wid*128 + fl*4) = acc;
}

// qv f32 -> qvb bf16 (NTOT*128)
__global__ __launch_bounds__(256) void k_cvtq(const float* __restrict__ qv,
                                              unsigned short* __restrict__ qvb){
  int i = blockIdx.x*256 + threadIdx.x;
  qvb[i] = f2bf(qv[i]);
}

// ---------------- lin via split-bf16 MFMA ----------------
template<int KD>
__global__ __launch_bounds__(256) void k_linm(const float* __restrict__ A,
                                              const float* __restrict__ X,
                                              const unsigned short* __restrict__ WT,
                                              const float* __restrict__ W, int bofs,
                                              float* __restrict__ out){
  __shared__ unsigned short Ah[64*72], Al[64*72], Xh[64*72], Xl[64*72];
  const int r0b = blockIdx.x*64;
  const int t = threadIdx.x;
  const int wv = t>>6, lane = t&63, quad = lane>>4, m = lane&15;
  const unsigned short* WRh = WT;
  const unsigned short* WRl = WT + 128*KD;
  const unsigned short* WOh = WT + 256*KD;
  const unsigned short* WOl = WT + 384*KD;
  f32x4 acc[8];
  #pragma unroll
  for(int ct=0; ct<8; ct++) acc[ct] = (f32x4){0.f,0.f,0.f,0.f};

  for(int kh=0; kh<KD; kh+=64){
    __syncthreads();
    for(int idx=t; idx<64*16; idx+=256){
      int r = idx>>4, k4 = (idx&15)*4;
      float4 va = *(const float4*)(A + (size_t)(r0b+r)*KD + kh + k4);
      float4 vx = *(const float4*)(X + (size_t)(r0b+r)*KD + kh + k4);
      ushort4 ah, al, xh, xl;
      ah.x=f2bf(va.x); al.x=f2bf(va.x-bf2f(ah.x));
      ah.y=f2bf(va.y); al.y=f2bf(va.y-bf2f(ah.y));
      ah.z=f2bf(va.z); al.z=f2bf(va.z-bf2f(ah.z));
      ah.w=f2bf(va.w); al.w=f2bf(va.w-bf2f(ah.w));
      xh.x=f2bf(vx.x); xl.x=f2bf(vx.x-bf2f(xh.x));
      xh.y=f2bf(vx.y); xl.y=f2bf(vx.y-bf2f(xh.y));
      xh.z=f2bf(vx.z); xl.z=f2bf(vx.z-bf2f(xh.z));
      xh.w=f2bf(vx.w); xl.w=f2bf(vx.w-bf2f(xh.w));
      *(ushort4*)(Ah + r*72 + k4) = ah;
      *(ushort4*)(Al + r*72 + k4) = al;
      *(ushort4*)(Xh + r*72 + k4) = xh;
      *(ushort4*)(Xl + r*72 + k4) = xl;
    }
    __syncthreads();
    #pragma unroll
    for(int ks=0; ks<2; ks++){
      const int ko = ks*32 + quad*8;
      bf16x8 fah = *(const bf16x8*)(Ah + (wv*16+m)*72 + ko);
      bf16x8 fal = *(const bf16x8*)(Al + (wv*16+m)*72 + ko);
      bf16x8 fxh = *(const bf16x8*)(Xh + (wv*16+m)*72 + ko);
      bf16x8 fxl = *(const bf16x8*)(Xl + (wv*16+m)*72 + ko);
      #pragma unroll
      for(int ct=0; ct<8; ct++){
        const size_t wo = (size_t)(ct*16+m)*KD + kh + ko;
        bf16x8 brh = *(const bf16x8*)(WRh + wo);
        bf16x8 brl = *(const bf16x8*)(WRl + wo);
        bf16x8 boh = *(const bf16x8*)(WOh + wo);
        bf16x8 bol = *(const bf16x8*)(WOl + wo);
        acc[ct] = __builtin_amdgcn_mfma_f32_16x16x32_bf16(fah, brh, acc[ct], 0,0,0);
        acc[ct] = __builtin_amdgcn_mfma_f32_16x16x32_bf16(fal, brh, acc[ct], 0,0,0);
        acc[ct] = __builtin_amdgcn_mfma_f32_16x16x32_bf16(fah, brl, acc[ct], 0,0,0);
        acc[ct] = __builtin_amdgcn_mfma_f32_16x16x32_bf16(fxh, boh, acc[ct], 0,0,0);
        acc[ct] = __builtin_amdgcn_mfma_f32_16x16x32_bf16(fxl, boh, acc[ct], 0,0,0);
        acc[ct] = __builtin_amdgcn_mfma_f32_16x16x32_bf16(fxh, bol, acc[ct], 0,0,0);
      }
    }
  }
  #pragma unroll
  for(int ct=0; ct<8; ct++){
    float b = W[bofs + ct*16 + m];
    #pragma unroll
    for(int i=0;i<4;i++){
      float v = acc[ct][i] + b;
      out[(size_t)(r0b + wv*16 + quad*4 + i)*128 + ct*16 + m] = fmaxf(v, 0.f);
    }
  }
}

// ---------------- batchnorm ----------------
__global__ __launch_bounds__(128) void k_bnstats(const float* __restrict__ qbn, double* bnsum, double* bnsq){
  const int j = threadIdx.x;
  const int r0 = blockIdx.x*128;
  float s=0.f, s2=0.f;
  for(int r=0;r<128;r++){ float v = qbn[(size_t)(r0+r)*128 + j]; s += v; s2 += v*v; }
  atomicAdd(&bnsum[j], (double)s);
  atomicAdd(&bnsq[j], (double)s2);
}

__global__ __launch_bounds__(256) void k_bnfin(const double* __restrict__ bnsum, const double* __restrict__ bnsq,
                                               const float* __restrict__ W,
                                               float* scale, float* shift, float* ksq0, float* ksq1){
  const int t = threadIdx.x;
  if(t < 128){
    double mu  = bnsum[t] / (double)NTOT;
    double var = bnsq[t] / (double)NTOT - mu*mu;
    if(var < 0.0) var = 0.0;
    float sc = W[W_GAMMA + t] * rsqrtf((float)var + 1e-5f);
    scale[t] = sc;
    shift[t] = W[W_BETA + t] - (float)mu * sc;
  }
  if(t < HEADS*K1){
    float s=0.f;
    for(int f=0;f<128;f++){ float v = W[W_KEYS0 + t*128 + f]; s += v*v; }
    ksq0[t] = s;
  }
  if(t < HEADS*K2){
    float s=0.f;
    for(int f=0;f<100;f++){ float v = W[W_KEYS1 + t*100 + f]; s += v*v; }
    ksq1[t] = s;
  }
}

// ---------------- memconv0 stage A: fused qk MFMA + C + partial cn ----------------
// grid 1024: block = 64 rows. BN+bf16 staging -> MFMA qk in LDS -> rs -> wsum ->
// softmax -> C to global + partial cn atomics.
__global__ __launch_bounds__(256) void k_memA(
    const float* __restrict__ qbn, const float* __restrict__ scale,
    const float* __restrict__ shift, const unsigned short* __restrict__ k0b,
    const float* __restrict__ W, const float* __restrict__ ksq,
    float* __restrict__ Cg, float* __restrict__ cn)
{
  __shared__ unsigned short Qb[64*136];
  __shared__ float qkL[160*68];        // [col][row]
  __shared__ float wsumL[64*36];
  __shared__ float qsqL[64];
  __shared__ float rsL[64*6];
  const int bid = blockIdx.x;
  const int r0 = bid*64;
  const int t = threadIdx.x;
  const int wv = t>>6, lane = t&63, quad = lane>>4, m = lane&15;

  for(int idx=t; idx<64*32; idx+=256){
    int r = idx>>5, c4 = (idx&31)*4;
    float4 u = *(const float4*)(qbn + (size_t)(r0+r)*128 + c4);
    float4 s = *(const float4*)(scale + c4);
    float4 h = *(const float4*)(shift + c4);
    ushort4 o;
    o.x = f2bf(u.x*s.x+h.x); o.y = f2bf(u.y*s.y+h.y);
    o.z = f2bf(u.z*s.z+h.z); o.w = f2bf(u.w*s.w+h.w);
    *(ushort4*)(Qb + r*136 + c4) = o;
  }
  __syncthreads();

  {
    bf16x8 a[4];
    #pragma unroll
    for(int ks=0;ks<4;ks++)
      a[ks] = *(const bf16x8*)(Qb + (wv*16+m)*136 + ks*32 + quad*8);
    for(int nb=0; nb<10; nb++){
      f32x4 acc = {0.f,0.f,0.f,0.f};
      const bf16x8* brow = (const bf16x8*)(k0b + (size_t)(nb*16+m)*128);
      #pragma unroll
      for(int ks=0;ks<4;ks++)
        acc = __builtin_amdgcn_mfma_f32_16x16x32_bf16(a[ks], brow[ks*4+quad], acc,0,0,0);
      *(f32x4*)(qkL + (nb*16+m)*68 + wv*16 + quad*4) = acc;   // col=nb*16+m, rows quad*4+i
    }
  }
  if(t < 64){
    float s = 0.f;
    for(int j=0;j<16;j++){
      bf16x8 v = *(const bf16x8*)(Qb + t*136 + j*8);
      #pragma unroll
      for(int e=0;e<8;e++){ float f = bf2f((unsigned short)v[e]); s += f*f; }
    }
    qsqL[t] = s;
  }
  __syncthreads();

  {
    int row = t & 63, g = t >> 6;
    float q2 = qsqL[row];
    #pragma unroll
    for(int pass=0; pass<2; pass++){
      int h = g + pass*4;
      if(h < HEADS){
        float rs = 0.f;
        for(int k=0;k<32;k++){
          float d2 = q2 + ksq[h*32+k] - 2.f*qkL[(h*32+k)*68 + row];
          d2 = fmaxf(d2, 1e-12f);
          rs += 1.f/(1.f+d2);
        }
        rsL[row*6+h] = W[W_CONVW0+h]/fmaxf(rs,1e-20f);
      }
    }
  }
  __syncthreads();

  {
    int row = t & 63, kq = t >> 6;
    float q2 = qsqL[row];
    for(int kk=0; kk<8; kk++){
      int k = kq*8+kk;
      float wsum = 0.f;
      #pragma unroll
      for(int h=0;h<HEADS;h++){
        float d2 = q2 + ksq[h*32+k] - 2.f*qkL[(h*32+k)*68 + row];
        d2 = fmaxf(d2, 1e-12f);
        wsum += rsL[row*6+h]/(1.f+d2);
      }
      wsumL[row*36+k] = wsum;
    }
  }
  __syncthreads();

  if(t < 64){
    float mx = -1e30f;
    #pragma unroll
    for(int k=0;k<32;k++) mx = fmaxf(mx, wsumL[t*36+k]);
    float cv[32]; float se = 0.f;
    #pragma unroll
    for(int k=0;k<32;k++){ float e = __expf(wsumL[t*36+k]-mx); cv[k]=e; se+=e; }
    float inv = 1.f/se;
    #pragma unroll
    for(int k=0;k<32;k++){ cv[k]*=inv; wsumL[t*36+k]=cv[k]; }
    float4* dst = (float4*)(Cg + (size_t)(r0+t)*32);
    #pragma unroll
    for(int k4=0;k4<8;k4++)
      dst[k4] = (float4){cv[k4*4],cv[k4*4+1],cv[k4*4+2],cv[k4*4+3]};
  }
  __syncthreads();
  if(t < 32){
    float s = 0.f;
    for(int r=0;r<64;r++) s += wsumL[r*36+t];
    atomicAdd(&cn[(bid>>2)*32 + t], s);
  }
}

// ---------------- memconv0 stage B: KL only ----------------
__global__ __launch_bounds__(256) void k_memB(const float* __restrict__ Cg,
                                              const float* __restrict__ cn,
                                              float* __restrict__ klacc){
  __shared__ float cn_s[32];
  __shared__ float red_s[4];
  const int b = blockIdx.x, t = threadIdx.x;
  if(t < 32) cn_s[t] = cn[b*32+t] + EPSF;
  __syncthreads();
  const float* crow = Cg + ((size_t)b*256 + t)*32;
  float cv[32]; float pn = 0.f;
  #pragma unroll
  for(int k4=0;k4<8;k4++){
    float4 u = *(const float4*)(crow + k4*4);
    cv[k4*4]=u.x; cv[k4*4+1]=u.y; cv[k4*4+2]=u.z; cv[k4*4+3]=u.w;
  }
  #pragma unroll
  for(int k=0;k<32;k++) pn += cv[k]*cv[k]/cn_s[k];
  pn += EPSF;
  float acc = 0.f;
  #pragma unroll
  for(int k=0;k<32;k++){
    float P = cv[k]*cv[k]/(cn_s[k]*pn);
    acc += P*(__logf(P+EPSF) - __logf(cv[k]+EPSF));
  }
  #pragma unroll
  for(int off=32; off>0; off>>=1) acc += __shfl_down(acc, off);
  if((t&63)==0) red_s[t>>6] = acc;
  __syncthreads();
  if(t==0) atomicAdd(klacc, 100.f*(red_s[0]+red_s[1]+red_s[2]+red_s[3]));
}

// ---------------- memconv0 stage V: V = C^T Q (grid 1024: batch x f-chunk) ----------
__global__ __launch_bounds__(256) void k_memV(const float* __restrict__ Cg,
                                              const float* __restrict__ qbn,
                                              const float* __restrict__ scale,
                                              const float* __restrict__ shift,
                                              float* __restrict__ V){
  __shared__ float Cs[256*36];
  __shared__ float Qs[256*32];
  const int b  = blockIdx.x >> 2;
  const int f0 = (blockIdx.x & 3) * 32;
  const int t = threadIdx.x;
  for(int idx=t; idx<256*8; idx+=256){
    int n = idx>>3, k4 = (idx&7)*4;
    *(float4*)(Cs + n*36 + k4) = *(const float4*)(Cg + ((size_t)b*256+n)*32 + k4);
  }
  for(int idx=t; idx<256*8; idx+=256){
    int n = idx>>3, j4 = (idx&7)*4;
    float4 u = *(const float4*)(qbn + ((size_t)b*256+n)*128 + f0 + j4);
    float4 s = *(const float4*)(scale + f0 + j4);
    float4 h = *(const float4*)(shift + f0 + j4);
    *(float4*)(Qs + n*32 + j4) = (float4){u.x*s.x+h.x, u.y*s.y+h.y, u.z*s.z+h.z, u.w*s.w+h.w};
  }
  __syncthreads();
  const int k = t & 31, fg = t >> 5;
  float v0=0.f,v1=0.f,v2=0.f,v3=0.f;
  for(int n=0;n<256;n++){
    float c = Cs[n*36+k];
    float4 q = *(const float4*)(Qs + n*32 + fg*4);
    v0 += c*q.x; v1 += c*q.y; v2 += c*q.z; v3 += c*q.w;
  }
  *(float4*)(V + ((size_t)b*32 + k)*128 + f0 + fg*4) = (float4){v0,v1,v2,v3};
}

// ---------------- memconv0 stage L: lin0 ----------------
__global__ __launch_bounds__(256) void k_memL(const float* __restrict__ V,
                                              const float* __restrict__ W,
                                              float* __restrict__ mq1){
  __shared__ float Vs[32*132];
  const int b = blockIdx.x, t = threadIdx.x;
  for(int idx=t; idx<32*32; idx+=256){
    int k = idx>>5, j4 = (idx&31)*4;
    *(float4*)(Vs + k*132 + j4) = *(const float4*)(V + ((size_t)b*32+k)*128 + j4);
  }
  __syncthreads();
  for(int idx=t; idx<K1*MEMH; idx+=256){
    int k = idx/100, mc = idx - k*100;
    float a = W[W_LINB0 + mc];
    for(int f=0; f<128; f++) a += Vs[k*132+f]*W[W_LINW0 + f*100 + mc];
    mq1[(size_t)(b*32+k)*100 + mc] = (a>0.f) ? a : 0.01f*a;
  }
}

// ---------------- mem conv 1 ----------------
__global__ __launch_bounds__(256) void k_memconv1(
    const float* __restrict__ mq1, const float* __restrict__ W,
    const float* __restrict__ ksq, float* __restrict__ mq2, float* __restrict__ klacc)
{
  __shared__ float Qs[32*104];
  __shared__ float Ks[40*100];
  __shared__ float QKs[32*40];
  __shared__ float Cs[32*8];
  __shared__ float cn_s[8];
  __shared__ float pn_s[32];
  __shared__ float qsq_s[32];
  __shared__ float Vs[8*100];
  __shared__ float red_s[4];
  const int b = blockIdx.x, t = threadIdx.x;

  for(int idx=t; idx<32*100; idx+=256){
    int n = idx/100, f = idx - n*100;
    Qs[n*104+f] = mq1[(size_t)b*3200 + idx];
  }
  for(int idx=t; idx<40*100; idx+=256) Ks[idx] = W[W_KEYS1 + idx];
  __syncthreads();

  if(t < 32){ float s=0.f; for(int f=0;f<100;f++){ float v=Qs[t*104+f]; s+=v*v; } qsq_s[t]=s; }
  for(int idx=t; idx<32*40; idx+=256){
    int n = idx/40, c = idx - n*40;
    float a = 0.f;
    for(int f=0;f<100;f++) a += Qs[n*104+f]*Ks[c*100+f];
    QKs[idx] = a;
  }
  __syncthreads();

  if(t < 32){
    float wsum[8];
    #pragma unroll
    for(int k=0;k<8;k++) wsum[k]=0.f;
    for(int h=0;h<HEADS;h++){
      float cw = W[W_CONVW1 + h];
      float c[8]; float rs=0.f;
      #pragma unroll
      for(int k=0;k<8;k++){
        float d2 = qsq_s[t] + ksq[h*8+k] - 2.f*QKs[t*40 + h*8+k];
        d2 = fmaxf(d2, 1e-12f);
        float cc = 1.f/(1.f+d2);
        c[k]=cc; rs+=cc;
      }
      float sc = cw/fmaxf(rs, 1e-20f);
      #pragma unroll
      for(int k=0;k<8;k++) wsum[k] += c[k]*sc;
    }
    float mx = wsum[0];
    #pragma unroll
    for(int k=1;k<8;k++) mx = fmaxf(mx, wsum[k]);
    float se=0.f;
    #pragma unroll
    for(int k=0;k<8;k++){ float e=__expf(wsum[k]-mx); wsum[k]=e; se+=e; }
    float inv = 1.f/se;
    #pragma unroll
    for(int k=0;k<8;k++) Cs[t*8+k] = wsum[k]*inv;
  }
  __syncthreads();
  if(t < 8){ float s=0.f; for(int n=0;n<32;n++) s += Cs[n*8+t]; cn_s[t]=s+EPSF; }
  __syncthreads();
  if(t < 32){
    float p=0.f;
    #pragma unroll
    for(int k=0;k<8;k++){ float sv=Cs[t*8+k]; p += sv*sv/cn_s[k]; }
    pn_s[t]=p+EPSF;
  }
  __syncthreads();

  float acc;
  {
    int n = t>>3, k = t&7;
    float sv = Cs[t];
    float P = sv*sv/(cn_s[k]*pn_s[n]);
    acc = P*(__logf(P+EPSF) - __logf(sv+EPSF));
  }
  #pragma unroll
  for(int off=32; off>0; off>>=1) acc += __shfl_down(acc, off);
  if((t&63)==0) red_s[t>>6] = acc;

  for(int idx=t; idx<8*100; idx+=256){
    int k = idx/100, f = idx - k*100;
    float a=0.f;
    for(int n=0;n<32;n++) a += Cs[n*8+k]*Qs[n*104+f];
    Vs[idx] = a;
  }
  __syncthreads();

  if(t==0) atomicAdd(klacc, 100.f*(red_s[0]+red_s[1]+red_s[2]+red_s[3]));

  for(int idx=t; idx<8*100; idx+=256){
    int k = idx/100, mc = idx - k*100;
    float a = W[W_LINB1 + mc];
    for(int f=0;f<100;f++) a += Vs[k*100+f]*W[W_LINW1 + f*100 + mc];
    mq2[(size_t)b*800 + idx] = (a>0.f) ? a : 0.01f*a;
  }
}

// ---------------- head (kl output folded in) ----------------
__global__ __launch_bounds__(128) void k_final(const float* __restrict__ mq2,
                                               const float* __restrict__ W,
                                               const int* __restrict__ flag,
                                               const float* __restrict__ kl,
                                               void* __restrict__ out){
  __shared__ float h_s[100];
  __shared__ float hid_s[50];
  const int b = blockIdx.x, t = threadIdx.x;
  if(t < 100){
    float s=0.f;
    #pragma unroll
    for(int k=0;k<8;k++) s += mq2[(size_t)b*800 + k*100 + t];
    h_s[t] = s*0.125f;
  }
  __syncthreads();
  if(t < 50){
    float a = W[W_MLPB1 + t];
    for(int f=0;f<100;f++) a += h_s[f]*W[W_MLPW1 + f*50 + t];
    hid_s[t] = (a>0.f) ? a : 0.01f*a;
  }
  __syncthreads();
  if(t < 12){
    float a = W[W_MLPB2 + t];
    #pragma unroll
    for(int j=0;j<50;j++) a += hid_s[j]*W[W_MLPW2 + j*12 + t];
    if(flag[0]) ((__hip_bfloat16*)out)[b*12+t] = __float2bfloat16(a);
    else        ((float*)out)[b*12+t] = a;
  }
  if(b==0 && t==64){
    float v = (kl[0]+kl[1]) * (1.f/65536.f);
    if(flag[0]) ((__hip_bfloat16*)out)[3072] = __float2bfloat16(v);
    else        ((float*)out)[3072] = v;
  }
}

// ---------------- launch ----------------
extern "C" void kernel_launch(void* const* d_in, const int* in_sizes, int n_in,
                              void* d_out, int out_size, void* d_ws, size_t ws_size,
                              hipStream_t stream) {
  (void)in_sizes; (void)n_in; (void)out_size; (void)ws_size;
  const void* x   = d_in[0];
  const int*  ei  = (const int*)d_in[1];
  const int* src = ei;
  const int* dst = ei + NEDGE;

  WPtrs wp;
  for(int i=0;i<20;i++) wp.p[i] = d_in[3+i];

  char* w = (char*)d_ws;
  int*    deg    = (int*)   (w + OFF_DEG);
  int*    cursor = (int*)   (w + OFF_CURSOR);
  int*    offs   = (int*)   (w + OFF_OFFS);
  double* bnsum  = (double*)(w + OFF_BNSUM);
  double* bnsq   = (double*)(w + OFF_BNSQ);
  float*  scale  = (float*) (w + OFF_SCALE);
  float*  shift  = (float*) (w + OFF_SHIFT);
  float*  ksq0   = (float*) (w + OFF_KSQ0);
  float*  ksq1   = (float*) (w + OFF_KSQ1);
  float*  kl     = (float*) (w + OFF_KL);
  int*    flag   = (int*)   (w + OFF_FLAG);
  float*  Wc     = (float*) (w + OFF_W);
  unsigned short* k0b = (unsigned short*)(w + OFF_K0B);
  unsigned short* wt1 = (unsigned short*)(w + OFF_WT1);
  unsigned short* wt2 = (unsigned short*)(w + OFF_WT2);
  float*  cn     = (float*) (w + OFF_CN);
  int*    csr    = (int*)   (w + OFF_CSR);
  float*  regA   = (float*) (w + OFF_A);
  float*  qv     = (float*) (w + OFF_B);
  unsigned short* xcb = (unsigned short*)(w + OFF_B);   // 8MB, dead before qv written
  float*  Cg     = (float*) (w + OFF_CG);               // after qv dead
  float*  Vbuf   = (float*) (w + OFF_V);
  float*  xc     = (float*) (w + OFF_C);
  unsigned short* qvb = (unsigned short*)(w + OFF_C);   // overlays xc (in-place via cvtq after linm64)
  float*  mq1    = (float*) (w + OFF_MQ1);
  float*  mq2    = (float*) (w + OFF_MQ2);

  float* aggr = regA;
  float* qbn  = regA;   // linm<128> writes in place over aggr rows

  k_detect <<<1,      64, 0, stream>>>((const unsigned short*)x, flag);
  k_init   <<<256,   256, 0, stream>>>(deg, cursor, (unsigned long long*)bnsum, (unsigned long long*)bnsq, kl, cn);
  k_count  <<<4096,  256, 0, stream>>>(dst, deg);
  k_scan   <<<1,    1024, 0, stream>>>(deg, offs);
  k_fill   <<<4096,  256, 0, stream>>>(src, dst, offs, cursor, csr);
  k_cvtx   <<<16384, 256, 0, stream>>>(x, flag, xc, xcb);
  k_cvtw   <<<402,   256, 0, stream>>>(wp, flag, Wc);
  k_cvtaux <<<80,    256, 0, stream>>>(Wc, k0b, wt1, wt2);
  k_aggr64 <<<16384, 256, 0, stream>>>(xcb, offs, deg, csr, aggr);
  k_linm<64> <<<1024,256, 0, stream>>>(aggr, xc, wt1, Wc, W_BREL0, qv);
  k_cvtq   <<<32768, 256, 0, stream>>>(qv, qvb);
  k_aggr128<<<16384, 256, 0, stream>>>(qvb, offs, deg, csr, aggr);
  k_linm<128><<<1024,256, 0, stream>>>(aggr, qv, wt2, Wc, W_BREL1, qbn);
  k_bnstats<<<512,   128, 0, stream>>>(qbn, bnsum, bnsq);
  k_bnfin  <<<1,     256, 0, stream>>>(bnsum, bnsq, Wc, scale, shift, ksq0, ksq1);
  k_memA   <<<1024,  256, 0, stream>>>(qbn, scale, shift, k0b, Wc, ksq0, Cg, cn);
  k_memB   <<<256,   256, 0, stream>>>(Cg, cn, kl);
  k_memV   <<<1024,  256, 0, stream>>>(Cg, qbn, scale, shift, Vbuf);
  k_memL   <<<256,   256, 0, stream>>>(Vbuf, Wc, mq1);
  k_memconv1<<<256,  256, 0, stream>>>(mq1, Wc, ksq1, mq2, kl+1);
  k_final  <<<256,   128, 0, stream>>>(mq2, Wc, flag, kl, d_out);
}

// Round 9
// 623.468 us; speedup vs baseline: 1.8619x; 1.0130x over previous
//
#include <hip/hip_runtime.h>
#include <hip/hip_bf16.h>

#define NTOT   65536
#define NEDGE  1048576
#define HEADS  5
#define K1     32
#define K2     8
#define MEMH   100
#define EPSF   1e-8f

// ---- workspace layout (bytes) ----
#define OFF_DEG     0x0000000
#define OFF_CURSOR  0x0040000   // dead after k_fill -> WT planes
#define OFF_WT1     0x0040000
#define OFF_WT2     0x0050000   // ends 0x70000
#define OFF_OFFS    0x0080000
#define OFF_BNSUM   0x00C0000
#define OFF_BNSQ    0x00C0400
#define OFF_SCALE   0x00C0800
#define OFF_SHIFT   0x00C0A00
#define OFF_KSQ0    0x00C0C00
#define OFF_KSQ1    0x00C0E80
#define OFF_KL      0x00C0F40
#define OFF_FLAG    0x00C0F60
#define OFF_W       0x00C1000   // f32 weights, ends ~0x125680
#define OFF_K0B     0x0128000   // keys0 bf16 (40KB)
#define OFF_CN      0x0134000   // cn[256*32] f32
#define OFF_CSR     0x0140000   // ushort csr: 2MB (0x140000..0x340000)
#define OFF_A       0x0540000   // 32MB: agH64(8)+agL64(8) -> agH128(16)+agL128(16)
#define OFF_AH128   0x0540000
#define OFF_AL128   0x1540000
#define OFF_AH64    0x0540000
#define OFF_AL64    0x0D40000
#define OFF_B       0x2540000   // 32MB: qvH(16)+qvL(16) -> qbnH/qbnL in place
#define OFF_QH      0x2540000
#define OFF_QL      0x3540000
#define OFF_C       0x4540000   // 16MB: xcH(8)+xcL(8) -> Cg(8)+V(4)+mq1(3.2)+mq2(0.8)
#define OFF_XH      0x4540000
#define OFF_XL      0x4D40000
#define OFF_CG      0x4540000
#define OFF_V       0x4D40000
#define OFF_MQ1     0x5140000
#define OFF_MQ2     0x5460000
// peak ws: 0x5540000 (identical to proven footprint)

// ---- canonical weight offsets (floats) ----
#define W_WREL0  0
#define W_BREL0  8192
#define W_WROOT0 8320
#define W_WREL1  16512
#define W_BREL1  32896
#define W_WROOT1 33024
#define W_GAMMA  49408
#define W_BETA   49536
#define W_KEYS0  49664
#define W_CONVW0 70144
#define W_LINW0  70149
#define W_LINB0  82949
#define W_KEYS1  83049
#define W_CONVW1 87049
#define W_LINW1  87054
#define W_LINB1  97054
#define W_MLPW1  97154
#define W_MLPB1  102154
#define W_MLPW2  102204
#define W_MLPB2  102804
#define W_TOTAL  102816

typedef __attribute__((ext_vector_type(8))) short  bf16x8;
typedef __attribute__((ext_vector_type(4))) float  f32x4;

__device__ __forceinline__ float bf2f(unsigned short u){
  union { unsigned int i; float f; } v; v.i = ((unsigned int)u) << 16; return v.f;
}
__device__ __forceinline__ unsigned short f2bf(float f){
  union { float f; unsigned int i; } v; v.f = f;
  unsigned int r = (v.i + 0x7FFFu + ((v.i >> 16) & 1u)) >> 16;   // RNE
  return (unsigned short)r;
}

__device__ const int g_seg[21] = {0,8192,8320,16512,32896,33024,49408,49536,49664,
                                  70144,70149,82949,83049,87049,87054,97054,97154,
                                  102154,102204,102804,102816};
struct WPtrs { const void* p[20]; };

// ---------------- dtype probe ----------------
__global__ void k_detect(const unsigned short* __restrict__ xr, int* flag){
  int t = threadIdx.x & 63;
  unsigned short u = xr[2*t];
  int e = (u >> 7) & 0xFF;
  bool plaus = (u != 0) && (e >= 115) && (e <= 135);
  unsigned long long m = __ballot(plaus);
  if(t == 0) flag[0] = (__popcll(m) >= 48) ? 1 : 0;
}

// x -> bf16 hi/lo planes
__global__ __launch_bounds__(256) void k_cvtx(const void* __restrict__ xin,
                                              const int* __restrict__ flag,
                                              unsigned short* __restrict__ xH,
                                              unsigned short* __restrict__ xL){
  int i = blockIdx.x*256 + threadIdx.x;          // NTOT*64
  float v;
  if(flag[0]) v = bf2f(((const unsigned short*)xin)[i]);
  else        v = ((const float*)xin)[i];
  unsigned short h = f2bf(v);
  xH[i] = h;
  xL[i] = f2bf(v - bf2f(h));
}

__global__ __launch_bounds__(256) void k_cvtw(WPtrs wp, const int* __restrict__ flag,
                                              float* __restrict__ wout){
  int i = blockIdx.x*256 + threadIdx.x;
  if(i >= W_TOTAL) return;
  int s = 0;
  #pragma unroll
  for(int k=0;k<20;k++) if(i >= g_seg[k+1]) s = k+1;
  int j = i - g_seg[s];
  const void* src = wp.p[s];
  wout[i] = flag[0] ? bf2f(((const unsigned short*)src)[j]) : ((const float*)src)[j];
}

// keys0 bf16 + lin W^T bf16 hi/lo planes
__global__ __launch_bounds__(256) void k_cvtaux(const float* __restrict__ W,
                                                unsigned short* __restrict__ k0b,
                                                unsigned short* __restrict__ wt1,
                                                unsigned short* __restrict__ wt2){
  int i = blockIdx.x*256 + threadIdx.x;
  if(i < HEADS*K1*128) k0b[i] = f2bf(W[W_KEYS0 + i]);
  if(i < 128*64){
    int col = i>>6, k = i&63;
    float wr = W[W_WREL0  + k*128 + col];
    float wo = W[W_WROOT0 + k*128 + col];
    unsigned short rh = f2bf(wr), oh = f2bf(wo);
    wt1[i]         = rh;
    wt1[ 8192 + i] = f2bf(wr - bf2f(rh));
    wt1[16384 + i] = oh;
    wt1[24576 + i] = f2bf(wo - bf2f(oh));
  }
  if(i < 128*128){
    int col = i>>7, k = i&127;
    float wr = W[W_WREL1  + k*128 + col];
    float wo = W[W_WROOT1 + k*128 + col];
    unsigned short rh = f2bf(wr), oh = f2bf(wo);
    wt2[i]         = rh;
    wt2[16384 + i] = f2bf(wr - bf2f(rh));
    wt2[32768 + i] = oh;
    wt2[49152 + i] = f2bf(wo - bf2f(oh));
  }
}

// ---------------- init / CSR build ----------------
__global__ __launch_bounds__(256) void k_init(int* deg, int* cursor,
                                              unsigned long long* bnsum,
                                              unsigned long long* bnsq, float* kl, float* cn){
  int i = blockIdx.x*256 + threadIdx.x;
  if(i < NTOT){ deg[i]=0; cursor[i]=0; }
  if(i < 128){ bnsum[i]=0ULL; bnsq[i]=0ULL; }
  if(i < 2) kl[i]=0.f;
  if(i < 256*32) cn[i]=0.f;
}

__global__ __launch_bounds__(256) void k_count(const int* __restrict__ dst, int* deg){
  int e = blockIdx.x*256 + threadIdx.x;
  atomicAdd(&deg[dst[e]], 1);
}

__global__ __launch_bounds__(1024) void k_scan(const int* __restrict__ deg, int* __restrict__ offs){
  __shared__ int ts[1024];
  const int t = threadIdx.x;
  const int base = t*64;
  int s = 0;
  for(int i=0;i<64;i++) s += deg[base+i];
  ts[t] = s; __syncthreads();
  for(int off=1; off<1024; off<<=1){
    int v = (t>=off) ? ts[t-off] : 0;
    __syncthreads();
    ts[t] += v;
    __syncthreads();
  }
  int run = (t==0) ? 0 : ts[t-1];
  for(int i=0;i<64;i++){ offs[base+i]=run; run += deg[base+i]; }
}

__global__ __launch_bounds__(256) void k_fill(const int* __restrict__ src, const int* __restrict__ dst,
                                              const int* __restrict__ offs, int* cursor,
                                              unsigned short* __restrict__ csr){
  int e = blockIdx.x*256 + threadIdx.x;
  int d = dst[e];
  int p = atomicAdd(&cursor[d], 1);
  csr[offs[d] + p] = (unsigned short)src[e];
}

// ---------------- graph aggregation (bf16 gathers, f32 acc, hi/lo out) --------
__global__ __launch_bounds__(256) void k_aggr64(const unsigned short* __restrict__ xH,
                                                const int* __restrict__ offs, const int* __restrict__ deg,
                                                const unsigned short* __restrict__ csr,
                                                unsigned short* __restrict__ aH,
                                                unsigned short* __restrict__ aL){
  const int wid  = (blockIdx.x*256 + threadIdx.x) >> 6;
  const int lane = threadIdx.x & 63;
  const int sub = lane >> 4, fl = lane & 15;
  const int beg = offs[wid], n = deg[wid];
  float4 acc = {0.f,0.f,0.f,0.f};
  int i = 0;
  for(; i+32 <= n; i += 32){
    int s[8];
    #pragma unroll
    for(int j=0;j<8;j++) s[j] = csr[beg + i + 4*j + sub];
    #pragma unroll
    for(int j=0;j<8;j++){
      ushort4 u = *(const ushort4*)(xH + (size_t)s[j]*64 + fl*4);
      acc.x += bf2f(u.x); acc.y += bf2f(u.y); acc.z += bf2f(u.z); acc.w += bf2f(u.w);
    }
  }
  for(; i < n; i += 4){
    if(i + sub < n){
      int s = csr[beg + i + sub];
      ushort4 u = *(const ushort4*)(xH + (size_t)s*64 + fl*4);
      acc.x += bf2f(u.x); acc.y += bf2f(u.y); acc.z += bf2f(u.z); acc.w += bf2f(u.w);
    }
  }
  acc.x += __shfl_xor(acc.x, 16); acc.y += __shfl_xor(acc.y, 16);
  acc.z += __shfl_xor(acc.z, 16); acc.w += __shfl_xor(acc.w, 16);
  acc.x += __shfl_xor(acc.x, 32); acc.y += __shfl_xor(acc.y, 32);
  acc.z += __shfl_xor(acc.z, 32); acc.w += __shfl_xor(acc.w, 32);
  if(sub == 0){
    ushort4 h, l;
    h.x=f2bf(acc.x); l.x=f2bf(acc.x-bf2f(h.x));
    h.y=f2bf(acc.y); l.y=f2bf(acc.y-bf2f(h.y));
    h.z=f2bf(acc.z); l.z=f2bf(acc.z-bf2f(h.z));
    h.w=f2bf(acc.w); l.w=f2bf(acc.w-bf2f(h.w));
    *(ushort4*)(aH + (size_t)wid*64 + fl*4) = h;
    *(ushort4*)(aL + (size_t)wid*64 + fl*4) = l;
  }
}

__global__ __launch_bounds__(256) void k_aggr128(const unsigned short* __restrict__ qH,
                                                 const int* __restrict__ offs, const int* __restrict__ deg,
                                                 const unsigned short* __restrict__ csr,
                                                 unsigned short* __restrict__ aH,
                                                 unsigned short* __restrict__ aL){
  const int wid  = (blockIdx.x*256 + threadIdx.x) >> 6;
  const int lane = threadIdx.x & 63;
  const int sub = lane >> 5, fl = lane & 31;
  const int beg = offs[wid], n = deg[wid];
  float4 acc = {0.f,0.f,0.f,0.f};
  int i = 0;
  for(; i+16 <= n; i += 16){
    int s[8];
    #pragma unroll
    for(int j=0;j<8;j++) s[j] = csr[beg + i + 2*j + sub];
    #pragma unroll
    for(int j=0;j<8;j++){
      ushort4 u = *(const ushort4*)(qH + (size_t)s[j]*128 + fl*4);
      acc.x += bf2f(u.x); acc.y += bf2f(u.y); acc.z += bf2f(u.z); acc.w += bf2f(u.w);
    }
  }
  for(; i < n; i += 2){
    if(i + sub < n){
      int s = csr[beg + i + sub];
      ushort4 u = *(const ushort4*)(qH + (size_t)s*128 + fl*4);
      acc.x += bf2f(u.x); acc.y += bf2f(u.y); acc.z += bf2f(u.z); acc.w += bf2f(u.w);
    }
  }
  acc.x += __shfl_xor(acc.x, 32); acc.y += __shfl_xor(acc.y, 32);
  acc.z += __shfl_xor(acc.z, 32); acc.w += __shfl_xor(acc.w, 32);
  if(sub == 0){
    ushort4 h, l;
    h.x=f2bf(acc.x); l.x=f2bf(acc.x-bf2f(h.x));
    h.y=f2bf(acc.y); l.y=f2bf(acc.y-bf2f(h.y));
    h.z=f2bf(acc.z); l.z=f2bf(acc.z-bf2f(h.z));
    h.w=f2bf(acc.w); l.w=f2bf(acc.w-bf2f(h.w));
    *(ushort4*)(aH + (size_t)wid*128 + fl*4) = h;
    *(ushort4*)(aL + (size_t)wid*128 + fl*4) = l;
  }
}

// ---------------- lin via split-bf16 MFMA, LDS-free / barrier-free ------------
// out = relu(A@Wrel + X@Wroot + b); A,X given as bf16 hi/lo planes; per-wave
// direct global fragment loads (m89 layouts). Output written as hi/lo planes.
template<int KD>
__global__ __launch_bounds__(256) void k_linm2(const unsigned short* __restrict__ AH,
                                               const unsigned short* __restrict__ AL,
                                               const unsigned short* __restrict__ XH,
                                               const unsigned short* __restrict__ XL,
                                               const unsigned short* __restrict__ WT,
                                               const float* __restrict__ W, int bofs,
                                               unsigned short* __restrict__ outH,
                                               unsigned short* __restrict__ outL){
  const int t = threadIdx.x;
  const int wv = t>>6, lane = t&63, quad = lane>>4, m = lane&15;
  const int m0 = (blockIdx.x*4 + wv)*16;
  const int row = m0 + m;
  constexpr int NK = KD/32;
  bf16x8 fah[NK], fal[NK], fxh[NK], fxl[NK];
  #pragma unroll
  for(int ks=0; ks<NK; ks++){
    const size_t o = (size_t)row*KD + ks*32 + quad*8;
    fah[ks] = *(const bf16x8*)(AH + o);
    fal[ks] = *(const bf16x8*)(AL + o);
    fxh[ks] = *(const bf16x8*)(XH + o);
    fxl[ks] = *(const bf16x8*)(XL + o);
  }
  const unsigned short* WRh = WT;
  const unsigned short* WRl = WT + 128*KD;
  const unsigned short* WOh = WT + 256*KD;
  const unsigned short* WOl = WT + 384*KD;
  #pragma unroll
  for(int ct=0; ct<8; ct++){
    f32x4 acc = {0.f,0.f,0.f,0.f};
    #pragma unroll
    for(int ks=0; ks<NK; ks++){
      const size_t wo = (size_t)(ct*16+m)*KD + ks*32 + quad*8;
      bf16x8 brh = *(const bf16x8*)(WRh + wo);
      bf16x8 brl = *(const bf16x8*)(WRl + wo);
      bf16x8 boh = *(const bf16x8*)(WOh + wo);
      bf16x8 bol = *(const bf16x8*)(WOl + wo);
      acc = __builtin_amdgcn_mfma_f32_16x16x32_bf16(fah[ks], brh, acc, 0,0,0);
      acc = __builtin_amdgcn_mfma_f32_16x16x32_bf16(fal[ks], brh, acc, 0,0,0);
      acc = __builtin_amdgcn_mfma_f32_16x16x32_bf16(fah[ks], brl, acc, 0,0,0);
      acc = __builtin_amdgcn_mfma_f32_16x16x32_bf16(fxh[ks], boh, acc, 0,0,0);
      acc = __builtin_amdgcn_mfma_f32_16x16x32_bf16(fxl[ks], boh, acc, 0,0,0);
      acc = __builtin_amdgcn_mfma_f32_16x16x32_bf16(fxh[ks], bol, acc, 0,0,0);
    }
    float b = W[bofs + ct*16 + m];
    #pragma unroll
    for(int i=0;i<4;i++){
      float v = fmaxf(acc[i] + b, 0.f);
      unsigned short h = f2bf(v);
      size_t o = (size_t)(m0 + quad*4 + i)*128 + ct*16 + m;
      outH[o] = h;
      outL[o] = f2bf(v - bf2f(h));
    }
  }
}

// ---------------- batchnorm ----------------
__global__ __launch_bounds__(128) void k_bnstats(const unsigned short* __restrict__ qH,
                                                 const unsigned short* __restrict__ qL,
                                                 double* bnsum, double* bnsq){
  const int j = threadIdx.x;
  const int r0 = blockIdx.x*128;
  float s=0.f, s2=0.f;
  for(int r=0;r<128;r++){
    size_t o = (size_t)(r0+r)*128 + j;
    float v = bf2f(qH[o]) + bf2f(qL[o]);
    s += v; s2 += v*v;
  }
  atomicAdd(&bnsum[j], (double)s);
  atomicAdd(&bnsq[j], (double)s2);
}

__global__ __launch_bounds__(256) void k_bnfin(const double* __restrict__ bnsum, const double* __restrict__ bnsq,
                                               const float* __restrict__ W,
                                               float* scale, float* shift, float* ksq0, float* ksq1){
  const int t = threadIdx.x;
  if(t < 128){
    double mu  = bnsum[t] / (double)NTOT;
    double var = bnsq[t] / (double)NTOT - mu*mu;
    if(var < 0.0) var = 0.0;
    float sc = W[W_GAMMA + t] * rsqrtf((float)var + 1e-5f);
    scale[t] = sc;
    shift[t] = W[W_BETA + t] - (float)mu * sc;
  }
  if(t < HEADS*K1){
    float s=0.f;
    for(int f=0;f<128;f++){ float v = W[W_KEYS0 + t*128 + f]; s += v*v; }
    ksq0[t] = s;
  }
  if(t < HEADS*K2){
    float s=0.f;
    for(int f=0;f<100;f++){ float v = W[W_KEYS1 + t*100 + f]; s += v*v; }
    ksq1[t] = s;
  }
}

// ---------------- memconv0 stage A: fused qk MFMA + C + partial cn ------------
__global__ __launch_bounds__(256) void k_memA(
    const unsigned short* __restrict__ qH, const unsigned short* __restrict__ qL,
    const float* __restrict__ scale, const float* __restrict__ shift,
    const unsigned short* __restrict__ k0b,
    const float* __restrict__ W, const float* __restrict__ ksq,
    float* __restrict__ Cg, float* __restrict__ cn)
{
  __shared__ unsigned short Qb[64*136];
  __shared__ float qkL[160*68];        // [col][row]
  __shared__ float wsumL[64*36];
  __shared__ float qsqL[64];
  __shared__ float rsL[64*6];
  const int bid = blockIdx.x;
  const int r0 = bid*64;
  const int t = threadIdx.x;
  const int wv = t>>6, lane = t&63, quad = lane>>4, m = lane&15;

  for(int idx=t; idx<64*32; idx+=256){
    int r = idx>>5, c4 = (idx&31)*4;
    size_t o = (size_t)(r0+r)*128 + c4;
    ushort4 uh = *(const ushort4*)(qH + o);
    ushort4 ul = *(const ushort4*)(qL + o);
    float4 s = *(const float4*)(scale + c4);
    float4 h = *(const float4*)(shift + c4);
    ushort4 ob;
    ob.x = f2bf((bf2f(uh.x)+bf2f(ul.x))*s.x + h.x);
    ob.y = f2bf((bf2f(uh.y)+bf2f(ul.y))*s.y + h.y);
    ob.z = f2bf((bf2f(uh.z)+bf2f(ul.z))*s.z + h.z);
    ob.w = f2bf((bf2f(uh.w)+bf2f(ul.w))*s.w + h.w);
    *(ushort4*)(Qb + r*136 + c4) = ob;
  }
  __syncthreads();

  {
    bf16x8 a[4];
    #pragma unroll
    for(int ks=0;ks<4;ks++)
      a[ks] = *(const bf16x8*)(Qb + (wv*16+m)*136 + ks*32 + quad*8);
    for(int nb=0; nb<10; nb++){
      f32x4 acc = {0.f,0.f,0.f,0.f};
      const bf16x8* brow = (const bf16x8*)(k0b + (size_t)(nb*16+m)*128);
      #pragma unroll
      for(int ks=0;ks<4;ks++)
        acc = __builtin_amdgcn_mfma_f32_16x16x32_bf16(a[ks], brow[ks*4+quad], acc,0,0,0);
      *(f32x4*)(qkL + (nb*16+m)*68 + wv*16 + quad*4) = acc;
    }
  }
  if(t < 64){
    float s = 0.f;
    for(int j=0;j<16;j++){
      bf16x8 v = *(const bf16x8*)(Qb + t*136 + j*8);
      #pragma unroll
      for(int e=0;e<8;e++){ float f = bf2f((unsigned short)v[e]); s += f*f; }
    }
    qsqL[t] = s;
  }
  __syncthreads();

  {
    int row = t & 63, g = t >> 6;
    float q2 = qsqL[row];
    #pragma unroll
    for(int pass=0; pass<2; pass++){
      int h = g + pass*4;
      if(h < HEADS){
        float rs = 0.f;
        for(int k=0;k<32;k++){
          float d2 = q2 + ksq[h*32+k] - 2.f*qkL[(h*32+k)*68 + row];
          d2 = fmaxf(d2, 1e-12f);
          rs += 1.f/(1.f+d2);
        }
        rsL[row*6+h] = W[W_CONVW0+h]/fmaxf(rs,1e-20f);
      }
    }
  }
  __syncthreads();

  {
    int row = t & 63, kq = t >> 6;
    float q2 = qsqL[row];
    for(int kk=0; kk<8; kk++){
      int k = kq*8+kk;
      float wsum = 0.f;
      #pragma unroll
      for(int h=0;h<HEADS;h++){
        float d2 = q2 + ksq[h*32+k] - 2.f*qkL[(h*32+k)*68 + row];
        d2 = fmaxf(d2, 1e-12f);
        wsum += rsL[row*6+h]/(1.f+d2);
      }
      wsumL[row*36+k] = wsum;
    }
  }
  __syncthreads();

  if(t < 64){
    float mx = -1e30f;
    #pragma unroll
    for(int k=0;k<32;k++) mx = fmaxf(mx, wsumL[t*36+k]);
    float cv[32]; float se = 0.f;
    #pragma unroll
    for(int k=0;k<32;k++){ float e = __expf(wsumL[t*36+k]-mx); cv[k]=e; se+=e; }
    float inv = 1.f/se;
    #pragma unroll
    for(int k=0;k<32;k++){ cv[k]*=inv; wsumL[t*36+k]=cv[k]; }
    float4* dst = (float4*)(Cg + (size_t)(r0+t)*32);
    #pragma unroll
    for(int k4=0;k4<8;k4++)
      dst[k4] = (float4){cv[k4*4],cv[k4*4+1],cv[k4*4+2],cv[k4*4+3]};
  }
  __syncthreads();
  if(t < 32){
    float s = 0.f;
    for(int r=0;r<64;r++) s += wsumL[r*36+t];
    atomicAdd(&cn[(bid>>2)*32 + t], s);
  }
}

// ---------------- memconv0 stage B: KL ----------------
__global__ __launch_bounds__(256) void k_memB(const float* __restrict__ Cg,
                                              const float* __restrict__ cn,
                                              float* __restrict__ klacc){
  __shared__ float cn_s[32];
  __shared__ float red_s[4];
  const int b = blockIdx.x, t = threadIdx.x;
  if(t < 32) cn_s[t] = cn[b*32+t] + EPSF;
  __syncthreads();
  const float* crow = Cg + ((size_t)b*256 + t)*32;
  float cv[32]; float pn = 0.f;
  #pragma unroll
  for(int k4=0;k4<8;k4++){
    float4 u = *(const float4*)(crow + k4*4);
    cv[k4*4]=u.x; cv[k4*4+1]=u.y; cv[k4*4+2]=u.z; cv[k4*4+3]=u.w;
  }
  #pragma unroll
  for(int k=0;k<32;k++) pn += cv[k]*cv[k]/cn_s[k];
  pn += EPSF;
  float acc = 0.f;
  #pragma unroll
  for(int k=0;k<32;k++){
    float P = cv[k]*cv[k]/(cn_s[k]*pn);
    acc += P*(__logf(P+EPSF) - __logf(cv[k]+EPSF));
  }
  #pragma unroll
  for(int off=32; off>0; off>>=1) acc += __shfl_down(acc, off);
  if((t&63)==0) red_s[t>>6] = acc;
  __syncthreads();
  if(t==0) atomicAdd(klacc, 100.f*(red_s[0]+red_s[1]+red_s[2]+red_s[3]));
}

// ---------------- memconv0 stage V: V = C^T Q ----------------
__global__ __launch_bounds__(256) void k_memV(const float* __restrict__ Cg,
                                              const unsigned short* __restrict__ qH,
                                              const unsigned short* __restrict__ qL,
                                              const float* __restrict__ scale,
                                              const float* __restrict__ shift,
                                              float* __restrict__ V){
  __shared__ float Cs[256*36];
  __shared__ float Qs[256*32];
  const int b  = blockIdx.x >> 2;
  const int f0 = (blockIdx.x & 3) * 32;
  const int t = threadIdx.x;
  for(int idx=t; idx<256*8; idx+=256){
    int n = idx>>3, k4 = (idx&7)*4;
    *(float4*)(Cs + n*36 + k4) = *(const float4*)(Cg + ((size_t)b*256+n)*32 + k4);
  }
  for(int idx=t; idx<256*8; idx+=256){
    int n = idx>>3, j4 = (idx&7)*4;
    size_t o = ((size_t)b*256+n)*128 + f0 + j4;
    ushort4 uh = *(const ushort4*)(qH + o);
    ushort4 ul = *(const ushort4*)(qL + o);
    float4 s = *(const float4*)(scale + f0 + j4);
    float4 h = *(const float4*)(shift + f0 + j4);
    *(float4*)(Qs + n*32 + j4) = (float4){
      (bf2f(uh.x)+bf2f(ul.x))*s.x + h.x,
      (bf2f(uh.y)+bf2f(ul.y))*s.y + h.y,
      (bf2f(uh.z)+bf2f(ul.z))*s.z + h.z,
      (bf2f(uh.w)+bf2f(ul.w))*s.w + h.w};
  }
  __syncthreads();
  const int k = t & 31, fg = t >> 5;
  float v0=0.f,v1=0.f,v2=0.f,v3=0.f;
  for(int n=0;n<256;n++){
    float c = Cs[n*36+k];
    float4 q = *(const float4*)(Qs + n*32 + fg*4);
    v0 += c*q.x; v1 += c*q.y; v2 += c*q.z; v3 += c*q.w;
  }
  *(float4*)(V + ((size_t)b*32 + k)*128 + f0 + fg*4) = (float4){v0,v1,v2,v3};
}

// ---------------- memconv0 stage L: lin0 ----------------
__global__ __launch_bounds__(256) void k_memL(const float* __restrict__ V,
                                              const float* __restrict__ W,
                                              float* __restrict__ mq1){
  __shared__ float Vs[32*132];
  const int b = blockIdx.x, t = threadIdx.x;
  for(int idx=t; idx<32*32; idx+=256){
    int k = idx>>5, j4 = (idx&31)*4;
    *(float4*)(Vs + k*132 + j4) = *(const float4*)(V + ((size_t)b*32+k)*128 + j4);
  }
  __syncthreads();
  for(int idx=t; idx<K1*MEMH; idx+=256){
    int k = idx/100, mc = idx - k*100;
    float a = W[W_LINB0 + mc];
    for(int f=0; f<128; f++) a += Vs[k*132+f]*W[W_LINW0 + f*100 + mc];
    mq1[(size_t)(b*32+k)*100 + mc] = (a>0.f) ? a : 0.01f*a;
  }
}

// ---------------- mem conv 1 ----------------
__global__ __launch_bounds__(256) void k_memconv1(
    const float* __restrict__ mq1, const float* __restrict__ W,
    const float* __restrict__ ksq, float* __restrict__ mq2, float* __restrict__ klacc)
{
  __shared__ float Qs[32*104];
  __shared__ float Ks[40*100];
  __shared__ float QKs[32*40];
  __shared__ float Cs[32*8];
  __shared__ float cn_s[8];
  __shared__ float pn_s[32];
  __shared__ float qsq_s[32];
  __shared__ float Vs[8*100];
  __shared__ float red_s[4];
  const int b = blockIdx.x, t = threadIdx.x;

  for(int idx=t; idx<32*100; idx+=256){
    int n = idx/100, f = idx - n*100;
    Qs[n*104+f] = mq1[(size_t)b*3200 + idx];
  }
  for(int idx=t; idx<40*100; idx+=256) Ks[idx] = W[W_KEYS1 + idx];
  __syncthreads();

  if(t < 32){ float s=0.f; for(int f=0;f<100;f++){ float v=Qs[t*104+f]; s+=v*v; } qsq_s[t]=s; }
  for(int idx=t; idx<32*40; idx+=256){
    int n = idx/40, c = idx - n*40;
    float a = 0.f;
    for(int f=0;f<100;f++) a += Qs[n*104+f]*Ks[c*100+f];
    QKs[idx] = a;
  }
  __syncthreads();

  if(t < 32){
    float wsum[8];
    #pragma unroll
    for(int k=0;k<8;k++) wsum[k]=0.f;
    for(int h=0;h<HEADS;h++){
      float cw = W[W_CONVW1 + h];
      float c[8]; float rs=0.f;
      #pragma unroll
      for(int k=0;k<8;k++){
        float d2 = qsq_s[t] + ksq[h*8+k] - 2.f*QKs[t*40 + h*8+k];
        d2 = fmaxf(d2, 1e-12f);
        float cc = 1.f/(1.f+d2);
        c[k]=cc; rs+=cc;
      }
      float sc = cw/fmaxf(rs, 1e-20f);
      #pragma unroll
      for(int k=0;k<8;k++) wsum[k] += c[k]*sc;
    }
    float mx = wsum[0];
    #pragma unroll
    for(int k=1;k<8;k++) mx = fmaxf(mx, wsum[k]);
    float se=0.f;
    #pragma unroll
    for(int k=0;k<8;k++){ float e=__expf(wsum[k]-mx); wsum[k]=e; se+=e; }
    float inv = 1.f/se;
    #pragma unroll
    for(int k=0;k<8;k++) Cs[t*8+k] = wsum[k]*inv;
  }
  __syncthreads();
  if(t < 8){ float s=0.f; for(int n=0;n<32;n++) s += Cs[n*8+t]; cn_s[t]=s+EPSF; }
  __syncthreads();
  if(t < 32){
    float p=0.f;
    #pragma unroll
    for(int k=0;k<8;k++){ float sv=Cs[t*8+k]; p += sv*sv/cn_s[k]; }
    pn_s[t]=p+EPSF;
  }
  __syncthreads();

  float acc;
  {
    int n = t>>3, k = t&7;
    float sv = Cs[t];
    float P = sv*sv/(cn_s[k]*pn_s[n]);
    acc = P*(__logf(P+EPSF) - __logf(sv+EPSF));
  }
  #pragma unroll
  for(int off=32; off>0; off>>=1) acc += __shfl_down(acc, off);
  if((t&63)==0) red_s[t>>6] = acc;

  for(int idx=t; idx<8*100; idx+=256){
    int k = idx/100, f = idx - k*100;
    float a=0.f;
    for(int n=0;n<32;n++) a += Cs[n*8+k]*Qs[n*104+f];
    Vs[idx] = a;
  }
  __syncthreads();

  if(t==0) atomicAdd(klacc, 100.f*(red_s[0]+red_s[1]+red_s[2]+red_s[3]));

  for(int idx=t; idx<8*100; idx+=256){
    int k = idx/100, mc = idx - k*100;
    float a = W[W_LINB1 + mc];
    for(int f=0;f<100;f++) a += Vs[k*100+f]*W[W_LINW1 + f*100 + mc];
    mq2[(size_t)b*800 + idx] = (a>0.f) ? a : 0.01f*a;
  }
}

// ---------------- head ----------------
__global__ __launch_bounds__(128) void k_final(const float* __restrict__ mq2,
                                               const float* __restrict__ W,
                                               const int* __restrict__ flag,
                                               const float* __restrict__ kl,
                                               void* __restrict__ out){
  __shared__ float h_s[100];
  __shared__ float hid_s[50];
  const int b = blockIdx.x, t = threadIdx.x;
  if(t < 100){
    float s=0.f;
    #pragma unroll
    for(int k=0;k<8;k++) s += mq2[(size_t)b*800 + k*100 + t];
    h_s[t] = s*0.125f;
  }
  __syncthreads();
  if(t < 50){
    float a = W[W_MLPB1 + t];
    for(int f=0;f<100;f++) a += h_s[f]*W[W_MLPW1 + f*50 + t];
    hid_s[t] = (a>0.f) ? a : 0.01f*a;
  }
  __syncthreads();
  if(t < 12){
    float a = W[W_MLPB2 + t];
    #pragma unroll
    for(int j=0;j<50;j++) a += hid_s[j]*W[W_MLPW2 + j*12 + t];
    if(flag[0]) ((__hip_bfloat16*)out)[b*12+t] = __float2bfloat16(a);
    else        ((float*)out)[b*12+t] = a;
  }
  if(b==0 && t==64){
    float v = (kl[0]+kl[1]) * (1.f/65536.f);
    if(flag[0]) ((__hip_bfloat16*)out)[3072] = __float2bfloat16(v);
    else        ((float*)out)[3072] = v;
  }
}

// ---------------- launch ----------------
extern "C" void kernel_launch(void* const* d_in, const int* in_sizes, int n_in,
                              void* d_out, int out_size, void* d_ws, size_t ws_size,
                              hipStream_t stream) {
  (void)in_sizes; (void)n_in; (void)out_size; (void)ws_size;
  const void* x   = d_in[0];
  const int*  ei  = (const int*)d_in[1];
  const int* src = ei;
  const int* dst = ei + NEDGE;

  WPtrs wp;
  for(int i=0;i<20;i++) wp.p[i] = d_in[3+i];

  char* w = (char*)d_ws;
  int*    deg    = (int*)   (w + OFF_DEG);
  int*    cursor = (int*)   (w + OFF_CURSOR);
  int*    offs   = (int*)   (w + OFF_OFFS);
  double* bnsum  = (double*)(w + OFF_BNSUM);
  double* bnsq   = (double*)(w + OFF_BNSQ);
  float*  scale  = (float*) (w + OFF_SCALE);
  float*  shift  = (float*) (w + OFF_SHIFT);
  float*  ksq0   = (float*) (w + OFF_KSQ0);
  float*  ksq1   = (float*) (w + OFF_KSQ1);
  float*  kl     = (float*) (w + OFF_KL);
  int*    flag   = (int*)   (w + OFF_FLAG);
  float*  Wc     = (float*) (w + OFF_W);
  unsigned short* k0b = (unsigned short*)(w + OFF_K0B);
  unsigned short* wt1 = (unsigned short*)(w + OFF_WT1);
  unsigned short* wt2 = (unsigned short*)(w + OFF_WT2);
  float*  cn     = (float*) (w + OFF_CN);
  unsigned short* csr = (unsigned short*)(w + OFF_CSR);
  unsigned short* agH64  = (unsigned short*)(w + OFF_AH64);
  unsigned short* agL64  = (unsigned short*)(w + OFF_AL64);
  unsigned short* agH128 = (unsigned short*)(w + OFF_AH128);
  unsigned short* agL128 = (unsigned short*)(w + OFF_AL128);
  unsigned short* qvH    = (unsigned short*)(w + OFF_QH);
  unsigned short* qvL    = (unsigned short*)(w + OFF_QL);
  unsigned short* xcH    = (unsigned short*)(w + OFF_XH);
  unsigned short* xcL    = (unsigned short*)(w + OFF_XL);
  float*  Cg     = (float*) (w + OFF_CG);
  float*  Vbuf   = (float*) (w + OFF_V);
  float*  mq1    = (float*) (w + OFF_MQ1);
  float*  mq2    = (float*) (w + OFF_MQ2);

  // qbn hi/lo planes written in place over qvH/qvL by linm2<128>
  unsigned short* qbnH = qvH;
  unsigned short* qbnL = qvL;

  k_detect <<<1,      64, 0, stream>>>((const unsigned short*)x, flag);
  k_init   <<<256,   256, 0, stream>>>(deg, cursor, (unsigned long long*)bnsum, (unsigned long long*)bnsq, kl, cn);
  k_count  <<<4096,  256, 0, stream>>>(dst, deg);
  k_scan   <<<1,    1024, 0, stream>>>(deg, offs);
  k_fill   <<<4096,  256, 0, stream>>>(src, dst, offs, cursor, csr);
  k_cvtx   <<<16384, 256, 0, stream>>>(x, flag, xcH, xcL);
  k_cvtw   <<<402,   256, 0, stream>>>(wp, flag, Wc);
  k_cvtaux <<<80,    256, 0, stream>>>(Wc, k0b, wt1, wt2);
  k_aggr64 <<<16384, 256, 0, stream>>>(xcH, offs, deg, csr, agH64, agL64);
  k_linm2<64> <<<1024,256, 0, stream>>>(agH64, agL64, xcH, xcL, wt1, Wc, W_BREL0, qvH, qvL);
  k_aggr128<<<16384, 256, 0, stream>>>(qvH, offs, deg, csr, agH128, agL128);
  k_linm2<128><<<1024,256, 0, stream>>>(agH128, agL128, qvH, qvL, wt2, Wc, W_BREL1, qbnH, qbnL);
  k_bnstats<<<512,   128, 0, stream>>>(qbnH, qbnL, bnsum, bnsq);
  k_bnfin  <<<1,     256, 0, stream>>>(bnsum, bnsq, Wc, scale, shift, ksq0, ksq1);
  k_memA   <<<1024,  256, 0, stream>>>(qbnH, qbnL, scale, shift, k0b, Wc, ksq0, Cg, cn);
  k_memB   <<<256,   256, 0, stream>>>(Cg, cn, kl);
  k_memV   <<<1024,  256, 0, stream>>>(Cg, qbnH, qbnL, scale, shift, Vbuf);
  k_memL   <<<256,   256, 0, stream>>>(Vbuf, Wc, mq1);
  k_memconv1<<<256,  256, 0, stream>>>(mq1, Wc, ksq1, mq2, kl+1);
  k_final  <<<256,   128, 0, stream>>>(mq2, Wc, flag, kl, d_out);
}

// Round 10
// 567.878 us; speedup vs baseline: 2.0442x; 1.0979x over previous
//
#include <hip/hip_runtime.h>
#include <hip/hip_bf16.h>

#define NTOT   65536
#define NEDGE  1048576
#define HEADS  5
#define K1     32
#define K2     8
#define MEMH   100
#define EPSF   1e-8f

// ---- workspace layout (bytes) ----
#define OFF_DEG     0x0000000
#define OFF_CURSOR  0x0040000   // dead after k_fill -> WT planes
#define OFF_WT1     0x0040000
#define OFF_WT2     0x0050000   // ends 0x70000
#define OFF_OFFS    0x0080000
#define OFF_BNSUM   0x00C0000
#define OFF_BNSQ    0x00C0400
#define OFF_SCALE   0x00C0800
#define OFF_SHIFT   0x00C0A00
#define OFF_KSQ0    0x00C0C00
#define OFF_KSQ1    0x00C0E80
#define OFF_KL      0x00C0F40
#define OFF_FLAG    0x00C0F60
#define OFF_W       0x00C1000   // f32 weights, ends ~0x125680
#define OFF_K0B     0x0128000   // keys0 bf16 (40KB)
#define OFF_CN      0x0134000   // cn[256*32] f32
#define OFF_CSR     0x0140000   // ushort csr: 2MB
#define OFF_A       0x0540000   // 32MB: agH64(8)+agL64(8) -> agH128(16)+agL128(16)
#define OFF_AH128   0x0540000
#define OFF_AL128   0x1540000
#define OFF_AH64    0x0540000
#define OFF_AL64    0x0D40000
#define OFF_B       0x2540000   // 32MB: qvH(16)+qvL(16) -> qbnH/qbnL in place
#define OFF_QH      0x2540000
#define OFF_QL      0x3540000
#define OFF_C       0x4540000   // 16MB: xcH(8)+xcL(8) -> Cg(8)+V(4)+mq1+mq2
#define OFF_XH      0x4540000
#define OFF_XL      0x4D40000
#define OFF_CG      0x4540000
#define OFF_V       0x4D40000
#define OFF_MQ1     0x5140000
#define OFF_MQ2     0x5460000
// peak ws: 0x5540000 (proven footprint)

// ---- canonical weight offsets (floats) ----
#define W_WREL0  0
#define W_BREL0  8192
#define W_WROOT0 8320
#define W_WREL1  16512
#define W_BREL1  32896
#define W_WROOT1 33024
#define W_GAMMA  49408
#define W_BETA   49536
#define W_KEYS0  49664
#define W_CONVW0 70144
#define W_LINW0  70149
#define W_LINB0  82949
#define W_KEYS1  83049
#define W_CONVW1 87049
#define W_LINW1  87054
#define W_LINB1  97054
#define W_MLPW1  97154
#define W_MLPB1  102154
#define W_MLPW2  102204
#define W_MLPB2  102804
#define W_TOTAL  102816

typedef __attribute__((ext_vector_type(8))) short  bf16x8;
typedef __attribute__((ext_vector_type(4))) float  f32x4;

__device__ __forceinline__ float bf2f(unsigned short u){
  union { unsigned int i; float f; } v; v.i = ((unsigned int)u) << 16; return v.f;
}
__device__ __forceinline__ unsigned short f2bf(float f){
  union { float f; unsigned int i; } v; v.f = f;
  unsigned int r = (v.i + 0x7FFFu + ((v.i >> 16) & 1u)) >> 16;   // RNE
  return (unsigned short)r;
}

__device__ const int g_seg[21] = {0,8192,8320,16512,32896,33024,49408,49536,49664,
                                  70144,70149,82949,83049,87049,87054,97054,97154,
                                  102154,102204,102804,102816};
struct WPtrs { const void* p[20]; };

// ---------------- dtype probe ----------------
__global__ void k_detect(const unsigned short* __restrict__ xr, int* flag){
  int t = threadIdx.x & 63;
  unsigned short u = xr[2*t];
  int e = (u >> 7) & 0xFF;
  bool plaus = (u != 0) && (e >= 115) && (e <= 135);
  unsigned long long m = __ballot(plaus);
  if(t == 0) flag[0] = (__popcll(m) >= 48) ? 1 : 0;
}

// x -> bf16 hi/lo planes
__global__ __launch_bounds__(256) void k_cvtx(const void* __restrict__ xin,
                                              const int* __restrict__ flag,
                                              unsigned short* __restrict__ xH,
                                              unsigned short* __restrict__ xL){
  int i = blockIdx.x*256 + threadIdx.x;          // NTOT*64
  float v;
  if(flag[0]) v = bf2f(((const unsigned short*)xin)[i]);
  else        v = ((const float*)xin)[i];
  unsigned short h = f2bf(v);
  xH[i] = h;
  xL[i] = f2bf(v - bf2f(h));
}

__global__ __launch_bounds__(256) void k_cvtw(WPtrs wp, const int* __restrict__ flag,
                                              float* __restrict__ wout){
  int i = blockIdx.x*256 + threadIdx.x;
  if(i >= W_TOTAL) return;
  int s = 0;
  #pragma unroll
  for(int k=0;k<20;k++) if(i >= g_seg[k+1]) s = k+1;
  int j = i - g_seg[s];
  const void* src = wp.p[s];
  wout[i] = flag[0] ? bf2f(((const unsigned short*)src)[j]) : ((const float*)src)[j];
}

// keys0 bf16 + lin W^T bf16 hi/lo planes
__global__ __launch_bounds__(256) void k_cvtaux(const float* __restrict__ W,
                                                unsigned short* __restrict__ k0b,
                                                unsigned short* __restrict__ wt1,
                                                unsigned short* __restrict__ wt2){
  int i = blockIdx.x*256 + threadIdx.x;
  if(i < HEADS*K1*128) k0b[i] = f2bf(W[W_KEYS0 + i]);
  if(i < 128*64){
    int col = i>>6, k = i&63;
    float wr = W[W_WREL0  + k*128 + col];
    float wo = W[W_WROOT0 + k*128 + col];
    unsigned short rh = f2bf(wr), oh = f2bf(wo);
    wt1[i]         = rh;
    wt1[ 8192 + i] = f2bf(wr - bf2f(rh));
    wt1[16384 + i] = oh;
    wt1[24576 + i] = f2bf(wo - bf2f(oh));
  }
  if(i < 128*128){
    int col = i>>7, k = i&127;
    float wr = W[W_WREL1  + k*128 + col];
    float wo = W[W_WROOT1 + k*128 + col];
    unsigned short rh = f2bf(wr), oh = f2bf(wo);
    wt2[i]         = rh;
    wt2[16384 + i] = f2bf(wr - bf2f(rh));
    wt2[32768 + i] = oh;
    wt2[49152 + i] = f2bf(wo - bf2f(oh));
  }
}

// ---------------- init / CSR build ----------------
__global__ __launch_bounds__(256) void k_init(int* deg, int* cursor,
                                              unsigned long long* bnsum,
                                              unsigned long long* bnsq, float* kl, float* cn){
  int i = blockIdx.x*256 + threadIdx.x;
  if(i < NTOT){ deg[i]=0; cursor[i]=0; }
  if(i < 128){ bnsum[i]=0ULL; bnsq[i]=0ULL; }
  if(i < 2) kl[i]=0.f;
  if(i < 256*32) cn[i]=0.f;
}

__global__ __launch_bounds__(256) void k_count(const int* __restrict__ dst, int* deg){
  int e = blockIdx.x*256 + threadIdx.x;
  atomicAdd(&deg[dst[e]], 1);
}

__global__ __launch_bounds__(1024) void k_scan(const int* __restrict__ deg, int* __restrict__ offs){
  __shared__ int ts[1024];
  const int t = threadIdx.x;
  const int base = t*64;
  int s = 0;
  for(int i=0;i<64;i++) s += deg[base+i];
  ts[t] = s; __syncthreads();
  for(int off=1; off<1024; off<<=1){
    int v = (t>=off) ? ts[t-off] : 0;
    __syncthreads();
    ts[t] += v;
    __syncthreads();
  }
  int run = (t==0) ? 0 : ts[t-1];
  for(int i=0;i<64;i++){ offs[base+i]=run; run += deg[base+i]; }
}

__global__ __launch_bounds__(256) void k_fill(const int* __restrict__ src, const int* __restrict__ dst,
                                              const int* __restrict__ offs, int* cursor,
                                              unsigned short* __restrict__ csr){
  int e = blockIdx.x*256 + threadIdx.x;
  int d = dst[e];
  int p = atomicAdd(&cursor[d], 1);
  csr[offs[d] + p] = (unsigned short)src[e];
}

// ---------------- graph aggregation (bf16 gathers, f32 acc, hi/lo out) --------
__global__ __launch_bounds__(256) void k_aggr64(const unsigned short* __restrict__ xH,
                                                const int* __restrict__ offs, const int* __restrict__ deg,
                                                const unsigned short* __restrict__ csr,
                                                unsigned short* __restrict__ aH,
                                                unsigned short* __restrict__ aL){
  const int wid  = (blockIdx.x*256 + threadIdx.x) >> 6;
  const int lane = threadIdx.x & 63;
  const int sub = lane >> 4, fl = lane & 15;
  const int beg = offs[wid], n = deg[wid];
  float4 acc = {0.f,0.f,0.f,0.f};
  int i = 0;
  for(; i+32 <= n; i += 32){
    int s[8];
    #pragma unroll
    for(int j=0;j<8;j++) s[j] = csr[beg + i + 4*j + sub];
    #pragma unroll
    for(int j=0;j<8;j++){
      ushort4 u = *(const ushort4*)(xH + (size_t)s[j]*64 + fl*4);
      acc.x += bf2f(u.x); acc.y += bf2f(u.y); acc.z += bf2f(u.z); acc.w += bf2f(u.w);
    }
  }
  for(; i < n; i += 4){
    if(i + sub < n){
      int s = csr[beg + i + sub];
      ushort4 u = *(const ushort4*)(xH + (size_t)s*64 + fl*4);
      acc.x += bf2f(u.x); acc.y += bf2f(u.y); acc.z += bf2f(u.z); acc.w += bf2f(u.w);
    }
  }
  acc.x += __shfl_xor(acc.x, 16); acc.y += __shfl_xor(acc.y, 16);
  acc.z += __shfl_xor(acc.z, 16); acc.w += __shfl_xor(acc.w, 16);
  acc.x += __shfl_xor(acc.x, 32); acc.y += __shfl_xor(acc.y, 32);
  acc.z += __shfl_xor(acc.z, 32); acc.w += __shfl_xor(acc.w, 32);
  if(sub == 0){
    ushort4 h, l;
    h.x=f2bf(acc.x); l.x=f2bf(acc.x-bf2f(h.x));
    h.y=f2bf(acc.y); l.y=f2bf(acc.y-bf2f(h.y));
    h.z=f2bf(acc.z); l.z=f2bf(acc.z-bf2f(h.z));
    h.w=f2bf(acc.w); l.w=f2bf(acc.w-bf2f(h.w));
    *(ushort4*)(aH + (size_t)wid*64 + fl*4) = h;
    *(ushort4*)(aL + (size_t)wid*64 + fl*4) = l;
  }
}

__global__ __launch_bounds__(256) void k_aggr128(const unsigned short* __restrict__ qH,
                                                 const int* __restrict__ offs, const int* __restrict__ deg,
                                                 const unsigned short* __restrict__ csr,
                                                 unsigned short* __restrict__ aH,
                                                 unsigned short* __restrict__ aL){
  const int wid  = (blockIdx.x*256 + threadIdx.x) >> 6;
  const int lane = threadIdx.x & 63;
  const int sub = lane >> 5, fl = lane & 31;
  const int beg = offs[wid], n = deg[wid];
  float4 acc = {0.f,0.f,0.f,0.f};
  int i = 0;
  for(; i+16 <= n; i += 16){
    int s[8];
    #pragma unroll
    for(int j=0;j<8;j++) s[j] = csr[beg + i + 2*j + sub];
    #pragma unroll
    for(int j=0;j<8;j++){
      ushort4 u = *(const ushort4*)(qH + (size_t)s[j]*128 + fl*4);
      acc.x += bf2f(u.x); acc.y += bf2f(u.y); acc.z += bf2f(u.z); acc.w += bf2f(u.w);
    }
  }
  for(; i < n; i += 2){
    if(i + sub < n){
      int s = csr[beg + i + sub];
      ushort4 u = *(const ushort4*)(qH + (size_t)s*128 + fl*4);
      acc.x += bf2f(u.x); acc.y += bf2f(u.y); acc.z += bf2f(u.z); acc.w += bf2f(u.w);
    }
  }
  acc.x += __shfl_xor(acc.x, 32); acc.y += __shfl_xor(acc.y, 32);
  acc.z += __shfl_xor(acc.z, 32); acc.w += __shfl_xor(acc.w, 32);
  if(sub == 0){
    ushort4 h, l;
    h.x=f2bf(acc.x); l.x=f2bf(acc.x-bf2f(h.x));
    h.y=f2bf(acc.y); l.y=f2bf(acc.y-bf2f(h.y));
    h.z=f2bf(acc.z); l.z=f2bf(acc.z-bf2f(h.z));
    h.w=f2bf(acc.w); l.w=f2bf(acc.w-bf2f(h.w));
    *(ushort4*)(aH + (size_t)wid*128 + fl*4) = h;
    *(ushort4*)(aL + (size_t)wid*128 + fl*4) = l;
  }
}

// ---------------- lin via split-bf16 MFMA, weight-fragments resident in VGPRs --
// Block: 128 rows x 128 cols. Wave w holds B-frags for cols [w*32, w*32+32) in
// registers (loaded ONCE), loops 8 row-tiles. One __syncthreads per tile between
// fragment consumption and stores makes the lin2 in-place overwrite (out aliases X)
// safe: all waves' reads of tile rt complete before any write; tiles are disjoint rows.
template<int KD>
__global__ __launch_bounds__(256) void k_ling(const unsigned short* __restrict__ AH,
                                              const unsigned short* __restrict__ AL,
                                              const unsigned short* XH,
                                              const unsigned short* XL,
                                              const unsigned short* __restrict__ WT,
                                              const float* __restrict__ W, int bofs,
                                              unsigned short* outH,
                                              unsigned short* outL){
  constexpr int NK = KD/32;
  const int t = threadIdx.x;
  const int wv = t>>6, lane = t&63, quad = lane>>4, m = lane&15;
  const int rbase = blockIdx.x*128;
  const int c0 = (wv*2)*16 + m;
  const int c1 = (wv*2+1)*16 + m;

  bf16x8 BrH0[NK], BrL0[NK], BoH0[NK], BoL0[NK];
  bf16x8 BrH1[NK], BrL1[NK], BoH1[NK], BoL1[NK];
  #pragma unroll
  for(int ks=0; ks<NK; ks++){
    const size_t o0 = (size_t)c0*KD + ks*32 + quad*8;
    const size_t o1 = (size_t)c1*KD + ks*32 + quad*8;
    BrH0[ks] = *(const bf16x8*)(WT + o0);
    BrL0[ks] = *(const bf16x8*)(WT + 128*KD + o0);
    BoH0[ks] = *(const bf16x8*)(WT + 256*KD + o0);
    BoL0[ks] = *(const bf16x8*)(WT + 384*KD + o0);
    BrH1[ks] = *(const bf16x8*)(WT + o1);
    BrL1[ks] = *(const bf16x8*)(WT + 128*KD + o1);
    BoH1[ks] = *(const bf16x8*)(WT + 256*KD + o1);
    BoL1[ks] = *(const bf16x8*)(WT + 384*KD + o1);
  }
  const float b0 = W[bofs + c0];
  const float b1 = W[bofs + c1];

  for(int rt=0; rt<8; rt++){
    const int r0 = rbase + rt*16;
    bf16x8 fah[NK], fal[NK], fxh[NK], fxl[NK];
    #pragma unroll
    for(int ks=0; ks<NK; ks++){
      const size_t o = (size_t)(r0+m)*KD + ks*32 + quad*8;
      fah[ks] = *(const bf16x8*)(AH + o);
      fal[ks] = *(const bf16x8*)(AL + o);
      fxh[ks] = *(const bf16x8*)(XH + o);
      fxl[ks] = *(const bf16x8*)(XL + o);
    }
    f32x4 a0 = {0.f,0.f,0.f,0.f}, a1 = {0.f,0.f,0.f,0.f};
    #pragma unroll
    for(int ks=0; ks<NK; ks++){
      a0 = __builtin_amdgcn_mfma_f32_16x16x32_bf16(fah[ks], BrH0[ks], a0, 0,0,0);
      a1 = __builtin_amdgcn_mfma_f32_16x16x32_bf16(fah[ks], BrH1[ks], a1, 0,0,0);
      a0 = __builtin_amdgcn_mfma_f32_16x16x32_bf16(fal[ks], BrH0[ks], a0, 0,0,0);
      a1 = __builtin_amdgcn_mfma_f32_16x16x32_bf16(fal[ks], BrH1[ks], a1, 0,0,0);
      a0 = __builtin_amdgcn_mfma_f32_16x16x32_bf16(fah[ks], BrL0[ks], a0, 0,0,0);
      a1 = __builtin_amdgcn_mfma_f32_16x16x32_bf16(fah[ks], BrL1[ks], a1, 0,0,0);
      a0 = __builtin_amdgcn_mfma_f32_16x16x32_bf16(fxh[ks], BoH0[ks], a0, 0,0,0);
      a1 = __builtin_amdgcn_mfma_f32_16x16x32_bf16(fxh[ks], BoH1[ks], a1, 0,0,0);
      a0 = __builtin_amdgcn_mfma_f32_16x16x32_bf16(fxl[ks], BoH0[ks], a0, 0,0,0);
      a1 = __builtin_amdgcn_mfma_f32_16x16x32_bf16(fxl[ks], BoH1[ks], a1, 0,0,0);
      a0 = __builtin_amdgcn_mfma_f32_16x16x32_bf16(fxh[ks], BoL0[ks], a0, 0,0,0);
      a1 = __builtin_amdgcn_mfma_f32_16x16x32_bf16(fxh[ks], BoL1[ks], a1, 0,0,0);
    }
    __syncthreads();   // all waves done reading tile rt (incl. aliased X) before writes
    #pragma unroll
    for(int i=0;i<4;i++){
      const size_t orow = (size_t)(r0 + quad*4 + i)*128;
      float v0 = fmaxf(a0[i] + b0, 0.f);
      unsigned short h0 = f2bf(v0);
      outH[orow + c0] = h0;
      outL[orow + c0] = f2bf(v0 - bf2f(h0));
      float v1 = fmaxf(a1[i] + b1, 0.f);
      unsigned short h1 = f2bf(v1);
      outH[orow + c1] = h1;
      outL[orow + c1] = f2bf(v1 - bf2f(h1));
    }
  }
}

// ---------------- batchnorm ----------------
__global__ __launch_bounds__(128) void k_bnstats(const unsigned short* __restrict__ qH,
                                                 const unsigned short* __restrict__ qL,
                                                 double* bnsum, double* bnsq){
  const int j = threadIdx.x;
  const int r0 = blockIdx.x*128;
  float s=0.f, s2=0.f;
  for(int r=0;r<128;r++){
    size_t o = (size_t)(r0+r)*128 + j;
    float v = bf2f(qH[o]) + bf2f(qL[o]);
    s += v; s2 += v*v;
  }
  atomicAdd(&bnsum[j], (double)s);
  atomicAdd(&bnsq[j], (double)s2);
}

__global__ __launch_bounds__(256) void k_bnfin(const double* __restrict__ bnsum, const double* __restrict__ bnsq,
                                               const float* __restrict__ W,
                                               float* scale, float* shift, float* ksq0, float* ksq1){
  const int t = threadIdx.x;
  if(t < 128){
    double mu  = bnsum[t] / (double)NTOT;
    double var = bnsq[t] / (double)NTOT - mu*mu;
    if(var < 0.0) var = 0.0;
    float sc = W[W_GAMMA + t] * rsqrtf((float)var + 1e-5f);
    scale[t] = sc;
    shift[t] = W[W_BETA + t] - (float)mu * sc;
  }
  if(t < HEADS*K1){
    float s=0.f;
    for(int f=0;f<128;f++){ float v = W[W_KEYS0 + t*128 + f]; s += v*v; }
    ksq0[t] = s;
  }
  if(t < HEADS*K2){
    float s=0.f;
    for(int f=0;f<100;f++){ float v = W[W_KEYS1 + t*100 + f]; s += v*v; }
    ksq1[t] = s;
  }
}

// ---------------- memconv0 stage A: fused qk MFMA + C + partial cn ------------
__global__ __launch_bounds__(256) void k_memA(
    const unsigned short* __restrict__ qH, const unsigned short* __restrict__ qL,
    const float* __restrict__ scale, const float* __restrict__ shift,
    const unsigned short* __restrict__ k0b,
    const float* __restrict__ W, const float* __restrict__ ksq,
    float* __restrict__ Cg, float* __restrict__ cn)
{
  __shared__ unsigned short Qb[64*136];
  __shared__ float qkL[160*68];        // [col][row]
  __shared__ float wsumL[64*36];
  __shared__ float qsqL[64];
  __shared__ float rsL[64*6];
  const int bid = blockIdx.x;
  const int r0 = bid*64;
  const int t = threadIdx.x;
  const int wv = t>>6, lane = t&63, quad = lane>>4, m = lane&15;

  for(int idx=t; idx<64*32; idx+=256){
    int r = idx>>5, c4 = (idx&31)*4;
    size_t o = (size_t)(r0+r)*128 + c4;
    ushort4 uh = *(const ushort4*)(qH + o);
    ushort4 ul = *(const ushort4*)(qL + o);
    float4 s = *(const float4*)(scale + c4);
    float4 h = *(const float4*)(shift + c4);
    ushort4 ob;
    ob.x = f2bf((bf2f(uh.x)+bf2f(ul.x))*s.x + h.x);
    ob.y = f2bf((bf2f(uh.y)+bf2f(ul.y))*s.y + h.y);
    ob.z = f2bf((bf2f(uh.z)+bf2f(ul.z))*s.z + h.z);
    ob.w = f2bf((bf2f(uh.w)+bf2f(ul.w))*s.w + h.w);
    *(ushort4*)(Qb + r*136 + c4) = ob;
  }
  __syncthreads();

  {
    bf16x8 a[4];
    #pragma unroll
    for(int ks=0;ks<4;ks++)
      a[ks] = *(const bf16x8*)(Qb + (wv*16+m)*136 + ks*32 + quad*8);
    for(int nb=0; nb<10; nb++){
      f32x4 acc = {0.f,0.f,0.f,0.f};
      const bf16x8* brow = (const bf16x8*)(k0b + (size_t)(nb*16+m)*128);
      #pragma unroll
      for(int ks=0;ks<4;ks++)
        acc = __builtin_amdgcn_mfma_f32_16x16x32_bf16(a[ks], brow[ks*4+quad], acc,0,0,0);
      *(f32x4*)(qkL + (nb*16+m)*68 + wv*16 + quad*4) = acc;
    }
  }
  if(t < 64){
    float s = 0.f;
    for(int j=0;j<16;j++){
      bf16x8 v = *(const bf16x8*)(Qb + t*136 + j*8);
      #pragma unroll
      for(int e=0;e<8;e++){ float f = bf2f((unsigned short)v[e]); s += f*f; }
    }
    qsqL[t] = s;
  }
  __syncthreads();

  {
    int row = t & 63, g = t >> 6;
    float q2 = qsqL[row];
    #pragma unroll
    for(int pass=0; pass<2; pass++){
      int h = g + pass*4;
      if(h < HEADS){
        float rs = 0.f;
        for(int k=0;k<32;k++){
          float d2 = q2 + ksq[h*32+k] - 2.f*qkL[(h*32+k)*68 + row];
          d2 = fmaxf(d2, 1e-12f);
          rs += 1.f/(1.f+d2);
        }
        rsL[row*6+h] = W[W_CONVW0+h]/fmaxf(rs,1e-20f);
      }
    }
  }
  __syncthreads();

  {
    int row = t & 63, kq = t >> 6;
    float q2 = qsqL[row];
    for(int kk=0; kk<8; kk++){
      int k = kq*8+kk;
      float wsum = 0.f;
      #pragma unroll
      for(int h=0;h<HEADS;h++){
        float d2 = q2 + ksq[h*32+k] - 2.f*qkL[(h*32+k)*68 + row];
        d2 = fmaxf(d2, 1e-12f);
        wsum += rsL[row*6+h]/(1.f+d2);
      }
      wsumL[row*36+k] = wsum;
    }
  }
  __syncthreads();

  if(t < 64){
    float mx = -1e30f;
    #pragma unroll
    for(int k=0;k<32;k++) mx = fmaxf(mx, wsumL[t*36+k]);
    float cv[32]; float se = 0.f;
    #pragma unroll
    for(int k=0;k<32;k++){ float e = __expf(wsumL[t*36+k]-mx); cv[k]=e; se+=e; }
    float inv = 1.f/se;
    #pragma unroll
    for(int k=0;k<32;k++){ cv[k]*=inv; wsumL[t*36+k]=cv[k]; }
    float4* dst = (float4*)(Cg + (size_t)(r0+t)*32);
    #pragma unroll
    for(int k4=0;k4<8;k4++)
      dst[k4] = (float4){cv[k4*4],cv[k4*4+1],cv[k4*4+2],cv[k4*4+3]};
  }
  __syncthreads();
  if(t < 32){
    float s = 0.f;
    for(int r=0;r<64;r++) s += wsumL[r*36+t];
    atomicAdd(&cn[(bid>>2)*32 + t], s);
  }
}

// ---------------- memconv0 stage B: KL ----------------
__global__ __launch_bounds__(256) void k_memB(const float* __restrict__ Cg,
                                              const float* __restrict__ cn,
                                              float* __restrict__ klacc){
  __shared__ float cn_s[32];
  __shared__ float red_s[4];
  const int b = blockIdx.x, t = threadIdx.x;
  if(t < 32) cn_s[t] = cn[b*32+t] + EPSF;
  __syncthreads();
  const float* crow = Cg + ((size_t)b*256 + t)*32;
  float cv[32]; float pn = 0.f;
  #pragma unroll
  for(int k4=0;k4<8;k4++){
    float4 u = *(const float4*)(crow + k4*4);
    cv[k4*4]=u.x; cv[k4*4+1]=u.y; cv[k4*4+2]=u.z; cv[k4*4+3]=u.w;
  }
  #pragma unroll
  for(int k=0;k<32;k++) pn += cv[k]*cv[k]/cn_s[k];
  pn += EPSF;
  float acc = 0.f;
  #pragma unroll
  for(int k=0;k<32;k++){
    float P = cv[k]*cv[k]/(cn_s[k]*pn);
    acc += P*(__logf(P+EPSF) - __logf(cv[k]+EPSF));
  }
  #pragma unroll
  for(int off=32; off>0; off>>=1) acc += __shfl_down(acc, off);
  if((t&63)==0) red_s[t>>6] = acc;
  __syncthreads();
  if(t==0) atomicAdd(klacc, 100.f*(red_s[0]+red_s[1]+red_s[2]+red_s[3]));
}

// ---------------- memconv0 stage V: V = C^T Q ----------------
__global__ __launch_bounds__(256) void k_memV(const float* __restrict__ Cg,
                                              const unsigned short* __restrict__ qH,
                                              const unsigned short* __restrict__ qL,
                                              const float* __restrict__ scale,
                                              const float* __restrict__ shift,
                                              float* __restrict__ V){
  __shared__ float Cs[256*36];
  __shared__ float Qs[256*32];
  const int b  = blockIdx.x >> 2;
  const int f0 = (blockIdx.x & 3) * 32;
  const int t = threadIdx.x;
  for(int idx=t; idx<256*8; idx+=256){
    int n = idx>>3, k4 = (idx&7)*4;
    *(float4*)(Cs + n*36 + k4) = *(const float4*)(Cg + ((size_t)b*256+n)*32 + k4);
  }
  for(int idx=t; idx<256*8; idx+=256){
    int n = idx>>3, j4 = (idx&7)*4;
    size_t o = ((size_t)b*256+n)*128 + f0 + j4;
    ushort4 uh = *(const ushort4*)(qH + o);
    ushort4 ul = *(const ushort4*)(qL + o);
    float4 s = *(const float4*)(scale + f0 + j4);
    float4 h = *(const float4*)(shift + f0 + j4);
    *(float4*)(Qs + n*32 + j4) = (float4){
      (bf2f(uh.x)+bf2f(ul.x))*s.x + h.x,
      (bf2f(uh.y)+bf2f(ul.y))*s.y + h.y,
      (bf2f(uh.z)+bf2f(ul.z))*s.z + h.z,
      (bf2f(uh.w)+bf2f(ul.w))*s.w + h.w};
  }
  __syncthreads();
  const int k = t & 31, fg = t >> 5;
  float v0=0.f,v1=0.f,v2=0.f,v3=0.f;
  for(int n=0;n<256;n++){
    float c = Cs[n*36+k];
    float4 q = *(const float4*)(Qs + n*32 + fg*4);
    v0 += c*q.x; v1 += c*q.y; v2 += c*q.z; v3 += c*q.w;
  }
  *(float4*)(V + ((size_t)b*32 + k)*128 + f0 + fg*4) = (float4){v0,v1,v2,v3};
}

// ---------------- memconv0 stage L: lin0 ----------------
__global__ __launch_bounds__(256) void k_memL(const float* __restrict__ V,
                                              const float* __restrict__ W,
                                              float* __restrict__ mq1){
  __shared__ float Vs[32*132];
  const int b = blockIdx.x, t = threadIdx.x;
  for(int idx=t; idx<32*32; idx+=256){
    int k = idx>>5, j4 = (idx&31)*4;
    *(float4*)(Vs + k*132 + j4) = *(const float4*)(V + ((size_t)b*32+k)*128 + j4);
  }
  __syncthreads();
  for(int idx=t; idx<K1*MEMH; idx+=256){
    int k = idx/100, mc = idx - k*100;
    float a = W[W_LINB0 + mc];
    for(int f=0; f<128; f++) a += Vs[k*132+f]*W[W_LINW0 + f*100 + mc];
    mq1[(size_t)(b*32+k)*100 + mc] = (a>0.f) ? a : 0.01f*a;
  }
}

// ---------------- mem conv 1 ----------------
__global__ __launch_bounds__(256) void k_memconv1(
    const float* __restrict__ mq1, const float* __restrict__ W,
    const float* __restrict__ ksq, float* __restrict__ mq2, float* __restrict__ klacc)
{
  __shared__ float Qs[32*104];
  __shared__ float Ks[40*100];
  __shared__ float QKs[32*40];
  __shared__ float Cs[32*8];
  __shared__ float cn_s[8];
  __shared__ float pn_s[32];
  __shared__ float qsq_s[32];
  __shared__ float Vs[8*100];
  __shared__ float red_s[4];
  const int b = blockIdx.x, t = threadIdx.x;

  for(int idx=t; idx<32*100; idx+=256){
    int n = idx/100, f = idx - n*100;
    Qs[n*104+f] = mq1[(size_t)b*3200 + idx];
  }
  for(int idx=t; idx<40*100; idx+=256) Ks[idx] = W[W_KEYS1 + idx];
  __syncthreads();

  if(t < 32){ float s=0.f; for(int f=0;f<100;f++){ float v=Qs[t*104+f]; s+=v*v; } qsq_s[t]=s; }
  for(int idx=t; idx<32*40; idx+=256){
    int n = idx/40, c = idx - n*40;
    float a = 0.f;
    for(int f=0;f<100;f++) a += Qs[n*104+f]*Ks[c*100+f];
    QKs[idx] = a;
  }
  __syncthreads();

  if(t < 32){
    float wsum[8];
    #pragma unroll
    for(int k=0;k<8;k++) wsum[k]=0.f;
    for(int h=0;h<HEADS;h++){
      float cw = W[W_CONVW1 + h];
      float c[8]; float rs=0.f;
      #pragma unroll
      for(int k=0;k<8;k++){
        float d2 = qsq_s[t] + ksq[h*8+k] - 2.f*QKs[t*40 + h*8+k];
        d2 = fmaxf(d2, 1e-12f);
        float cc = 1.f/(1.f+d2);
        c[k]=cc; rs+=cc;
      }
      float sc = cw/fmaxf(rs, 1e-20f);
      #pragma unroll
      for(int k=0;k<8;k++) wsum[k] += c[k]*sc;
    }
    float mx = wsum[0];
    #pragma unroll
    for(int k=1;k<8;k++) mx = fmaxf(mx, wsum[k]);
    float se=0.f;
    #pragma unroll
    for(int k=0;k<8;k++){ float e=__expf(wsum[k]-mx); wsum[k]=e; se+=e; }
    float inv = 1.f/se;
    #pragma unroll
    for(int k=0;k<8;k++) Cs[t*8+k] = wsum[k]*inv;
  }
  __syncthreads();
  if(t < 8){ float s=0.f; for(int n=0;n<32;n++) s += Cs[n*8+t]; cn_s[t]=s+EPSF; }
  __syncthreads();
  if(t < 32){
    float p=0.f;
    #pragma unroll
    for(int k=0;k<8;k++){ float sv=Cs[t*8+k]; p += sv*sv/cn_s[k]; }
    pn_s[t]=p+EPSF;
  }
  __syncthreads();

  float acc;
  {
    int n = t>>3, k = t&7;
    float sv = Cs[t];
    float P = sv*sv/(cn_s[k]*pn_s[n]);
    acc = P*(__logf(P+EPSF) - __logf(sv+EPSF));
  }
  #pragma unroll
  for(int off=32; off>0; off>>=1) acc += __shfl_down(acc, off);
  if((t&63)==0) red_s[t>>6] = acc;

  for(int idx=t; idx<8*100; idx+=256){
    int k = idx/100, f = idx - k*100;
    float a=0.f;
    for(int n=0;n<32;n++) a += Cs[n*8+k]*Qs[n*104+f];
    Vs[idx] = a;
  }
  __syncthreads();

  if(t==0) atomicAdd(klacc, 100.f*(red_s[0]+red_s[1]+red_s[2]+red_s[3]));

  for(int idx=t; idx<8*100; idx+=256){
    int k = idx/100, mc = idx - k*100;
    float a = W[W_LINB1 + mc];
    for(int f=0;f<100;f++) a += Vs[k*100+f]*W[W_LINW1 + f*100 + mc];
    mq2[(size_t)b*800 + idx] = (a>0.f) ? a : 0.01f*a;
  }
}

// ---------------- head ----------------
__global__ __launch_bounds__(128) void k_final(const float* __restrict__ mq2,
                                               const float* __restrict__ W,
                                               const int* __restrict__ flag,
                                               const float* __restrict__ kl,
                                               void* __restrict__ out){
  __shared__ float h_s[100];
  __shared__ float hid_s[50];
  const int b = blockIdx.x, t = threadIdx.x;
  if(t < 100){
    float s=0.f;
    #pragma unroll
    for(int k=0;k<8;k++) s += mq2[(size_t)b*800 + k*100 + t];
    h_s[t] = s*0.125f;
  }
  __syncthreads();
  if(t < 50){
    float a = W[W_MLPB1 + t];
    for(int f=0;f<100;f++) a += h_s[f]*W[W_MLPW1 + f*50 + t];
    hid_s[t] = (a>0.f) ? a : 0.01f*a;
  }
  __syncthreads();
  if(t < 12){
    float a = W[W_MLPB2 + t];
    #pragma unroll
    for(int j=0;j<50;j++) a += hid_s[j]*W[W_MLPW2 + j*12 + t];
    if(flag[0]) ((__hip_bfloat16*)out)[b*12+t] = __float2bfloat16(a);
    else        ((float*)out)[b*12+t] = a;
  }
  if(b==0 && t==64){
    float v = (kl[0]+kl[1]) * (1.f/65536.f);
    if(flag[0]) ((__hip_bfloat16*)out)[3072] = __float2bfloat16(v);
    else        ((float*)out)[3072] = v;
  }
}

// ---------------- launch ----------------
extern "C" void kernel_launch(void* const* d_in, const int* in_sizes, int n_in,
                              void* d_out, int out_size, void* d_ws, size_t ws_size,
                              hipStream_t stream) {
  (void)in_sizes; (void)n_in; (void)out_size; (void)ws_size;
  const void* x   = d_in[0];
  const int*  ei  = (const int*)d_in[1];
  const int* src = ei;
  const int* dst = ei + NEDGE;

  WPtrs wp;
  for(int i=0;i<20;i++) wp.p[i] = d_in[3+i];

  char* w = (char*)d_ws;
  int*    deg    = (int*)   (w + OFF_DEG);
  int*    cursor = (int*)   (w + OFF_CURSOR);
  int*    offs   = (int*)   (w + OFF_OFFS);
  double* bnsum  = (double*)(w + OFF_BNSUM);
  double* bnsq   = (double*)(w + OFF_BNSQ);
  float*  scale  = (float*) (w + OFF_SCALE);
  float*  shift  = (float*) (w + OFF_SHIFT);
  float*  ksq0   = (float*) (w + OFF_KSQ0);
  float*  ksq1   = (float*) (w + OFF_KSQ1);
  float*  kl     = (float*) (w + OFF_KL);
  int*    flag   = (int*)   (w + OFF_FLAG);
  float*  Wc     = (float*) (w + OFF_W);
  unsigned short* k0b = (unsigned short*)(w + OFF_K0B);
  unsigned short* wt1 = (unsigned short*)(w + OFF_WT1);
  unsigned short* wt2 = (unsigned short*)(w + OFF_WT2);
  float*  cn     = (float*) (w + OFF_CN);
  unsigned short* csr = (unsigned short*)(w + OFF_CSR);
  unsigned short* agH64  = (unsigned short*)(w + OFF_AH64);
  unsigned short* agL64  = (unsigned short*)(w + OFF_AL64);
  unsigned short* agH128 = (unsigned short*)(w + OFF_AH128);
  unsigned short* agL128 = (unsigned short*)(w + OFF_AL128);
  unsigned short* qvH    = (unsigned short*)(w + OFF_QH);
  unsigned short* qvL    = (unsigned short*)(w + OFF_QL);
  unsigned short* xcH    = (unsigned short*)(w + OFF_XH);
  unsigned short* xcL    = (unsigned short*)(w + OFF_XL);
  float*  Cg     = (float*) (w + OFF_CG);
  float*  Vbuf   = (float*) (w + OFF_V);
  float*  mq1    = (float*) (w + OFF_MQ1);
  float*  mq2    = (float*) (w + OFF_MQ2);

  // qbn hi/lo planes written in place over qvH/qvL by k_ling<128> (barrier-protected)
  unsigned short* qbnH = qvH;
  unsigned short* qbnL = qvL;

  k_detect <<<1,      64, 0, stream>>>((const unsigned short*)x, flag);
  k_init   <<<256,   256, 0, stream>>>(deg, cursor, (unsigned long long*)bnsum, (unsigned long long*)bnsq, kl, cn);
  k_count  <<<4096,  256, 0, stream>>>(dst, deg);
  k_scan   <<<1,    1024, 0, stream>>>(deg, offs);
  k_fill   <<<4096,  256, 0, stream>>>(src, dst, offs, cursor, csr);
  k_cvtx   <<<16384, 256, 0, stream>>>(x, flag, xcH, xcL);
  k_cvtw   <<<402,   256, 0, stream>>>(wp, flag, Wc);
  k_cvtaux <<<80,    256, 0, stream>>>(Wc, k0b, wt1, wt2);
  k_aggr64 <<<16384, 256, 0, stream>>>(xcH, offs, deg, csr, agH64, agL64);
  k_ling<64> <<<512, 256, 0, stream>>>(agH64, agL64, xcH, xcL, wt1, Wc, W_BREL0, qvH, qvL);
  k_aggr128<<<16384, 256, 0, stream>>>(qvH, offs, deg, csr, agH128, agL128);
  k_ling<128><<<512, 256, 0, stream>>>(agH128, agL128, qvH, qvL, wt2, Wc, W_BREL1, qbnH, qbnL);
  k_bnstats<<<512,   128, 0, stream>>>(qbnH, qbnL, bnsum, bnsq);
  k_bnfin  <<<1,     256, 0, stream>>>(bnsum, bnsq, Wc, scale, shift, ksq0, ksq1);
  k_memA   <<<1024,  256, 0, stream>>>(qbnH, qbnL, scale, shift, k0b, Wc, ksq0, Cg, cn);
  k_memB   <<<256,   256, 0, stream>>>(Cg, cn, kl);
  k_memV   <<<1024,  256, 0, stream>>>(Cg, qbnH, qbnL, scale, shift, Vbuf);
  k_memL   <<<256,   256, 0, stream>>>(Vbuf, Wc, mq1);
  k_memconv1<<<256,  256, 0, stream>>>(mq1, Wc, ksq1, mq2, kl+1);
  k_final  <<<256,   128, 0, stream>>>(mq2, Wc, flag, kl, d_out);
}

// Round 11
// 479.127 us; speedup vs baseline: 2.4228x; 1.1852x over previous
//
#include <hip/hip_runtime.h>
#include <hip/hip_bf16.h>

#define NTOT   65536
#define NEDGE  1048576
#define HEADS  5
#define K1     32
#define K2     8
#define MEMH   100
#define EPSF   1e-8f

// ---- workspace layout (bytes) ----
#define OFF_DEG     0x0000000
#define OFF_CURSOR  0x0040000   // dead (no k_fill) -> WT planes
#define OFF_WT1     0x0040000
#define OFF_WT2     0x0050000   // ends 0x70000
#define OFF_OFFS    0x0080000
#define OFF_BNSUM   0x00C0000
#define OFF_BNSQ    0x00C0400
#define OFF_SCALE   0x00C0800
#define OFF_SHIFT   0x00C0A00
#define OFF_KSQ0    0x00C0C00
#define OFF_KSQ1    0x00C0E80
#define OFF_KL      0x00C0F40
#define OFF_FLAG    0x00C0F60
#define OFF_W       0x00C1000   // f32 weights
#define OFF_K0B     0x0128000   // keys0 bf16 (40KB)
#define OFF_CN      0x0134000   // cn[256*32] f32
#define OFF_BH      0x013C000   // bhist[256]
#define OFF_EBASE   0x013C400   // ebase[256]
#define OFF_BCUR    0x013C800   // bcur[256]
#define OFF_CSR     0x0140000   // ushort csr: 2MB
#define OFF_A       0x0540000   // 32MB: agH64(8)+agL64(8) -> agH128(16)+agL128(16)
#define OFF_AH128   0x0540000
#define OFF_AL128   0x1540000
#define OFF_AH64    0x0540000
#define OFF_AL64    0x0D40000
#define OFF_B       0x2540000   // 32MB: ebuf(4MB, dead after k_fine) -> qvH(16)+qvL(16)
#define OFF_EBUF    0x2540000
#define OFF_QH      0x2540000
#define OFF_QL      0x3540000
#define OFF_C       0x4540000   // 16MB: xcH(8)+xcL(8) -> Cg(8)+V(4)+mq1+mq2
#define OFF_XH      0x4540000
#define OFF_XL      0x4D40000
#define OFF_CG      0x4540000
#define OFF_V       0x4D40000
#define OFF_MQ1     0x5140000
#define OFF_MQ2     0x5460000
// peak ws: 0x5540000 (proven footprint)

// ---- canonical weight offsets (floats) ----
#define W_WREL0  0
#define W_BREL0  8192
#define W_WROOT0 8320
#define W_WREL1  16512
#define W_BREL1  32896
#define W_WROOT1 33024
#define W_GAMMA  49408
#define W_BETA   49536
#define W_KEYS0  49664
#define W_CONVW0 70144
#define W_LINW0  70149
#define W_LINB0  82949
#define W_KEYS1  83049
#define W_CONVW1 87049
#define W_LINW1  87054
#define W_LINB1  97054
#define W_MLPW1  97154
#define W_MLPB1  102154
#define W_MLPW2  102204
#define W_MLPB2  102804
#define W_TOTAL  102816

typedef __attribute__((ext_vector_type(8))) short  bf16x8;
typedef __attribute__((ext_vector_type(4))) float  f32x4;

__device__ __forceinline__ float bf2f(unsigned short u){
  union { unsigned int i; float f; } v; v.i = ((unsigned int)u) << 16; return v.f;
}
__device__ __forceinline__ unsigned short f2bf(float f){
  union { float f; unsigned int i; } v; v.f = f;
  unsigned int r = (v.i + 0x7FFFu + ((v.i >> 16) & 1u)) >> 16;   // RNE
  return (unsigned short)r;
}

__device__ const int g_seg[21] = {0,8192,8320,16512,32896,33024,49408,49536,49664,
                                  70144,70149,82949,83049,87049,87054,97054,97154,
                                  102154,102204,102804,102816};
struct WPtrs { const void* p[20]; };

// ---------------- dtype probe ----------------
__global__ void k_detect(const unsigned short* __restrict__ xr, int* flag){
  int t = threadIdx.x & 63;
  unsigned short u = xr[2*t];
  int e = (u >> 7) & 0xFF;
  bool plaus = (u != 0) && (e >= 115) && (e <= 135);
  unsigned long long m = __ballot(plaus);
  if(t == 0) flag[0] = (__popcll(m) >= 48) ? 1 : 0;
}

// x -> bf16 hi/lo planes
__global__ __launch_bounds__(256) void k_cvtx(const void* __restrict__ xin,
                                              const int* __restrict__ flag,
                                              unsigned short* __restrict__ xH,
                                              unsigned short* __restrict__ xL){
  int i = blockIdx.x*256 + threadIdx.x;          // NTOT*64
  float v;
  if(flag[0]) v = bf2f(((const unsigned short*)xin)[i]);
  else        v = ((const float*)xin)[i];
  unsigned short h = f2bf(v);
  xH[i] = h;
  xL[i] = f2bf(v - bf2f(h));
}

__global__ __launch_bounds__(256) void k_cvtw(WPtrs wp, const int* __restrict__ flag,
                                              float* __restrict__ wout){
  int i = blockIdx.x*256 + threadIdx.x;
  if(i >= W_TOTAL) return;
  int s = 0;
  #pragma unroll
  for(int k=0;k<20;k++) if(i >= g_seg[k+1]) s = k+1;
  int j = i - g_seg[s];
  const void* src = wp.p[s];
  wout[i] = flag[0] ? bf2f(((const unsigned short*)src)[j]) : ((const float*)src)[j];
}

// keys0 bf16 + lin W^T bf16 hi/lo planes
__global__ __launch_bounds__(256) void k_cvtaux(const float* __restrict__ W,
                                                unsigned short* __restrict__ k0b,
                                                unsigned short* __restrict__ wt1,
                                                unsigned short* __restrict__ wt2){
  int i = blockIdx.x*256 + threadIdx.x;
  if(i < HEADS*K1*128) k0b[i] = f2bf(W[W_KEYS0 + i]);
  if(i < 128*64){
    int col = i>>6, k = i&63;
    float wr = W[W_WREL0  + k*128 + col];
    float wo = W[W_WROOT0 + k*128 + col];
    unsigned short rh = f2bf(wr), oh = f2bf(wo);
    wt1[i]         = rh;
    wt1[ 8192 + i] = f2bf(wr - bf2f(rh));
    wt1[16384 + i] = oh;
    wt1[24576 + i] = f2bf(wo - bf2f(oh));
  }
  if(i < 128*128){
    int col = i>>7, k = i&127;
    float wr = W[W_WREL1  + k*128 + col];
    float wo = W[W_WROOT1 + k*128 + col];
    unsigned short rh = f2bf(wr), oh = f2bf(wo);
    wt2[i]         = rh;
    wt2[16384 + i] = f2bf(wr - bf2f(rh));
    wt2[32768 + i] = oh;
    wt2[49152 + i] = f2bf(wo - bf2f(oh));
  }
}

// ---------------- init ----------------
__global__ __launch_bounds__(256) void k_init(unsigned long long* bnsum,
                                              unsigned long long* bnsq, float* kl, float* cn,
                                              int* bhist){
  int i = blockIdx.x*256 + threadIdx.x;
  if(i < 128){ bnsum[i]=0ULL; bnsq[i]=0ULL; }
  if(i < 2) kl[i]=0.f;
  if(i < 256*32) cn[i]=0.f;
  if(i < 256) bhist[i]=0;
}

// ---------------- CSR build: two-level counting sort ----------------
// bucket = dst>>8 (256 buckets x ~4096 edges). Segments parallel node-level csr.
__global__ __launch_bounds__(256) void k_bin1(const int* __restrict__ dst, int* bhist){
  __shared__ int hist[256];
  const int t = threadIdx.x;
  hist[t] = 0; __syncthreads();
  const int e0 = blockIdx.x*4096 + t;
  #pragma unroll 4
  for(int j=0;j<16;j++) atomicAdd(&hist[dst[e0 + j*256] >> 8], 1);
  __syncthreads();
  if(hist[t]) atomicAdd(&bhist[t], hist[t]);
}

__global__ __launch_bounds__(256) void k_bscan(const int* __restrict__ bhist,
                                               int* ebase, int* bcur){
  __shared__ int ts[256];
  const int t = threadIdx.x;
  ts[t] = bhist[t]; __syncthreads();
  for(int off=1; off<256; off<<=1){
    int v = (t>=off) ? ts[t-off] : 0;
    __syncthreads(); ts[t] += v; __syncthreads();
  }
  int ex = (t==0) ? 0 : ts[t-1];
  ebase[t] = ex; bcur[t] = ex;
}

__global__ __launch_bounds__(256) void k_bin2(const int* __restrict__ src, const int* __restrict__ dst,
                                              int* bcur, unsigned int* __restrict__ ebuf){
  __shared__ int hist[256], lofs[256], lcur[256], gbase[256];
  __shared__ unsigned int sbuf[4096];
  const int t = threadIdx.x;
  hist[t] = 0; __syncthreads();
  const int e0 = blockIdx.x*4096;
  unsigned int pair[16]; int bk[16];
  #pragma unroll 4
  for(int j=0;j<16;j++){
    int e = e0 + t + j*256;
    int s = src[e], d = dst[e];
    pair[j] = (((unsigned)d)<<16) | (unsigned)s;
    bk[j] = d>>8;
    atomicAdd(&hist[bk[j]], 1);
  }
  __syncthreads();
  lcur[t] = hist[t]; __syncthreads();
  for(int off=1; off<256; off<<=1){
    int v = (t>=off) ? lcur[t-off] : 0;
    __syncthreads(); lcur[t] += v; __syncthreads();
  }
  lofs[t] = (t==0) ? 0 : lcur[t-1];
  __syncthreads();
  lcur[t] = lofs[t];
  if(hist[t]) gbase[t] = atomicAdd(&bcur[t], hist[t]);
  __syncthreads();
  #pragma unroll 4
  for(int j=0;j<16;j++){
    int p = atomicAdd(&lcur[bk[j]], 1);
    sbuf[p] = pair[j];
  }
  __syncthreads();
  // thread t streams out bucket t's run (~16 u32 = 64B, full-line writes)
  const int n = hist[t], lo = lofs[t], go = gbase[t];
  for(int i=0;i<n;i++) ebuf[go + i] = sbuf[lo + i];
}

// block b = bucket b: build the fine CSR entirely in LDS, write coalesced.
__global__ __launch_bounds__(256) void k_fine(const unsigned int* __restrict__ ebuf,
                                              const int* __restrict__ ebase,
                                              unsigned short* __restrict__ csr,
                                              int* __restrict__ deg, int* __restrict__ offs){
  __shared__ int ldeg[256], lofs[256], lcur[256];
  __shared__ unsigned int led[8192];
  __shared__ unsigned short lcsr[8192];
  const int b = blockIdx.x, t = threadIdx.x;
  const int base = ebase[b];
  const int n = ((b==255) ? NEDGE : ebase[b+1]) - base;
  ldeg[t] = 0; __syncthreads();
  for(int i=t; i<n; i+=256){
    unsigned int p = ebuf[base+i];
    led[i] = p;
    atomicAdd(&ldeg[(p>>16)&255], 1);
  }
  __syncthreads();
  lcur[t] = ldeg[t]; __syncthreads();
  for(int off=1; off<256; off<<=1){
    int v = (t>=off) ? lcur[t-off] : 0;
    __syncthreads(); lcur[t] += v; __syncthreads();
  }
  lofs[t] = (t==0) ? 0 : lcur[t-1];
  __syncthreads();
  lcur[t] = lofs[t];
  __syncthreads();
  for(int i=t; i<n; i+=256){
    unsigned int p = led[i];
    int d = (p>>16)&255;
    int pos = atomicAdd(&lcur[d], 1);
    lcsr[pos] = (unsigned short)(p & 0xFFFF);
  }
  __syncthreads();
  for(int i=t; i<n; i+=256) csr[base+i] = lcsr[i];
  deg[b*256 + t]  = ldeg[t];
  offs[b*256 + t] = base + lofs[t];
}

// ---------------- graph aggregation (bf16 gathers, f32 acc, hi/lo out) --------
__global__ __launch_bounds__(256) void k_aggr64(const unsigned short* __restrict__ xH,
                                                const int* __restrict__ offs, const int* __restrict__ deg,
                                                const unsigned short* __restrict__ csr,
                                                unsigned short* __restrict__ aH,
                                                unsigned short* __restrict__ aL){
  const int wid  = (blockIdx.x*256 + threadIdx.x) >> 6;
  const int lane = threadIdx.x & 63;
  const int sub = lane >> 4, fl = lane & 15;
  const int beg = offs[wid], n = deg[wid];
  float4 acc = {0.f,0.f,0.f,0.f};
  int i = 0;
  for(; i+32 <= n; i += 32){
    int s[8];
    #pragma unroll
    for(int j=0;j<8;j++) s[j] = csr[beg + i + 4*j + sub];
    #pragma unroll
    for(int j=0;j<8;j++){
      ushort4 u = *(const ushort4*)(xH + (size_t)s[j]*64 + fl*4);
      acc.x += bf2f(u.x); acc.y += bf2f(u.y); acc.z += bf2f(u.z); acc.w += bf2f(u.w);
    }
  }
  for(; i < n; i += 4){
    if(i + sub < n){
      int s = csr[beg + i + sub];
      ushort4 u = *(const ushort4*)(xH + (size_t)s*64 + fl*4);
      acc.x += bf2f(u.x); acc.y += bf2f(u.y); acc.z += bf2f(u.z); acc.w += bf2f(u.w);
    }
  }
  acc.x += __shfl_xor(acc.x, 16); acc.y += __shfl_xor(acc.y, 16);
  acc.z += __shfl_xor(acc.z, 16); acc.w += __shfl_xor(acc.w, 16);
  acc.x += __shfl_xor(acc.x, 32); acc.y += __shfl_xor(acc.y, 32);
  acc.z += __shfl_xor(acc.z, 32); acc.w += __shfl_xor(acc.w, 32);
  if(sub == 0){
    ushort4 h, l;
    h.x=f2bf(acc.x); l.x=f2bf(acc.x-bf2f(h.x));
    h.y=f2bf(acc.y); l.y=f2bf(acc.y-bf2f(h.y));
    h.z=f2bf(acc.z); l.z=f2bf(acc.z-bf2f(h.z));
    h.w=f2bf(acc.w); l.w=f2bf(acc.w-bf2f(h.w));
    *(ushort4*)(aH + (size_t)wid*64 + fl*4) = h;
    *(ushort4*)(aL + (size_t)wid*64 + fl*4) = l;
  }
}

__global__ __launch_bounds__(256) void k_aggr128(const unsigned short* __restrict__ qH,
                                                 const int* __restrict__ offs, const int* __restrict__ deg,
                                                 const unsigned short* __restrict__ csr,
                                                 unsigned short* __restrict__ aH,
                                                 unsigned short* __restrict__ aL){
  const int wid  = (blockIdx.x*256 + threadIdx.x) >> 6;
  const int lane = threadIdx.x & 63;
  const int sub = lane >> 5, fl = lane & 31;
  const int beg = offs[wid], n = deg[wid];
  float4 acc = {0.f,0.f,0.f,0.f};
  int i = 0;
  for(; i+16 <= n; i += 16){
    int s[8];
    #pragma unroll
    for(int j=0;j<8;j++) s[j] = csr[beg + i + 2*j + sub];
    #pragma unroll
    for(int j=0;j<8;j++){
      ushort4 u = *(const ushort4*)(qH + (size_t)s[j]*128 + fl*4);
      acc.x += bf2f(u.x); acc.y += bf2f(u.y); acc.z += bf2f(u.z); acc.w += bf2f(u.w);
    }
  }
  for(; i < n; i += 2){
    if(i + sub < n){
      int s = csr[beg + i + sub];
      ushort4 u = *(const ushort4*)(qH + (size_t)s*128 + fl*4);
      acc.x += bf2f(u.x); acc.y += bf2f(u.y); acc.z += bf2f(u.z); acc.w += bf2f(u.w);
    }
  }
  acc.x += __shfl_xor(acc.x, 32); acc.y += __shfl_xor(acc.y, 32);
  acc.z += __shfl_xor(acc.z, 32); acc.w += __shfl_xor(acc.w, 32);
  if(sub == 0){
    ushort4 h, l;
    h.x=f2bf(acc.x); l.x=f2bf(acc.x-bf2f(h.x));
    h.y=f2bf(acc.y); l.y=f2bf(acc.y-bf2f(h.y));
    h.z=f2bf(acc.z); l.z=f2bf(acc.z-bf2f(h.z));
    h.w=f2bf(acc.w); l.w=f2bf(acc.w-bf2f(h.w));
    *(ushort4*)(aH + (size_t)wid*128 + fl*4) = h;
    *(ushort4*)(aL + (size_t)wid*128 + fl*4) = l;
  }
}

// ---------------- lin via split-bf16 MFMA, weight-fragments resident in VGPRs --
template<int KD>
__global__ __launch_bounds__(256) void k_ling(const unsigned short* __restrict__ AH,
                                              const unsigned short* __restrict__ AL,
                                              const unsigned short* XH,
                                              const unsigned short* XL,
                                              const unsigned short* __restrict__ WT,
                                              const float* __restrict__ W, int bofs,
                                              unsigned short* outH,
                                              unsigned short* outL){
  constexpr int NK = KD/32;
  const int t = threadIdx.x;
  const int wv = t>>6, lane = t&63, quad = lane>>4, m = lane&15;
  const int rbase = blockIdx.x*128;
  const int c0 = (wv*2)*16 + m;
  const int c1 = (wv*2+1)*16 + m;

  bf16x8 BrH0[NK], BrL0[NK], BoH0[NK], BoL0[NK];
  bf16x8 BrH1[NK], BrL1[NK], BoH1[NK], BoL1[NK];
  #pragma unroll
  for(int ks=0; ks<NK; ks++){
    const size_t o0 = (size_t)c0*KD + ks*32 + quad*8;
    const size_t o1 = (size_t)c1*KD + ks*32 + quad*8;
    BrH0[ks] = *(const bf16x8*)(WT + o0);
    BrL0[ks] = *(const bf16x8*)(WT + 128*KD + o0);
    BoH0[ks] = *(const bf16x8*)(WT + 256*KD + o0);
    BoL0[ks] = *(const bf16x8*)(WT + 384*KD + o0);
    BrH1[ks] = *(const bf16x8*)(WT + o1);
    BrL1[ks] = *(const bf16x8*)(WT + 128*KD + o1);
    BoH1[ks] = *(const bf16x8*)(WT + 256*KD + o1);
    BoL1[ks] = *(const bf16x8*)(WT + 384*KD + o1);
  }
  const float b0 = W[bofs + c0];
  const float b1 = W[bofs + c1];

  for(int rt=0; rt<8; rt++){
    const int r0 = rbase + rt*16;
    bf16x8 fah[NK], fal[NK], fxh[NK], fxl[NK];
    #pragma unroll
    for(int ks=0; ks<NK; ks++){
      const size_t o = (size_t)(r0+m)*KD + ks*32 + quad*8;
      fah[ks] = *(const bf16x8*)(AH + o);
      fal[ks] = *(const bf16x8*)(AL + o);
      fxh[ks] = *(const bf16x8*)(XH + o);
      fxl[ks] = *(const bf16x8*)(XL + o);
    }
    f32x4 a0 = {0.f,0.f,0.f,0.f}, a1 = {0.f,0.f,0.f,0.f};
    #pragma unroll
    for(int ks=0; ks<NK; ks++){
      a0 = __builtin_amdgcn_mfma_f32_16x16x32_bf16(fah[ks], BrH0[ks], a0, 0,0,0);
      a1 = __builtin_amdgcn_mfma_f32_16x16x32_bf16(fah[ks], BrH1[ks], a1, 0,0,0);
      a0 = __builtin_amdgcn_mfma_f32_16x16x32_bf16(fal[ks], BrH0[ks], a0, 0,0,0);
      a1 = __builtin_amdgcn_mfma_f32_16x16x32_bf16(fal[ks], BrH1[ks], a1, 0,0,0);
      a0 = __builtin_amdgcn_mfma_f32_16x16x32_bf16(fah[ks], BrL0[ks], a0, 0,0,0);
      a1 = __builtin_amdgcn_mfma_f32_16x16x32_bf16(fah[ks], BrL1[ks], a1, 0,0,0);
      a0 = __builtin_amdgcn_mfma_f32_16x16x32_bf16(fxh[ks], BoH0[ks], a0, 0,0,0);
      a1 = __builtin_amdgcn_mfma_f32_16x16x32_bf16(fxh[ks], BoH1[ks], a1, 0,0,0);
      a0 = __builtin_amdgcn_mfma_f32_16x16x32_bf16(fxl[ks], BoH0[ks], a0, 0,0,0);
      a1 = __builtin_amdgcn_mfma_f32_16x16x32_bf16(fxl[ks], BoH1[ks], a1, 0,0,0);
      a0 = __builtin_amdgcn_mfma_f32_16x16x32_bf16(fxh[ks], BoL0[ks], a0, 0,0,0);
      a1 = __builtin_amdgcn_mfma_f32_16x16x32_bf16(fxh[ks], BoL1[ks], a1, 0,0,0);
    }
    __syncthreads();   // all waves done reading tile rt (incl. aliased X) before writes
    #pragma unroll
    for(int i=0;i<4;i++){
      const size_t orow = (size_t)(r0 + quad*4 + i)*128;
      float v0 = fmaxf(a0[i] + b0, 0.f);
      unsigned short h0 = f2bf(v0);
      outH[orow + c0] = h0;
      outL[orow + c0] = f2bf(v0 - bf2f(h0));
      float v1 = fmaxf(a1[i] + b1, 0.f);
      unsigned short h1 = f2bf(v1);
      outH[orow + c1] = h1;
      outL[orow + c1] = f2bf(v1 - bf2f(h1));
    }
  }
}

// ---------------- batchnorm ----------------
__global__ __launch_bounds__(128) void k_bnstats(const unsigned short* __restrict__ qH,
                                                 const unsigned short* __restrict__ qL,
                                                 double* bnsum, double* bnsq){
  const int j = threadIdx.x;
  const int r0 = blockIdx.x*128;
  float s=0.f, s2=0.f;
  for(int r=0;r<128;r++){
    size_t o = (size_t)(r0+r)*128 + j;
    float v = bf2f(qH[o]) + bf2f(qL[o]);
    s += v; s2 += v*v;
  }
  atomicAdd(&bnsum[j], (double)s);
  atomicAdd(&bnsq[j], (double)s2);
}

__global__ __launch_bounds__(256) void k_bnfin(const double* __restrict__ bnsum, const double* __restrict__ bnsq,
                                               const float* __restrict__ W,
                                               float* scale, float* shift, float* ksq0, float* ksq1){
  const int t = threadIdx.x;
  if(t < 128){
    double mu  = bnsum[t] / (double)NTOT;
    double var = bnsq[t] / (double)NTOT - mu*mu;
    if(var < 0.0) var = 0.0;
    float sc = W[W_GAMMA + t] * rsqrtf((float)var + 1e-5f);
    scale[t] = sc;
    shift[t] = W[W_BETA + t] - (float)mu * sc;
  }
  if(t < HEADS*K1){
    float s=0.f;
    for(int f=0;f<128;f++){ float v = W[W_KEYS0 + t*128 + f]; s += v*v; }
    ksq0[t] = s;
  }
  if(t < HEADS*K2){
    float s=0.f;
    for(int f=0;f<100;f++){ float v = W[W_KEYS1 + t*100 + f]; s += v*v; }
    ksq1[t] = s;
  }
}

// ---------------- memconv0 stage A: fused qk MFMA + C + partial cn ------------
__global__ __launch_bounds__(256) void k_memA(
    const unsigned short* __restrict__ qH, const unsigned short* __restrict__ qL,
    const float* __restrict__ scale, const float* __restrict__ shift,
    const unsigned short* __restrict__ k0b,
    const float* __restrict__ W, const float* __restrict__ ksq,
    float* __restrict__ Cg, float* __restrict__ cn)
{
  __shared__ unsigned short Qb[64*136];
  __shared__ float qkL[160*68];        // [col][row]
  __shared__ float wsumL[64*36];
  __shared__ float qsqL[64];
  __shared__ float rsL[64*6];
  const int bid = blockIdx.x;
  const int r0 = bid*64;
  const int t = threadIdx.x;
  const int wv = t>>6, lane = t&63, quad = lane>>4, m = lane&15;

  for(int idx=t; idx<64*32; idx+=256){
    int r = idx>>5, c4 = (idx&31)*4;
    size_t o = (size_t)(r0+r)*128 + c4;
    ushort4 uh = *(const ushort4*)(qH + o);
    ushort4 ul = *(const ushort4*)(qL + o);
    float4 s = *(const float4*)(scale + c4);
    float4 h = *(const float4*)(shift + c4);
    ushort4 ob;
    ob.x = f2bf((bf2f(uh.x)+bf2f(ul.x))*s.x + h.x);
    ob.y = f2bf((bf2f(uh.y)+bf2f(ul.y))*s.y + h.y);
    ob.z = f2bf((bf2f(uh.z)+bf2f(ul.z))*s.z + h.z);
    ob.w = f2bf((bf2f(uh.w)+bf2f(ul.w))*s.w + h.w);
    *(ushort4*)(Qb + r*136 + c4) = ob;
  }
  __syncthreads();

  {
    bf16x8 a[4];
    #pragma unroll
    for(int ks=0;ks<4;ks++)
      a[ks] = *(const bf16x8*)(Qb + (wv*16+m)*136 + ks*32 + quad*8);
    for(int nb=0; nb<10; nb++){
      f32x4 acc = {0.f,0.f,0.f,0.f};
      const bf16x8* brow = (const bf16x8*)(k0b + (size_t)(nb*16+m)*128);
      #pragma unroll
      for(int ks=0;ks<4;ks++)
        acc = __builtin_amdgcn_mfma_f32_16x16x32_bf16(a[ks], brow[ks*4+quad], acc,0,0,0);
      *(f32x4*)(qkL + (nb*16+m)*68 + wv*16 + quad*4) = acc;
    }
  }
  if(t < 64){
    float s = 0.f;
    for(int j=0;j<16;j++){
      bf16x8 v = *(const bf16x8*)(Qb + t*136 + j*8);
      #pragma unroll
      for(int e=0;e<8;e++){ float f = bf2f((unsigned short)v[e]); s += f*f; }
    }
    qsqL[t] = s;
  }
  __syncthreads();

  {
    int row = t & 63, g = t >> 6;
    float q2 = qsqL[row];
    #pragma unroll
    for(int pass=0; pass<2; pass++){
      int h = g + pass*4;
      if(h < HEADS){
        float rs = 0.f;
        for(int k=0;k<32;k++){
          float d2 = q2 + ksq[h*32+k] - 2.f*qkL[(h*32+k)*68 + row];
          d2 = fmaxf(d2, 1e-12f);
          rs += 1.f/(1.f+d2);
        }
        rsL[row*6+h] = W[W_CONVW0+h]/fmaxf(rs,1e-20f);
      }
    }
  }
  __syncthreads();

  {
    int row = t & 63, kq = t >> 6;
    float q2 = qsqL[row];
    for(int kk=0; kk<8; kk++){
      int k = kq*8+kk;
      float wsum = 0.f;
      #pragma unroll
      for(int h=0;h<HEADS;h++){
        float d2 = q2 + ksq[h*32+k] - 2.f*qkL[(h*32+k)*68 + row];
        d2 = fmaxf(d2, 1e-12f);
        wsum += rsL[row*6+h]/(1.f+d2);
      }
      wsumL[row*36+k] = wsum;
    }
  }
  __syncthreads();

  if(t < 64){
    float mx = -1e30f;
    #pragma unroll
    for(int k=0;k<32;k++) mx = fmaxf(mx, wsumL[t*36+k]);
    float cv[32]; float se = 0.f;
    #pragma unroll
    for(int k=0;k<32;k++){ float e = __expf(wsumL[t*36+k]-mx); cv[k]=e; se+=e; }
    float inv = 1.f/se;
    #pragma unroll
    for(int k=0;k<32;k++){ cv[k]*=inv; wsumL[t*36+k]=cv[k]; }
    float4* dst = (float4*)(Cg + (size_t)(r0+t)*32);
    #pragma unroll
    for(int k4=0;k4<8;k4++)
      dst[k4] = (float4){cv[k4*4],cv[k4*4+1],cv[k4*4+2],cv[k4*4+3]};
  }
  __syncthreads();
  if(t < 32){
    float s = 0.f;
    for(int r=0;r<64;r++) s += wsumL[r*36+t];
    atomicAdd(&cn[(bid>>2)*32 + t], s);
  }
}

// ---------------- memconv0 stage B: KL ----------------
__global__ __launch_bounds__(256) void k_memB(const float* __restrict__ Cg,
                                              const float* __restrict__ cn,
                                              float* __restrict__ klacc){
  __shared__ float cn_s[32];
  __shared__ float red_s[4];
  const int b = blockIdx.x, t = threadIdx.x;
  if(t < 32) cn_s[t] = cn[b*32+t] + EPSF;
  __syncthreads();
  const float* crow = Cg + ((size_t)b*256 + t)*32;
  float cv[32]; float pn = 0.f;
  #pragma unroll
  for(int k4=0;k4<8;k4++){
    float4 u = *(const float4*)(crow + k4*4);
    cv[k4*4]=u.x; cv[k4*4+1]=u.y; cv[k4*4+2]=u.z; cv[k4*4+3]=u.w;
  }
  #pragma unroll
  for(int k=0;k<32;k++) pn += cv[k]*cv[k]/cn_s[k];
  pn += EPSF;
  float acc = 0.f;
  #pragma unroll
  for(int k=0;k<32;k++){
    float P = cv[k]*cv[k]/(cn_s[k]*pn);
    acc += P*(__logf(P+EPSF) - __logf(cv[k]+EPSF));
  }
  #pragma unroll
  for(int off=32; off>0; off>>=1) acc += __shfl_down(acc, off);
  if((t&63)==0) red_s[t>>6] = acc;
  __syncthreads();
  if(t==0) atomicAdd(klacc, 100.f*(red_s[0]+red_s[1]+red_s[2]+red_s[3]));
}

// ---------------- memconv0 stage V: V = C^T Q ----------------
__global__ __launch_bounds__(256) void k_memV(const float* __restrict__ Cg,
                                              const unsigned short* __restrict__ qH,
                                              const unsigned short* __restrict__ qL,
                                              const float* __restrict__ scale,
                                              const float* __restrict__ shift,
                                              float* __restrict__ V){
  __shared__ float Cs[256*36];
  __shared__ float Qs[256*32];
  const int b  = blockIdx.x >> 2;
  const int f0 = (blockIdx.x & 3) * 32;
  const int t = threadIdx.x;
  for(int idx=t; idx<256*8; idx+=256){
    int n = idx>>3, k4 = (idx&7)*4;
    *(float4*)(Cs + n*36 + k4) = *(const float4*)(Cg + ((size_t)b*256+n)*32 + k4);
  }
  for(int idx=t; idx<256*8; idx+=256){
    int n = idx>>3, j4 = (idx&7)*4;
    size_t o = ((size_t)b*256+n)*128 + f0 + j4;
    ushort4 uh = *(const ushort4*)(qH + o);
    ushort4 ul = *(const ushort4*)(qL + o);
    float4 s = *(const float4*)(scale + f0 + j4);
    float4 h = *(const float4*)(shift + f0 + j4);
    *(float4*)(Qs + n*32 + j4) = (float4){
      (bf2f(uh.x)+bf2f(ul.x))*s.x + h.x,
      (bf2f(uh.y)+bf2f(ul.y))*s.y + h.y,
      (bf2f(uh.z)+bf2f(ul.z))*s.z + h.z,
      (bf2f(uh.w)+bf2f(ul.w))*s.w + h.w};
  }
  __syncthreads();
  const int k = t & 31, fg = t >> 5;
  float v0=0.f,v1=0.f,v2=0.f,v3=0.f;
  for(int n=0;n<256;n++){
    float c = Cs[n*36+k];
    float4 q = *(const float4*)(Qs + n*32 + fg*4);
    v0 += c*q.x; v1 += c*q.y; v2 += c*q.z; v3 += c*q.w;
  }
  *(float4*)(V + ((size_t)b*32 + k)*128 + f0 + fg*4) = (float4){v0,v1,v2,v3};
}

// ---------------- memconv0 stage L: lin0 ----------------
__global__ __launch_bounds__(256) void k_memL(const float* __restrict__ V,
                                              const float* __restrict__ W,
                                              float* __restrict__ mq1){
  __shared__ float Vs[32*132];
  const int b = blockIdx.x, t = threadIdx.x;
  for(int idx=t; idx<32*32; idx+=256){
    int k = idx>>5, j4 = (idx&31)*4;
    *(float4*)(Vs + k*132 + j4) = *(const float4*)(V + ((size_t)b*32+k)*128 + j4);
  }
  __syncthreads();
  for(int idx=t; idx<K1*MEMH; idx+=256){
    int k = idx/100, mc = idx - k*100;
    float a = W[W_LINB0 + mc];
    for(int f=0; f<128; f++) a += Vs[k*132+f]*W[W_LINW0 + f*100 + mc];
    mq1[(size_t)(b*32+k)*100 + mc] = (a>0.f) ? a : 0.01f*a;
  }
}

// ---------------- mem conv 1 ----------------
__global__ __launch_bounds__(256) void k_memconv1(
    const float* __restrict__ mq1, const float* __restrict__ W,
    const float* __restrict__ ksq, float* __restrict__ mq2, float* __restrict__ klacc)
{
  __shared__ float Qs[32*104];
  __shared__ float Ks[40*100];
  __shared__ float QKs[32*40];
  __shared__ float Cs[32*8];
  __shared__ float cn_s[8];
  __shared__ float pn_s[32];
  __shared__ float qsq_s[32];
  __shared__ float Vs[8*100];
  __shared__ float red_s[4];
  const int b = blockIdx.x, t = threadIdx.x;

  for(int idx=t; idx<32*100; idx+=256){
    int n = idx/100, f = idx - n*100;
    Qs[n*104+f] = mq1[(size_t)b*3200 + idx];
  }
  for(int idx=t; idx<40*100; idx+=256) Ks[idx] = W[W_KEYS1 + idx];
  __syncthreads();

  if(t < 32){ float s=0.f; for(int f=0;f<100;f++){ float v=Qs[t*104+f]; s+=v*v; } qsq_s[t]=s; }
  for(int idx=t; idx<32*40; idx+=256){
    int n = idx/40, c = idx - n*40;
    float a = 0.f;
    for(int f=0;f<100;f++) a += Qs[n*104+f]*Ks[c*100+f];
    QKs[idx] = a;
  }
  __syncthreads();

  if(t < 32){
    float wsum[8];
    #pragma unroll
    for(int k=0;k<8;k++) wsum[k]=0.f;
    for(int h=0;h<HEADS;h++){
      float cw = W[W_CONVW1 + h];
      float c[8]; float rs=0.f;
      #pragma unroll
      for(int k=0;k<8;k++){
        float d2 = qsq_s[t] + ksq[h*8+k] - 2.f*QKs[t*40 + h*8+k];
        d2 = fmaxf(d2, 1e-12f);
        float cc = 1.f/(1.f+d2);
        c[k]=cc; rs+=cc;
      }
      float sc = cw/fmaxf(rs, 1e-20f);
      #pragma unroll
      for(int k=0;k<8;k++) wsum[k] += c[k]*sc;
    }
    float mx = wsum[0];
    #pragma unroll
    for(int k=1;k<8;k++) mx = fmaxf(mx, wsum[k]);
    float se=0.f;
    #pragma unroll
    for(int k=0;k<8;k++){ float e=__expf(wsum[k]-mx); wsum[k]=e; se+=e; }
    float inv = 1.f/se;
    #pragma unroll
    for(int k=0;k<8;k++) Cs[t*8+k] = wsum[k]*inv;
  }
  __syncthreads();
  if(t < 8){ float s=0.f; for(int n=0;n<32;n++) s += Cs[n*8+t]; cn_s[t]=s+EPSF; }
  __syncthreads();
  if(t < 32){
    float p=0.f;
    #pragma unroll
    for(int k=0;k<8;k++){ float sv=Cs[t*8+k]; p += sv*sv/cn_s[k]; }
    pn_s[t]=p+EPSF;
  }
  __syncthreads();

  float acc;
  {
    int n = t>>3, k = t&7;
    float sv = Cs[t];
    float P = sv*sv/(cn_s[k]*pn_s[n]);
    acc = P*(__logf(P+EPSF) - __logf(sv+EPSF));
  }
  #pragma unroll
  for(int off=32; off>0; off>>=1) acc += __shfl_down(acc, off);
  if((t&63)==0) red_s[t>>6] = acc;

  for(int idx=t; idx<8*100; idx+=256){
    int k = idx/100, f = idx - k*100;
    float a=0.f;
    for(int n=0;n<32;n++) a += Cs[n*8+k]*Qs[n*104+f];
    Vs[idx] = a;
  }
  __syncthreads();

  if(t==0) atomicAdd(klacc, 100.f*(red_s[0]+red_s[1]+red_s[2]+red_s[3]));

  for(int idx=t; idx<8*100; idx+=256){
    int k = idx/100, mc = idx - k*100;
    float a = W[W_LINB1 + mc];
    for(int f=0;f<100;f++) a += Vs[k*100+f]*W[W_LINW1 + f*100 + mc];
    mq2[(size_t)b*800 + idx] = (a>0.f) ? a : 0.01f*a;
  }
}

// ---------------- head ----------------
__global__ __launch_bounds__(128) void k_final(const float* __restrict__ mq2,
                                               const float* __restrict__ W,
                                               const int* __restrict__ flag,
                                               const float* __restrict__ kl,
                                               void* __restrict__ out){
  __shared__ float h_s[100];
  __shared__ float hid_s[50];
  const int b = blockIdx.x, t = threadIdx.x;
  if(t < 100){
    float s=0.f;
    #pragma unroll
    for(int k=0;k<8;k++) s += mq2[(size_t)b*800 + k*100 + t];
    h_s[t] = s*0.125f;
  }
  __syncthreads();
  if(t < 50){
    float a = W[W_MLPB1 + t];
    for(int f=0;f<100;f++) a += h_s[f]*W[W_MLPW1 + f*50 + t];
    hid_s[t] = (a>0.f) ? a : 0.01f*a;
  }
  __syncthreads();
  if(t < 12){
    float a = W[W_MLPB2 + t];
    #pragma unroll
    for(int j=0;j<50;j++) a += hid_s[j]*W[W_MLPW2 + j*12 + t];
    if(flag[0]) ((__hip_bfloat16*)out)[b*12+t] = __float2bfloat16(a);
    else        ((float*)out)[b*12+t] = a;
  }
  if(b==0 && t==64){
    float v = (kl[0]+kl[1]) * (1.f/65536.f);
    if(flag[0]) ((__hip_bfloat16*)out)[3072] = __float2bfloat16(v);
    else        ((float*)out)[3072] = v;
  }
}

// ---------------- launch ----------------
extern "C" void kernel_launch(void* const* d_in, const int* in_sizes, int n_in,
                              void* d_out, int out_size, void* d_ws, size_t ws_size,
                              hipStream_t stream) {
  (void)in_sizes; (void)n_in; (void)out_size; (void)ws_size;
  const void* x   = d_in[0];
  const int*  ei  = (const int*)d_in[1];
  const int* src = ei;
  const int* dst = ei + NEDGE;

  WPtrs wp;
  for(int i=0;i<20;i++) wp.p[i] = d_in[3+i];

  char* w = (char*)d_ws;
  int*    deg    = (int*)   (w + OFF_DEG);
  int*    offs   = (int*)   (w + OFF_OFFS);
  double* bnsum  = (double*)(w + OFF_BNSUM);
  double* bnsq   = (double*)(w + OFF_BNSQ);
  float*  scale  = (float*) (w + OFF_SCALE);
  float*  shift  = (float*) (w + OFF_SHIFT);
  float*  ksq0   = (float*) (w + OFF_KSQ0);
  float*  ksq1   = (float*) (w + OFF_KSQ1);
  float*  kl     = (float*) (w + OFF_KL);
  int*    flag   = (int*)   (w + OFF_FLAG);
  float*  Wc     = (float*) (w + OFF_W);
  unsigned short* k0b = (unsigned short*)(w + OFF_K0B);
  unsigned short* wt1 = (unsigned short*)(w + OFF_WT1);
  unsigned short* wt2 = (unsigned short*)(w + OFF_WT2);
  float*  cn     = (float*) (w + OFF_CN);
  int*    bhist  = (int*)   (w + OFF_BH);
  int*    ebase  = (int*)   (w + OFF_EBASE);
  int*    bcur   = (int*)   (w + OFF_BCUR);
  unsigned short* csr = (unsigned short*)(w + OFF_CSR);
  unsigned int*   ebuf = (unsigned int*)(w + OFF_EBUF);
  unsigned short* agH64  = (unsigned short*)(w + OFF_AH64);
  unsigned short* agL64  = (unsigned short*)(w + OFF_AL64);
  unsigned short* agH128 = (unsigned short*)(w + OFF_AH128);
  unsigned short* agL128 = (unsigned short*)(w + OFF_AL128);
  unsigned short* qvH    = (unsigned short*)(w + OFF_QH);
  unsigned short* qvL    = (unsigned short*)(w + OFF_QL);
  unsigned short* xcH    = (unsigned short*)(w + OFF_XH);
  unsigned short* xcL    = (unsigned short*)(w + OFF_XL);
  float*  Cg     = (float*) (w + OFF_CG);
  float*  Vbuf   = (float*) (w + OFF_V);
  float*  mq1    = (float*) (w + OFF_MQ1);
  float*  mq2    = (float*) (w + OFF_MQ2);

  unsigned short* qbnH = qvH;
  unsigned short* qbnL = qvL;

  k_detect <<<1,      64, 0, stream>>>((const unsigned short*)x, flag);
  k_init   <<<32,    256, 0, stream>>>((unsigned long long*)bnsum, (unsigned long long*)bnsq, kl, cn, bhist);
  k_bin1   <<<256,   256, 0, stream>>>(dst, bhist);
  k_bscan  <<<1,     256, 0, stream>>>(bhist, ebase, bcur);
  k_bin2   <<<256,   256, 0, stream>>>(src, dst, bcur, ebuf);
  k_fine   <<<256,   256, 0, stream>>>(ebuf, ebase, csr, deg, offs);
  k_cvtx   <<<16384, 256, 0, stream>>>(x, flag, xcH, xcL);
  k_cvtw   <<<402,   256, 0, stream>>>(wp, flag, Wc);
  k_cvtaux <<<80,    256, 0, stream>>>(Wc, k0b, wt1, wt2);
  k_aggr64 <<<16384, 256, 0, stream>>>(xcH, offs, deg, csr, agH64, agL64);
  k_ling<64> <<<512, 256, 0, stream>>>(agH64, agL64, xcH, xcL, wt1, Wc, W_BREL0, qvH, qvL);
  k_aggr128<<<16384, 256, 0, stream>>>(qvH, offs, deg, csr, agH128, agL128);
  k_ling<128><<<512, 256, 0, stream>>>(agH128, agL128, qvH, qvL, wt2, Wc, W_BREL1, qbnH, qbnL);
  k_bnstats<<<512,   128, 0, stream>>>(qbnH, qbnL, bnsum, bnsq);
  k_bnfin  <<<1,     256, 0, stream>>>(bnsum, bnsq, Wc, scale, shift, ksq0, ksq1);
  k_memA   <<<1024,  256, 0, stream>>>(qbnH, qbnL, scale, shift, k0b, Wc, ksq0, Cg, cn);
  k_memB   <<<256,   256, 0, stream>>>(Cg, cn, kl);
  k_memV   <<<1024,  256, 0, stream>>>(Cg, qbnH, qbnL, scale, shift, Vbuf);
  k_memL   <<<256,   256, 0, stream>>>(Vbuf, Wc, mq1);
  k_memconv1<<<256,  256, 0, stream>>>(mq1, Wc, ksq1, mq2, kl+1);
  k_final  <<<256,   128, 0, stream>>>(mq2, Wc, flag, kl, d_out);
}

// Round 12
// 457.819 us; speedup vs baseline: 2.5356x; 1.0465x over previous
//
#include <hip/hip_runtime.h>
#include <hip/hip_bf16.h>

#define NTOT   65536
#define NEDGE  1048576
#define HEADS  5
#define K1     32
#define K2     8
#define MEMH   100
#define EPSF   1e-8f

// ---- workspace layout (bytes) ----
#define OFF_DEG     0x0000000   // deg[65536]; doubles as bh2[256*256] before k_fine
#define OFF_BH2     0x0000000
#define OFF_CURSOR  0x0040000   // dead -> WT planes
#define OFF_WT1     0x0040000
#define OFF_WT2     0x0050000   // ends 0x70000
#define OFF_OFFS    0x0080000
#define OFF_BNSUM   0x00C0000   // f32[128]
#define OFF_BNSQ    0x00C0400   // f32[128]
#define OFF_SCALE   0x00C0800
#define OFF_SHIFT   0x00C0A00
#define OFF_KSQ0    0x00C0C00
#define OFF_KSQ1    0x00C0E80
#define OFF_KL      0x00C0F40
#define OFF_FLAG    0x00C0F60
#define OFF_W       0x00C1000   // f32 weights
#define OFF_K0B     0x0128000   // keys0 bf16 (40KB)
#define OFF_CN      0x0134000   // cn[256*32] f32
#define OFF_EBASE   0x013C400   // ebase[256]
#define OFF_BCUR    0x013C800   // bcur[256]
#define OFF_CSR     0x0140000   // ushort csr: 2MB
#define OFF_A       0x0540000   // 32MB: agH64(8)+agL64(8) -> agH128(16)+agL128(16)
#define OFF_AH128   0x0540000
#define OFF_AL128   0x1540000
#define OFF_AH64    0x0540000
#define OFF_AL64    0x0D40000
#define OFF_B       0x2540000   // 32MB: ebuf(4MB, dead after k_fine) -> qvH(16)+qvL(16)
#define OFF_EBUF    0x2540000
#define OFF_QH      0x2540000
#define OFF_QL      0x3540000
#define OFF_C       0x4540000   // 16MB: xcH(8)+xcL(8) -> Cg(8)+V(4)+mq1+mq2
#define OFF_XH      0x4540000
#define OFF_XL      0x4D40000
#define OFF_CG      0x4540000
#define OFF_V       0x4D40000
#define OFF_MQ1     0x5140000
#define OFF_MQ2     0x5460000
// peak ws: 0x5540000 (proven footprint)

// ---- canonical weight offsets (floats) ----
#define W_WREL0  0
#define W_BREL0  8192
#define W_WROOT0 8320
#define W_WREL1  16512
#define W_BREL1  32896
#define W_WROOT1 33024
#define W_GAMMA  49408
#define W_BETA   49536
#define W_KEYS0  49664
#define W_CONVW0 70144
#define W_LINW0  70149
#define W_LINB0  82949
#define W_KEYS1  83049
#define W_CONVW1 87049
#define W_LINW1  87054
#define W_LINB1  97054
#define W_MLPW1  97154
#define W_MLPB1  102154
#define W_MLPW2  102204
#define W_MLPB2  102804
#define W_TOTAL  102816

typedef __attribute__((ext_vector_type(8))) short  bf16x8;
typedef __attribute__((ext_vector_type(4))) float  f32x4;

__device__ __forceinline__ float bf2f(unsigned short u){
  union { unsigned int i; float f; } v; v.i = ((unsigned int)u) << 16; return v.f;
}
__device__ __forceinline__ unsigned short f2bf(float f){
  union { float f; unsigned int i; } v; v.f = f;
  unsigned int r = (v.i + 0x7FFFu + ((v.i >> 16) & 1u)) >> 16;   // RNE
  return (unsigned short)r;
}

__device__ const int g_seg[21] = {0,8192,8320,16512,32896,33024,49408,49536,49664,
                                  70144,70149,82949,83049,87049,87054,97054,97154,
                                  102154,102204,102804,102816};
struct WPtrs { const void* p[20]; };

__device__ __forceinline__ float rdw(const void* p, int j, int flag){
  return flag ? bf2f(((const unsigned short*)p)[j]) : ((const float*)p)[j];
}

// ---------------- k_pre: detect + init + bin1 (per-block hist, no global atomics) --
__global__ __launch_bounds__(256) void k_pre(const unsigned short* __restrict__ xr,
                                             const int* __restrict__ dst,
                                             int* flag, float* bnsum, float* bnsq,
                                             float* kl, float* cn, int* bh2){
  __shared__ int hist[256];
  const int b = blockIdx.x, t = threadIdx.x;
  hist[t] = 0; __syncthreads();
  const int e0 = b*4096 + t;
  #pragma unroll 4
  for(int j=0;j<16;j++) atomicAdd(&hist[dst[e0 + j*256] >> 8], 1);
  __syncthreads();
  bh2[b*256 + t] = hist[t];
  if(b == 0){
    if(t < 64){
      unsigned short u = xr[2*t];
      int e = (u >> 7) & 0xFF;
      bool plaus = (u != 0) && (e >= 115) && (e <= 135);
      unsigned long long m = __ballot(plaus);
      if(t == 0) flag[0] = (__popcll(m) >= 48) ? 1 : 0;
    }
    if(t < 128){ bnsum[t]=0.f; bnsq[t]=0.f; }
    if(t < 2) kl[t]=0.f;
  }
  if(b < 32) cn[b*256 + t] = 0.f;
}

__global__ __launch_bounds__(256) void k_bscan(const int* __restrict__ bh2,
                                               int* ebase, int* bcur){
  __shared__ int ts[256];
  const int t = threadIdx.x;
  int s = 0;
  for(int b=0;b<256;b++) s += bh2[b*256 + t];
  ts[t] = s; __syncthreads();
  for(int off=1; off<256; off<<=1){
    int v = (t>=off) ? ts[t-off] : 0;
    __syncthreads(); ts[t] += v; __syncthreads();
  }
  int ex = (t==0) ? 0 : ts[t-1];
  ebase[t] = ex; bcur[t] = ex;
}

__global__ __launch_bounds__(256) void k_bin2(const int* __restrict__ src, const int* __restrict__ dst,
                                              int* bcur, unsigned int* __restrict__ ebuf){
  __shared__ int hist[256], lofs[256], lcur[256], gbase[256];
  __shared__ unsigned int sbuf[4096];
  const int t = threadIdx.x;
  hist[t] = 0; __syncthreads();
  const int e0 = blockIdx.x*4096;
  unsigned int pair[16]; int bk[16];
  #pragma unroll 4
  for(int j=0;j<16;j++){
    int e = e0 + t + j*256;
    int s = src[e], d = dst[e];
    pair[j] = (((unsigned)d)<<16) | (unsigned)s;
    bk[j] = d>>8;
    atomicAdd(&hist[bk[j]], 1);
  }
  __syncthreads();
  lcur[t] = hist[t]; __syncthreads();
  for(int off=1; off<256; off<<=1){
    int v = (t>=off) ? lcur[t-off] : 0;
    __syncthreads(); lcur[t] += v; __syncthreads();
  }
  lofs[t] = (t==0) ? 0 : lcur[t-1];
  __syncthreads();
  lcur[t] = lofs[t];
  if(hist[t]) gbase[t] = atomicAdd(&bcur[t], hist[t]);
  __syncthreads();
  #pragma unroll 4
  for(int j=0;j<16;j++){
    int p = atomicAdd(&lcur[bk[j]], 1);
    sbuf[p] = pair[j];
  }
  __syncthreads();
  const int n = hist[t], lo = lofs[t], go = gbase[t];
  for(int i=0;i<n;i++) ebuf[go + i] = sbuf[lo + i];
}

__global__ __launch_bounds__(256) void k_fine(const unsigned int* __restrict__ ebuf,
                                              const int* __restrict__ ebase,
                                              unsigned short* __restrict__ csr,
                                              int* __restrict__ deg, int* __restrict__ offs){
  __shared__ int ldeg[256], lofs[256], lcur[256];
  __shared__ unsigned int led[8192];
  __shared__ unsigned short lcsr[8192];
  const int b = blockIdx.x, t = threadIdx.x;
  const int base = ebase[b];
  const int n = ((b==255) ? NEDGE : ebase[b+1]) - base;
  ldeg[t] = 0; __syncthreads();
  for(int i=t; i<n; i+=256){
    unsigned int p = ebuf[base+i];
    led[i] = p;
    atomicAdd(&ldeg[(p>>16)&255], 1);
  }
  __syncthreads();
  lcur[t] = ldeg[t]; __syncthreads();
  for(int off=1; off<256; off<<=1){
    int v = (t>=off) ? lcur[t-off] : 0;
    __syncthreads(); lcur[t] += v; __syncthreads();
  }
  lofs[t] = (t==0) ? 0 : lcur[t-1];
  __syncthreads();
  lcur[t] = lofs[t];
  __syncthreads();
  for(int i=t; i<n; i+=256){
    unsigned int p = led[i];
    int d = (p>>16)&255;
    int pos = atomicAdd(&lcur[d], 1);
    lcsr[pos] = (unsigned short)(p & 0xFFFF);
  }
  __syncthreads();
  for(int i=t; i<n; i+=256) csr[base+i] = lcsr[i];
  deg[b*256 + t]  = ldeg[t];
  offs[b*256 + t] = base + lofs[t];
}

// ---------------- conversions ----------------
__global__ __launch_bounds__(256) void k_cvtx(const void* __restrict__ xin,
                                              const int* __restrict__ flag,
                                              unsigned short* __restrict__ xH,
                                              unsigned short* __restrict__ xL){
  int i = blockIdx.x*256 + threadIdx.x;          // NTOT*64
  float v = rdw(xin, i, flag[0]);
  unsigned short h = f2bf(v);
  xH[i] = h;
  xL[i] = f2bf(v - bf2f(h));
}

// blocks <402: canonical f32 weights; blocks >=402: k0b + WT planes from raw inputs
__global__ __launch_bounds__(256) void k_cvtw(WPtrs wp, const int* __restrict__ flag,
                                              float* __restrict__ wout,
                                              unsigned short* __restrict__ k0b,
                                              unsigned short* __restrict__ wt1,
                                              unsigned short* __restrict__ wt2){
  const int fl = flag[0];
  if(blockIdx.x < 402){
    int i = blockIdx.x*256 + threadIdx.x;
    if(i >= W_TOTAL) return;
    int s = 0;
    #pragma unroll
    for(int k=0;k<20;k++) if(i >= g_seg[k+1]) s = k+1;
    wout[i] = rdw(wp.p[s], i - g_seg[s], fl);
  } else {
    int i = (blockIdx.x-402)*256 + threadIdx.x;
    if(i < HEADS*K1*128) k0b[i] = f2bf(rdw(wp.p[8], i, fl));
    if(i < 128*64){
      int col = i>>6, k = i&63;
      float wr = rdw(wp.p[0], k*128 + col, fl);
      float wo = rdw(wp.p[2], k*128 + col, fl);
      unsigned short rh = f2bf(wr), oh = f2bf(wo);
      wt1[i]         = rh;
      wt1[ 8192 + i] = f2bf(wr - bf2f(rh));
      wt1[16384 + i] = oh;
      wt1[24576 + i] = f2bf(wo - bf2f(oh));
    }
    if(i < 128*128){
      int col = i>>7, k = i&127;
      float wr = rdw(wp.p[3], k*128 + col, fl);
      float wo = rdw(wp.p[5], k*128 + col, fl);
      unsigned short rh = f2bf(wr), oh = f2bf(wo);
      wt2[i]         = rh;
      wt2[16384 + i] = f2bf(wr - bf2f(rh));
      wt2[32768 + i] = oh;
      wt2[49152 + i] = f2bf(wo - bf2f(oh));
    }
  }
}

// ---------------- graph aggregation (16B bf16x8 gathers) ----------------
// aggr64: 8 lanes/row, 8 edges/wave, 64-edge batches
__global__ __launch_bounds__(256) void k_aggr64(const unsigned short* __restrict__ xH,
                                                const int* __restrict__ offs, const int* __restrict__ deg,
                                                const unsigned short* __restrict__ csr,
                                                unsigned short* __restrict__ aH,
                                                unsigned short* __restrict__ aL){
  const int wid  = (blockIdx.x*256 + threadIdx.x) >> 6;
  const int lane = threadIdx.x & 63;
  const int sub = lane >> 3, fl = lane & 7;
  const int beg = offs[wid], n = deg[wid];
  float acc[8];
  #pragma unroll
  for(int e=0;e<8;e++) acc[e]=0.f;
  int i = 0;
  for(; i+64 <= n; i += 64){
    int s[8];
    #pragma unroll
    for(int j=0;j<8;j++) s[j] = csr[beg + i + 8*j + sub];
    #pragma unroll
    for(int j=0;j<8;j++){
      bf16x8 u = *(const bf16x8*)(xH + (size_t)s[j]*64 + fl*8);
      #pragma unroll
      for(int e=0;e<8;e++) acc[e] += bf2f((unsigned short)u[e]);
    }
  }
  for(; i < n; i += 8){
    if(i + sub < n){
      int s = csr[beg + i + sub];
      bf16x8 u = *(const bf16x8*)(xH + (size_t)s*64 + fl*8);
      #pragma unroll
      for(int e=0;e<8;e++) acc[e] += bf2f((unsigned short)u[e]);
    }
  }
  #pragma unroll
  for(int e=0;e<8;e++){
    acc[e] += __shfl_xor(acc[e], 8);
    acc[e] += __shfl_xor(acc[e], 16);
    acc[e] += __shfl_xor(acc[e], 32);
  }
  if(sub == 0){
    ushort4 h0,h1,l0,l1;
    h0.x=f2bf(acc[0]); l0.x=f2bf(acc[0]-bf2f(h0.x));
    h0.y=f2bf(acc[1]); l0.y=f2bf(acc[1]-bf2f(h0.y));
    h0.z=f2bf(acc[2]); l0.z=f2bf(acc[2]-bf2f(h0.z));
    h0.w=f2bf(acc[3]); l0.w=f2bf(acc[3]-bf2f(h0.w));
    h1.x=f2bf(acc[4]); l1.x=f2bf(acc[4]-bf2f(h1.x));
    h1.y=f2bf(acc[5]); l1.y=f2bf(acc[5]-bf2f(h1.y));
    h1.z=f2bf(acc[6]); l1.z=f2bf(acc[6]-bf2f(h1.z));
    h1.w=f2bf(acc[7]); l1.w=f2bf(acc[7]-bf2f(h1.w));
    *(ushort4*)(aH + (size_t)wid*64 + fl*8)     = h0;
    *(ushort4*)(aH + (size_t)wid*64 + fl*8 + 4) = h1;
    *(ushort4*)(aL + (size_t)wid*64 + fl*8)     = l0;
    *(ushort4*)(aL + (size_t)wid*64 + fl*8 + 4) = l1;
  }
}

// aggr128: 16 lanes/row, 4 edges/wave, 32-edge batches
__global__ __launch_bounds__(256) void k_aggr128(const unsigned short* __restrict__ qH,
                                                 const int* __restrict__ offs, const int* __restrict__ deg,
                                                 const unsigned short* __restrict__ csr,
                                                 unsigned short* __restrict__ aH,
                                                 unsigned short* __restrict__ aL){
  const int wid  = (blockIdx.x*256 + threadIdx.x) >> 6;
  const int lane = threadIdx.x & 63;
  const int sub = lane >> 4, fl = lane & 15;
  const int beg = offs[wid], n = deg[wid];
  float acc[8];
  #pragma unroll
  for(int e=0;e<8;e++) acc[e]=0.f;
  int i = 0;
  for(; i+32 <= n; i += 32){
    int s[8];
    #pragma unroll
    for(int j=0;j<8;j++) s[j] = csr[beg + i + 4*j + sub];
    #pragma unroll
    for(int j=0;j<8;j++){
      bf16x8 u = *(const bf16x8*)(qH + (size_t)s[j]*128 + fl*8);
      #pragma unroll
      for(int e=0;e<8;e++) acc[e] += bf2f((unsigned short)u[e]);
    }
  }
  for(; i < n; i += 4){
    if(i + sub < n){
      int s = csr[beg + i + sub];
      bf16x8 u = *(const bf16x8*)(qH + (size_t)s*128 + fl*8);
      #pragma unroll
      for(int e=0;e<8;e++) acc[e] += bf2f((unsigned short)u[e]);
    }
  }
  #pragma unroll
  for(int e=0;e<8;e++){
    acc[e] += __shfl_xor(acc[e], 16);
    acc[e] += __shfl_xor(acc[e], 32);
  }
  if(sub == 0){
    ushort4 h0,h1,l0,l1;
    h0.x=f2bf(acc[0]); l0.x=f2bf(acc[0]-bf2f(h0.x));
    h0.y=f2bf(acc[1]); l0.y=f2bf(acc[1]-bf2f(h0.y));
    h0.z=f2bf(acc[2]); l0.z=f2bf(acc[2]-bf2f(h0.z));
    h0.w=f2bf(acc[3]); l0.w=f2bf(acc[3]-bf2f(h0.w));
    h1.x=f2bf(acc[4]); l1.x=f2bf(acc[4]-bf2f(h1.x));
    h1.y=f2bf(acc[5]); l1.y=f2bf(acc[5]-bf2f(h1.y));
    h1.z=f2bf(acc[6]); l1.z=f2bf(acc[6]-bf2f(h1.z));
    h1.w=f2bf(acc[7]); l1.w=f2bf(acc[7]-bf2f(h1.w));
    *(ushort4*)(aH + (size_t)wid*128 + fl*8)     = h0;
    *(ushort4*)(aH + (size_t)wid*128 + fl*8 + 4) = h1;
    *(ushort4*)(aL + (size_t)wid*128 + fl*8)     = l0;
    *(ushort4*)(aL + (size_t)wid*128 + fl*8 + 4) = l1;
  }
}

// ---------------- lin via split-bf16 MFMA, B-resident; optional fused BN stats --
template<int KD, bool STATS>
__global__ __launch_bounds__(256) void k_ling(const unsigned short* __restrict__ AH,
                                              const unsigned short* __restrict__ AL,
                                              const unsigned short* XH,
                                              const unsigned short* XL,
                                              const unsigned short* __restrict__ WT,
                                              const float* __restrict__ W, int bofs,
                                              unsigned short* outH,
                                              unsigned short* outL,
                                              float* bnsum, float* bnsq){
  constexpr int NK = KD/32;
  const int t = threadIdx.x;
  const int wv = t>>6, lane = t&63, quad = lane>>4, m = lane&15;
  const int rbase = blockIdx.x*128;
  const int c0 = (wv*2)*16 + m;
  const int c1 = (wv*2+1)*16 + m;

  bf16x8 BrH0[NK], BrL0[NK], BoH0[NK], BoL0[NK];
  bf16x8 BrH1[NK], BrL1[NK], BoH1[NK], BoL1[NK];
  #pragma unroll
  for(int ks=0; ks<NK; ks++){
    const size_t o0 = (size_t)c0*KD + ks*32 + quad*8;
    const size_t o1 = (size_t)c1*KD + ks*32 + quad*8;
    BrH0[ks] = *(const bf16x8*)(WT + o0);
    BrL0[ks] = *(const bf16x8*)(WT + 128*KD + o0);
    BoH0[ks] = *(const bf16x8*)(WT + 256*KD + o0);
    BoL0[ks] = *(const bf16x8*)(WT + 384*KD + o0);
    BrH1[ks] = *(const bf16x8*)(WT + o1);
    BrL1[ks] = *(const bf16x8*)(WT + 128*KD + o1);
    BoH1[ks] = *(const bf16x8*)(WT + 256*KD + o1);
    BoL1[ks] = *(const bf16x8*)(WT + 384*KD + o1);
  }
  const float b0 = W[bofs + c0];
  const float b1 = W[bofs + c1];
  float s1a=0.f, s2a=0.f, s1b=0.f, s2b=0.f;

  for(int rt=0; rt<8; rt++){
    const int r0 = rbase + rt*16;
    bf16x8 fah[NK], fal[NK], fxh[NK], fxl[NK];
    #pragma unroll
    for(int ks=0; ks<NK; ks++){
      const size_t o = (size_t)(r0+m)*KD + ks*32 + quad*8;
      fah[ks] = *(const bf16x8*)(AH + o);
      fal[ks] = *(const bf16x8*)(AL + o);
      fxh[ks] = *(const bf16x8*)(XH + o);
      fxl[ks] = *(const bf16x8*)(XL + o);
    }
    f32x4 a0 = {0.f,0.f,0.f,0.f}, a1 = {0.f,0.f,0.f,0.f};
    #pragma unroll
    for(int ks=0; ks<NK; ks++){
      a0 = __builtin_amdgcn_mfma_f32_16x16x32_bf16(fah[ks], BrH0[ks], a0, 0,0,0);
      a1 = __builtin_amdgcn_mfma_f32_16x16x32_bf16(fah[ks], BrH1[ks], a1, 0,0,0);
      a0 = __builtin_amdgcn_mfma_f32_16x16x32_bf16(fal[ks], BrH0[ks], a0, 0,0,0);
      a1 = __builtin_amdgcn_mfma_f32_16x16x32_bf16(fal[ks], BrH1[ks], a1, 0,0,0);
      a0 = __builtin_amdgcn_mfma_f32_16x16x32_bf16(fah[ks], BrL0[ks], a0, 0,0,0);
      a1 = __builtin_amdgcn_mfma_f32_16x16x32_bf16(fah[ks], BrL1[ks], a1, 0,0,0);
      a0 = __builtin_amdgcn_mfma_f32_16x16x32_bf16(fxh[ks], BoH0[ks], a0, 0,0,0);
      a1 = __builtin_amdgcn_mfma_f32_16x16x32_bf16(fxh[ks], BoH1[ks], a1, 0,0,0);
      a0 = __builtin_amdgcn_mfma_f32_16x16x32_bf16(fxl[ks], BoH0[ks], a0, 0,0,0);
      a1 = __builtin_amdgcn_mfma_f32_16x16x32_bf16(fxl[ks], BoH1[ks], a1, 0,0,0);
      a0 = __builtin_amdgcn_mfma_f32_16x16x32_bf16(fxh[ks], BoL0[ks], a0, 0,0,0);
      a1 = __builtin_amdgcn_mfma_f32_16x16x32_bf16(fxh[ks], BoL1[ks], a1, 0,0,0);
    }
    __syncthreads();   // all waves done reading tile rt (incl. aliased X) before writes
    #pragma unroll
    for(int i=0;i<4;i++){
      const size_t orow = (size_t)(r0 + quad*4 + i)*128;
      float v0 = fmaxf(a0[i] + b0, 0.f);
      unsigned short h0 = f2bf(v0);
      outH[orow + c0] = h0;
      outL[orow + c0] = f2bf(v0 - bf2f(h0));
      float v1 = fmaxf(a1[i] + b1, 0.f);
      unsigned short h1 = f2bf(v1);
      outH[orow + c1] = h1;
      outL[orow + c1] = f2bf(v1 - bf2f(h1));
      if(STATS){
        s1a += v0; s2a += v0*v0;
        s1b += v1; s2b += v1*v1;
      }
    }
  }
  if(STATS){
    s1a += __shfl_xor(s1a,16); s1a += __shfl_xor(s1a,32);
    s2a += __shfl_xor(s2a,16); s2a += __shfl_xor(s2a,32);
    s1b += __shfl_xor(s1b,16); s1b += __shfl_xor(s1b,32);
    s2b += __shfl_xor(s2b,16); s2b += __shfl_xor(s2b,32);
    if(quad == 0){
      atomicAdd(&bnsum[c0], s1a); atomicAdd(&bnsq[c0], s2a);
      atomicAdd(&bnsum[c1], s1b); atomicAdd(&bnsq[c1], s2b);
    }
  }
}

__global__ __launch_bounds__(256) void k_bnfin(const float* __restrict__ bnsum, const float* __restrict__ bnsq,
                                               const float* __restrict__ W,
                                               float* scale, float* shift, float* ksq0, float* ksq1){
  const int t = threadIdx.x;
  if(t < 128){
    double mu  = (double)bnsum[t] / (double)NTOT;
    double var = (double)bnsq[t] / (double)NTOT - mu*mu;
    if(var < 0.0) var = 0.0;
    float sc = W[W_GAMMA + t] * rsqrtf((float)var + 1e-5f);
    scale[t] = sc;
    shift[t] = W[W_BETA + t] - (float)mu * sc;
  }
  if(t < HEADS*K1){
    float s=0.f;
    for(int f=0;f<128;f++){ float v = W[W_KEYS0 + t*128 + f]; s += v*v; }
    ksq0[t] = s;
  }
  if(t < HEADS*K2){
    float s=0.f;
    for(int f=0;f<100;f++){ float v = W[W_KEYS1 + t*100 + f]; s += v*v; }
    ksq1[t] = s;
  }
}

// ---------------- memconv0 stage A: fused qk MFMA + C + partial cn ------------
__global__ __launch_bounds__(256) void k_memA(
    const unsigned short* __restrict__ qH, const unsigned short* __restrict__ qL,
    const float* __restrict__ scale, const float* __restrict__ shift,
    const unsigned short* __restrict__ k0b,
    const float* __restrict__ W, const float* __restrict__ ksq,
    float* __restrict__ Cg, float* __restrict__ cn)
{
  __shared__ unsigned short Qb[64*136];
  __shared__ float qkL[160*68];        // [col][row]
  __shared__ float wsumL[64*36];
  __shared__ float qsqL[64];
  __shared__ float rsL[64*6];
  const int bid = blockIdx.x;
  const int r0 = bid*64;
  const int t = threadIdx.x;
  const int wv = t>>6, lane = t&63, quad = lane>>4, m = lane&15;

  for(int idx=t; idx<64*32; idx+=256){
    int r = idx>>5, c4 = (idx&31)*4;
    size_t o = (size_t)(r0+r)*128 + c4;
    ushort4 uh = *(const ushort4*)(qH + o);
    ushort4 ul = *(const ushort4*)(qL + o);
    float4 s = *(const float4*)(scale + c4);
    float4 h = *(const float4*)(shift + c4);
    ushort4 ob;
    ob.x = f2bf((bf2f(uh.x)+bf2f(ul.x))*s.x + h.x);
    ob.y = f2bf((bf2f(uh.y)+bf2f(ul.y))*s.y + h.y);
    ob.z = f2bf((bf2f(uh.z)+bf2f(ul.z))*s.z + h.z);
    ob.w = f2bf((bf2f(uh.w)+bf2f(ul.w))*s.w + h.w);
    *(ushort4*)(Qb + r*136 + c4) = ob;
  }
  __syncthreads();

  {
    bf16x8 a[4];
    #pragma unroll
    for(int ks=0;ks<4;ks++)
      a[ks] = *(const bf16x8*)(Qb + (wv*16+m)*136 + ks*32 + quad*8);
    for(int nb=0; nb<10; nb++){
      f32x4 acc = {0.f,0.f,0.f,0.f};
      const bf16x8* brow = (const bf16x8*)(k0b + (size_t)(nb*16+m)*128);
      #pragma unroll
      for(int ks=0;ks<4;ks++)
        acc = __builtin_amdgcn_mfma_f32_16x16x32_bf16(a[ks], brow[ks*4+quad], acc,0,0,0);
      *(f32x4*)(qkL + (nb*16+m)*68 + wv*16 + quad*4) = acc;
    }
  }
  if(t < 64){
    float s = 0.f;
    for(int j=0;j<16;j++){
      bf16x8 v = *(const bf16x8*)(Qb + t*136 + j*8);
      #pragma unroll
      for(int e=0;e<8;e++){ float f = bf2f((unsigned short)v[e]); s += f*f; }
    }
    qsqL[t] = s;
  }
  __syncthreads();

  {
    int row = t & 63, g = t >> 6;
    float q2 = qsqL[row];
    #pragma unroll
    for(int pass=0; pass<2; pass++){
      int h = g + pass*4;
      if(h < HEADS){
        float rs = 0.f;
        for(int k=0;k<32;k++){
          float d2 = q2 + ksq[h*32+k] - 2.f*qkL[(h*32+k)*68 + row];
          d2 = fmaxf(d2, 1e-12f);
          rs += 1.f/(1.f+d2);
        }
        rsL[row*6+h] = W[W_CONVW0+h]/fmaxf(rs,1e-20f);
      }
    }
  }
  __syncthreads();

  {
    int row = t & 63, kq = t >> 6;
    float q2 = qsqL[row];
    for(int kk=0; kk<8; kk++){
      int k = kq*8+kk;
      float wsum = 0.f;
      #pragma unroll
      for(int h=0;h<HEADS;h++){
        float d2 = q2 + ksq[h*32+k] - 2.f*qkL[(h*32+k)*68 + row];
        d2 = fmaxf(d2, 1e-12f);
        wsum += rsL[row*6+h]/(1.f+d2);
      }
      wsumL[row*36+k] = wsum;
    }
  }
  __syncthreads();

  if(t < 64){
    float mx = -1e30f;
    #pragma unroll
    for(int k=0;k<32;k++) mx = fmaxf(mx, wsumL[t*36+k]);
    float cv[32]; float se = 0.f;
    #pragma unroll
    for(int k=0;k<32;k++){ float e = __expf(wsumL[t*36+k]-mx); cv[k]=e; se+=e; }
    float inv = 1.f/se;
    #pragma unroll
    for(int k=0;k<32;k++){ cv[k]*=inv; wsumL[t*36+k]=cv[k]; }
    float4* dst = (float4*)(Cg + (size_t)(r0+t)*32);
    #pragma unroll
    for(int k4=0;k4<8;k4++)
      dst[k4] = (float4){cv[k4*4],cv[k4*4+1],cv[k4*4+2],cv[k4*4+3]};
  }
  __syncthreads();
  if(t < 32){
    float s = 0.f;
    for(int r=0;r<64;r++) s += wsumL[r*36+t];
    atomicAdd(&cn[(bid>>2)*32 + t], s);
  }
}

// ---------------- memconv0 stage V+B: V = C^T Q (blocks<1024) and KL (blocks>=1024) --
__global__ __launch_bounds__(256) void k_memVB(const float* __restrict__ Cg,
                                               const unsigned short* __restrict__ qH,
                                               const unsigned short* __restrict__ qL,
                                               const float* __restrict__ scale,
                                               const float* __restrict__ shift,
                                               const float* __restrict__ cn,
                                               float* __restrict__ V,
                                               float* __restrict__ klacc){
  __shared__ float Cs[256*36];
  __shared__ float Qs[256*32];
  const int t = threadIdx.x;
  if(blockIdx.x >= 1024){
    const int b = blockIdx.x - 1024;
    if(t < 32) Cs[t] = cn[b*32+t] + EPSF;
    __syncthreads();
    const float* crow = Cg + ((size_t)b*256 + t)*32;
    float cv[32]; float pn = 0.f;
    #pragma unroll
    for(int k4=0;k4<8;k4++){
      float4 u = *(const float4*)(crow + k4*4);
      cv[k4*4]=u.x; cv[k4*4+1]=u.y; cv[k4*4+2]=u.z; cv[k4*4+3]=u.w;
    }
    #pragma unroll
    for(int k=0;k<32;k++) pn += cv[k]*cv[k]/Cs[k];
    pn += EPSF;
    float acc = 0.f;
    #pragma unroll
    for(int k=0;k<32;k++){
      float P = cv[k]*cv[k]/(Cs[k]*pn);
      acc += P*(__logf(P+EPSF) - __logf(cv[k]+EPSF));
    }
    #pragma unroll
    for(int off=32; off>0; off>>=1) acc += __shfl_down(acc, off);
    if((t&63)==0) Qs[t>>6] = acc;
    __syncthreads();
    if(t==0) atomicAdd(klacc, 100.f*(Qs[0]+Qs[1]+Qs[2]+Qs[3]));
    return;
  }
  const int b  = blockIdx.x >> 2;
  const int f0 = (blockIdx.x & 3) * 32;
  for(int idx=t; idx<256*8; idx+=256){
    int n = idx>>3, k4 = (idx&7)*4;
    *(float4*)(Cs + n*36 + k4) = *(const float4*)(Cg + ((size_t)b*256+n)*32 + k4);
  }
  for(int idx=t; idx<256*8; idx+=256){
    int n = idx>>3, j4 = (idx&7)*4;
    size_t o = ((size_t)b*256+n)*128 + f0 + j4;
    ushort4 uh = *(const ushort4*)(qH + o);
    ushort4 ul = *(const ushort4*)(qL + o);
    float4 s = *(const float4*)(scale + f0 + j4);
    float4 h = *(const float4*)(shift + f0 + j4);
    *(float4*)(Qs + n*32 + j4) = (float4){
      (bf2f(uh.x)+bf2f(ul.x))*s.x + h.x,
      (bf2f(uh.y)+bf2f(ul.y))*s.y + h.y,
      (bf2f(uh.z)+bf2f(ul.z))*s.z + h.z,
      (bf2f(uh.w)+bf2f(ul.w))*s.w + h.w};
  }
  __syncthreads();
  const int k = t & 31, fg = t >> 5;
  float v0=0.f,v1=0.f,v2=0.f,v3=0.f;
  for(int n=0;n<256;n++){
    float c = Cs[n*36+k];
    float4 q = *(const float4*)(Qs + n*32 + fg*4);
    v0 += c*q.x; v1 += c*q.y; v2 += c*q.z; v3 += c*q.w;
  }
  *(float4*)(V + ((size_t)b*32 + k)*128 + f0 + fg*4) = (float4){v0,v1,v2,v3};
}

// ---------------- memconv0 stage L: lin0 ----------------
__global__ __launch_bounds__(256) void k_memL(const float* __restrict__ V,
                                              const float* __restrict__ W,
                                              float* __restrict__ mq1){
  __shared__ float Vs[32*132];
  const int b = blockIdx.x, t = threadIdx.x;
  for(int idx=t; idx<32*32; idx+=256){
    int k = idx>>5, j4 = (idx&31)*4;
    *(float4*)(Vs + k*132 + j4) = *(const float4*)(V + ((size_t)b*32+k)*128 + j4);
  }
  __syncthreads();
  for(int idx=t; idx<K1*MEMH; idx+=256){
    int k = idx/100, mc = idx - k*100;
    float a = W[W_LINB0 + mc];
    for(int f=0; f<128; f++) a += Vs[k*132+f]*W[W_LINW0 + f*100 + mc];
    mq1[(size_t)(b*32+k)*100 + mc] = (a>0.f) ? a : 0.01f*a;
  }
}

// ---------------- mem conv 1 ----------------
__global__ __launch_bounds__(256) void k_memconv1(
    const float* __restrict__ mq1, const float* __restrict__ W,
    const float* __restrict__ ksq, float* __restrict__ mq2, float* __restrict__ klacc)
{
  __shared__ float Qs[32*104];
  __shared__ float Ks[40*100];
  __shared__ float QKs[32*40];
  __shared__ float Cs[32*8];
  __shared__ float cn_s[8];
  __shared__ float pn_s[32];
  __shared__ float qsq_s[32];
  __shared__ float Vs[8*100];
  __shared__ float red_s[4];
  const int b = blockIdx.x, t = threadIdx.x;

  for(int idx=t; idx<32*100; idx+=256){
    int n = idx/100, f = idx - n*100;
    Qs[n*104+f] = mq1[(size_t)b*3200 + idx];
  }
  for(int idx=t; idx<40*100; idx+=256) Ks[idx] = W[W_KEYS1 + idx];
  __syncthreads();

  if(t < 32){ float s=0.f; for(int f=0;f<100;f++){ float v=Qs[t*104+f]; s+=v*v; } qsq_s[t]=s; }
  for(int idx=t; idx<32*40; idx+=256){
    int n = idx/40, c = idx - n*40;
    float a = 0.f;
    for(int f=0;f<100;f++) a += Qs[n*104+f]*Ks[c*100+f];
    QKs[idx] = a;
  }
  __syncthreads();

  if(t < 32){
    float wsum[8];
    #pragma unroll
    for(int k=0;k<8;k++) wsum[k]=0.f;
    for(int h=0;h<HEADS;h++){
      float cw = W[W_CONVW1 + h];
      float c[8]; float rs=0.f;
      #pragma unroll
      for(int k=0;k<8;k++){
        float d2 = qsq_s[t] + ksq[h*8+k] - 2.f*QKs[t*40 + h*8+k];
        d2 = fmaxf(d2, 1e-12f);
        float cc = 1.f/(1.f+d2);
        c[k]=cc; rs+=cc;
      }
      float sc = cw/fmaxf(rs, 1e-20f);
      #pragma unroll
      for(int k=0;k<8;k++) wsum[k] += c[k]*sc;
    }
    float mx = wsum[0];
    #pragma unroll
    for(int k=1;k<8;k++) mx = fmaxf(mx, wsum[k]);
    float se=0.f;
    #pragma unroll
    for(int k=0;k<8;k++){ float e=__expf(wsum[k]-mx); wsum[k]=e; se+=e; }
    float inv = 1.f/se;
    #pragma unroll
    for(int k=0;k<8;k++) Cs[t*8+k] = wsum[k]*inv;
  }
  __syncthreads();
  if(t < 8){ float s=0.f; for(int n=0;n<32;n++) s += Cs[n*8+t]; cn_s[t]=s+EPSF; }
  __syncthreads();
  if(t < 32){
    float p=0.f;
    #pragma unroll
    for(int k=0;k<8;k++){ float sv=Cs[t*8+k]; p += sv*sv/cn_s[k]; }
    pn_s[t]=p+EPSF;
  }
  __syncthreads();

  float acc;
  {
    int n = t>>3, k = t&7;
    float sv = Cs[t];
    float P = sv*sv/(cn_s[k]*pn_s[n]);
    acc = P*(__logf(P+EPSF) - __logf(sv+EPSF));
  }
  #pragma unroll
  for(int off=32; off>0; off>>=1) acc += __shfl_down(acc, off);
  if((t&63)==0) red_s[t>>6] = acc;

  for(int idx=t; idx<8*100; idx+=256){
    int k = idx/100, f = idx - k*100;
    float a=0.f;
    for(int n=0;n<32;n++) a += Cs[n*8+k]*Qs[n*104+f];
    Vs[idx] = a;
  }
  __syncthreads();

  if(t==0) atomicAdd(klacc, 100.f*(red_s[0]+red_s[1]+red_s[2]+red_s[3]));

  for(int idx=t; idx<8*100; idx+=256){
    int k = idx/100, mc = idx - k*100;
    float a = W[W_LINB1 + mc];
    for(int f=0;f<100;f++) a += Vs[k*100+f]*W[W_LINW1 + f*100 + mc];
    mq2[(size_t)b*800 + idx] = (a>0.f) ? a : 0.01f*a;
  }
}

// ---------------- head ----------------
__global__ __launch_bounds__(128) void k_final(const float* __restrict__ mq2,
                                               const float* __restrict__ W,
                                               const int* __restrict__ flag,
                                               const float* __restrict__ kl,
                                               void* __restrict__ out){
  __shared__ float h_s[100];
  __shared__ float hid_s[50];
  const int b = blockIdx.x, t = threadIdx.x;
  if(t < 100){
    float s=0.f;
    #pragma unroll
    for(int k=0;k<8;k++) s += mq2[(size_t)b*800 + k*100 + t];
    h_s[t] = s*0.125f;
  }
  __syncthreads();
  if(t < 50){
    float a = W[W_MLPB1 + t];
    for(int f=0;f<100;f++) a += h_s[f]*W[W_MLPW1 + f*50 + t];
    hid_s[t] = (a>0.f) ? a : 0.01f*a;
  }
  __syncthreads();
  if(t < 12){
    float a = W[W_MLPB2 + t];
    #pragma unroll
    for(int j=0;j<50;j++) a += hid_s[j]*W[W_MLPW2 + j*12 + t];
    if(flag[0]) ((__hip_bfloat16*)out)[b*12+t] = __float2bfloat16(a);
    else        ((float*)out)[b*12+t] = a;
  }
  if(b==0 && t==64){
    float v = (kl[0]+kl[1]) * (1.f/65536.f);
    if(flag[0]) ((__hip_bfloat16*)out)[3072] = __float2bfloat16(v);
    else        ((float*)out)[3072] = v;
  }
}

// ---------------- launch ----------------
extern "C" void kernel_launch(void* const* d_in, const int* in_sizes, int n_in,
                              void* d_out, int out_size, void* d_ws, size_t ws_size,
                              hipStream_t stream) {
  (void)in_sizes; (void)n_in; (void)out_size; (void)ws_size;
  const void* x   = d_in[0];
  const int*  ei  = (const int*)d_in[1];
  const int* src = ei;
  const int* dst = ei + NEDGE;

  WPtrs wp;
  for(int i=0;i<20;i++) wp.p[i] = d_in[3+i];

  char* w = (char*)d_ws;
  int*    deg    = (int*)   (w + OFF_DEG);
  int*    bh2    = (int*)   (w + OFF_BH2);
  int*    offs   = (int*)   (w + OFF_OFFS);
  float*  bnsum  = (float*) (w + OFF_BNSUM);
  float*  bnsq   = (float*) (w + OFF_BNSQ);
  float*  scale  = (float*) (w + OFF_SCALE);
  float*  shift  = (float*) (w + OFF_SHIFT);
  float*  ksq0   = (float*) (w + OFF_KSQ0);
  float*  ksq1   = (float*) (w + OFF_KSQ1);
  float*  kl     = (float*) (w + OFF_KL);
  int*    flag   = (int*)   (w + OFF_FLAG);
  float*  Wc     = (float*) (w + OFF_W);
  unsigned short* k0b = (unsigned short*)(w + OFF_K0B);
  unsigned short* wt1 = (unsigned short*)(w + OFF_WT1);
  unsigned short* wt2 = (unsigned short*)(w + OFF_WT2);
  float*  cn     = (float*) (w + OFF_CN);
  int*    ebase  = (int*)   (w + OFF_EBASE);
  int*    bcur   = (int*)   (w + OFF_BCUR);
  unsigned short* csr = (unsigned short*)(w + OFF_CSR);
  unsigned int*   ebuf = (unsigned int*)(w + OFF_EBUF);
  unsigned short* agH64  = (unsigned short*)(w + OFF_AH64);
  unsigned short* agL64  = (unsigned short*)(w + OFF_AL64);
  unsigned short* agH128 = (unsigned short*)(w + OFF_AH128);
  unsigned short* agL128 = (unsigned short*)(w + OFF_AL128);
  unsigned short* qvH    = (unsigned short*)(w + OFF_QH);
  unsigned short* qvL    = (unsigned short*)(w + OFF_QL);
  unsigned short* xcH    = (unsigned short*)(w + OFF_XH);
  unsigned short* xcL    = (unsigned short*)(w + OFF_XL);
  float*  Cg     = (float*) (w + OFF_CG);
  float*  Vbuf   = (float*) (w + OFF_V);
  float*  mq1    = (float*) (w + OFF_MQ1);
  float*  mq2    = (float*) (w + OFF_MQ2);

  unsigned short* qbnH = qvH;
  unsigned short* qbnL = qvL;

  k_pre    <<<256,   256, 0, stream>>>((const unsigned short*)x, dst, flag, bnsum, bnsq, kl, cn, bh2);
  k_bscan  <<<1,     256, 0, stream>>>(bh2, ebase, bcur);
  k_bin2   <<<256,   256, 0, stream>>>(src, dst, bcur, ebuf);
  k_fine   <<<256,   256, 0, stream>>>(ebuf, ebase, csr, deg, offs);
  k_cvtx   <<<16384, 256, 0, stream>>>(x, flag, xcH, xcL);
  k_cvtw   <<<482,   256, 0, stream>>>(wp, flag, Wc, k0b, wt1, wt2);
  k_aggr64 <<<16384, 256, 0, stream>>>(xcH, offs, deg, csr, agH64, agL64);
  k_ling<64,false> <<<512, 256, 0, stream>>>(agH64, agL64, xcH, xcL, wt1, Wc, W_BREL0, qvH, qvL, bnsum, bnsq);
  k_aggr128<<<16384, 256, 0, stream>>>(qvH, offs, deg, csr, agH128, agL128);
  k_ling<128,true><<<512, 256, 0, stream>>>(agH128, agL128, qvH, qvL, wt2, Wc, W_BREL1, qbnH, qbnL, bnsum, bnsq);
  k_bnfin  <<<1,     256, 0, stream>>>(bnsum, bnsq, Wc, scale, shift, ksq0, ksq1);
  k_memA   <<<1024,  256, 0, stream>>>(qbnH, qbnL, scale, shift, k0b, Wc, ksq0, Cg, cn);
  k_memVB  <<<1280,  256, 0, stream>>>(Cg, qbnH, qbnL, scale, shift, cn, Vbuf, kl);
  k_memL   <<<256,   256, 0, stream>>>(Vbuf, Wc, mq1);
  k_memconv1<<<256,  256, 0, stream>>>(mq1, Wc, ksq1, mq2, kl+1);
  k_final  <<<256,   128, 0, stream>>>(mq2, Wc, flag, kl, d_out);
}